// Round 16
// baseline (414.544 us; speedup 1.0000x reference)
//
#include <hip/hip_runtime.h>
#include <math.h>

#define BB 16
#define MM 512
#define LL 1024
#define DD 128
#define KK 16
#define HH 8
#define DHH 16
#define NDFF 512
#define NNODE (BB*MM)      // 8192
#define NEDGE (NNODE*KK)   // 131072

typedef __attribute__((ext_vector_type(8))) short bf16x8;
typedef __attribute__((ext_vector_type(4))) float f32x4;
#define MFMA(a,b,c) __builtin_amdgcn_mfma_f32_16x16x32_bf16(a,b,c,0,0,0)

__device__ inline unsigned short bf16rne(float x) {
  union { float f; unsigned u; } v; v.f = x;
  return (unsigned short)((v.u + 0x7FFFu + ((v.u >> 16) & 1u)) >> 16);
}
__device__ inline float bf16tof(unsigned short h) {
  union { unsigned u; float f; } v; v.u = ((unsigned)h) << 16; return v.f;
}
__device__ inline void hilo(float x, unsigned short& h, unsigned short& l) {
  h = bf16rne(x);
  l = bf16rne(x - bf16tof(h));
}

// async global->LDS, 16B per lane (linear dest = wave-uniform base + lane*16)
__device__ inline void async16(const void* g, void* l) {
  __builtin_amdgcn_global_load_lds(
      (const __attribute__((address_space(1))) unsigned int*)g,
      (__attribute__((address_space(3))) unsigned int*)l, 16, 0, 0);
}

// ---------------- transpose x_enc [b][l][m] -> chunked k-major bf16 hi/lo ----------
__global__ __launch_bounds__(256) void transpose_x_kernel(const float* __restrict__ X,
                                                          unsigned short* __restrict__ XTh,
                                                          unsigned short* __restrict__ XTl) {
  __shared__ float t[32][33];
  int b = blockIdx.z;
  int m0 = blockIdx.x * 32, l0 = blockIdx.y * 32;
  int c = threadIdx.x & 31, r = threadIdx.x >> 5;   // r 0..7
  const float* Xb = X + (size_t)b * LL * MM;
  #pragma unroll
  for (int i = 0; i < 4; ++i)
    t[r + i*8][c] = Xb[(size_t)(l0 + r + i*8) * MM + m0 + c];
  __syncthreads();
  int R = m0 >> 6;
  int rbase = m0 & 63;
  size_t base = ((size_t)(b * 8 + R)) * 65536 + (size_t)(l0 >> 5) * 2048
              + (size_t)(c >> 3) * 512 + (c & 7);
  #pragma unroll
  for (int i = 0; i < 4; ++i) {
    unsigned short h, l;
    hilo(t[c][r + i*8], h, l);
    size_t idx = base + (size_t)(rbase + r + i*8) * 8;
    XTh[idx] = h; XTl[idx] = l;
  }
}

// ---------------- transpose weights [K][N] -> bf16 hi/lo [N][K] ----------------
__global__ __launch_bounds__(256) void transpose_w_kernel(
    const float* __restrict__ gw1, const float* __restrict__ gw2,
    const float* __restrict__ Wq, const float* __restrict__ Wk,
    const float* __restrict__ Wv, const float* __restrict__ Wo,
    const float* __restrict__ W1, const float* __restrict__ W2,
    unsigned short* __restrict__ wTh, unsigned short* __restrict__ wTl) {
  int z = blockIdx.z;
  const float* src; int K, N; size_t doff;
  if (z < 10) {
    K = 128; N = 128;
    switch (z) {
      case 0: src = gw1;         doff = 0;         break;
      case 1: src = gw2;         doff = 16384;     break;
      case 2: src = Wk;          doff = 2*16384;   break;
      case 3: src = Wv;          doff = 3*16384;   break;
      case 4: src = Wk + 16384;  doff = 4*16384;   break;
      case 5: src = Wv + 16384;  doff = 5*16384;   break;
      case 6: src = Wq;          doff = 6*16384;   break;
      case 7: src = Wq + 16384;  doff = 7*16384;   break;
      case 8: src = Wo;          doff = 8*16384;   break;
      default: src = Wo + 16384; doff = 9*16384;   break;
    }
  } else if (z < 12) {
    K = 128; N = 512; doff = 163840 + (size_t)(z - 10) * 65536;
    src = W1 + (size_t)(z - 10) * 65536;
  } else {
    K = 512; N = 128; doff = 294912 + (size_t)(z - 12) * 65536;
    src = W2 + (size_t)(z - 12) * 65536;
  }
  int k0 = blockIdx.x * 32, n0 = blockIdx.y * 32;
  if (k0 >= K || n0 >= N) return;
  __shared__ float t[32][33];
  int c = threadIdx.x & 31, r = threadIdx.x >> 5;
  #pragma unroll
  for (int i = 0; i < 4; ++i)
    t[r + i*8][c] = src[(size_t)(k0 + r + i*8) * N + n0 + c];
  __syncthreads();
  #pragma unroll
  for (int i = 0; i < 4; ++i) {
    size_t idx = doff + (size_t)(n0 + r + i*8) * K + k0 + c;
    unsigned short h, l;
    hilo(t[c][r + i*8], h, l);
    wTh[idx] = h; wTl[idx] = l;
  }
}

// ---------------- plain fp32 -> bf16 hi/lo split (for enc) ----------------
__global__ void split_kernel(const float* __restrict__ in,
                             unsigned short* __restrict__ h,
                             unsigned short* __restrict__ l) {
  int i = blockIdx.x * 256 + threadIdx.x;     // per float4
  float4 v = ((const float4*)in)[i];
  unsigned short h0,h1,h2,h3,l0,l1,l2,l3;
  hilo(v.x,h0,l0); hilo(v.y,h1,l1); hilo(v.z,h2,l2); hilo(v.w,h3,l3);
  uint2 hh, ll;
  hh.x = (unsigned)h0 | ((unsigned)h1 << 16); hh.y = (unsigned)h2 | ((unsigned)h3 << 16);
  ll.x = (unsigned)l0 | ((unsigned)l1 << 16); ll.y = (unsigned)l2 | ((unsigned)l3 << 16);
  ((uint2*)h)[i] = hh; ((uint2*)l)[i] = ll;
}

// ---------------- column means (original layout) ----------------
__global__ void colmean_part_kernel(const float* __restrict__ X, float* __restrict__ part) {
  int bm = blockIdx.x * 256 + threadIdx.x;
  int b = bm >> 9, m = bm & (MM - 1);
  int l0 = blockIdx.y * 128;
  const float* p = X + (size_t)b * LL * MM + (size_t)l0 * MM + m;
  float s = 0.f;
  #pragma unroll 8
  for (int l = 0; l < 128; ++l) s += p[(size_t)l * MM];
  part[(size_t)blockIdx.y * NNODE + bm] = s;
}

__global__ void colmean_finish_kernel(const float* __restrict__ part, float* __restrict__ mu) {
  int bm = blockIdx.x * 256 + threadIdx.x;
  float s = 0.f;
  #pragma unroll
  for (int j = 0; j < 8; ++j) s += part[(size_t)j * NNODE + bm];
  mu[bm] = s * (1.f / 1024.f);
}

// ---------------- MFMA gram, LDS-staged via global_load_lds, z-split partials -----
__global__ __launch_bounds__(256) void gram_kernel(const unsigned short* __restrict__ XTh,
                                                   const unsigned short* __restrict__ XTl,
                                                   float* __restrict__ G0,
                                                   float* __restrict__ G1) {
  __shared__ unsigned short lAh[2048], lAl[2048], lBh[2048], lBl[2048];
  int b = blockIdx.y, z = blockIdx.z;
  int pi = blockIdx.x;
  int ti = 0, rem = pi;
  while (rem >= 8 - ti) { rem -= 8 - ti; ++ti; }
  int tj = ti + rem;
  int tid = threadIdx.x;
  int wid = tid >> 6, lane = tid & 63;
  int wr = wid >> 1, wc = wid & 1;
  int fr = lane & 15, fkb = lane >> 4;
  size_t abase = ((size_t)(b * 8 + ti)) * 65536 + (size_t)z * 16 * 2048;
  size_t bbase = ((size_t)(b * 8 + tj)) * 65536 + (size_t)z * 16 * 2048;
  int toff = tid * 8;
  int aoff0 = fkb * 512 + (wr*32 + fr) * 8;
  int aoff1 = aoff0 + 128;
  int boff0 = fkb * 512 + (wc*32 + fr) * 8;
  int boff1 = boff0 + 128;
  f32x4 acc00 = {0,0,0,0}, acc01 = {0,0,0,0}, acc10 = {0,0,0,0}, acc11 = {0,0,0,0};
  for (int s = 0; s < 16; ++s) {
    size_t ao = abase + (size_t)s * 2048 + toff;
    size_t bo = bbase + (size_t)s * 2048 + toff;
    async16(XTh + ao, lAh + toff);
    async16(XTl + ao, lAl + toff);
    async16(XTh + bo, lBh + toff);
    async16(XTl + bo, lBl + toff);
    __syncthreads();
    bf16x8 a0h = *(const bf16x8*)(lAh + aoff0);
    bf16x8 a1h = *(const bf16x8*)(lAh + aoff1);
    bf16x8 a0l = *(const bf16x8*)(lAl + aoff0);
    bf16x8 a1l = *(const bf16x8*)(lAl + aoff1);
    bf16x8 b0h = *(const bf16x8*)(lBh + boff0);
    bf16x8 b1h = *(const bf16x8*)(lBh + boff1);
    bf16x8 b0l = *(const bf16x8*)(lBl + boff0);
    bf16x8 b1l = *(const bf16x8*)(lBl + boff1);
    acc00 = MFMA(a0h, b0h, acc00); acc00 = MFMA(a0h, b0l, acc00); acc00 = MFMA(a0l, b0h, acc00);
    acc01 = MFMA(a0h, b1h, acc01); acc01 = MFMA(a0h, b1l, acc01); acc01 = MFMA(a0l, b1h, acc01);
    acc10 = MFMA(a1h, b0h, acc10); acc10 = MFMA(a1h, b0l, acc10); acc10 = MFMA(a1l, b0h, acc10);
    acc11 = MFMA(a1h, b1h, acc11); acc11 = MFMA(a1h, b1l, acc11); acc11 = MFMA(a1l, b1h, acc11);
    __syncthreads();
  }
  int m0 = ti * 64, n0 = tj * 64;
  float* G = (z ? G1 : G0) + (size_t)b * MM * MM;
  int mirror = (ti != tj);
  #pragma unroll
  for (int i = 0; i < 2; ++i) {
    #pragma unroll
    for (int j = 0; j < 2; ++j) {
      const f32x4& a = (i == 0) ? (j == 0 ? acc00 : acc01) : (j == 0 ? acc10 : acc11);
      #pragma unroll
      for (int r = 0; r < 4; ++r) {
        int row = m0 + wr*32 + i*16 + (lane >> 4)*4 + r;
        int col = n0 + wc*32 + j*16 + (lane & 15);
        float v = a[r];
        G[(size_t)row * MM + col] = v;
        if (mirror) G[(size_t)col * MM + row] = v;
      }
    }
  }
}

// ---------------- MFMA GEMM, K=128 fully unrolled: all 32 frags loaded up front ---
// Epilogue: fp32 C, bf16 hi/lo (Ch+Cl), or single bf16 (Ch only, Cl==null).
__global__ __launch_bounds__(256) void bf_gemm_k128_kernel(
    const unsigned short* __restrict__ Ah, const unsigned short* __restrict__ Al,
    const unsigned short* __restrict__ Bh, const unsigned short* __restrict__ Bl,
    float* __restrict__ C, unsigned short* __restrict__ Ch, unsigned short* __restrict__ Cl,
    int Ldc, int col0, const float* __restrict__ bias,
    const float* __restrict__ resid, int relu) {
  int tid = threadIdx.x;
  int m0 = blockIdx.y * 64, n0 = blockIdx.x * 64;
  int wid = tid >> 6, lane = tid & 63;
  int wr = wid >> 1, wc = wid & 1;
  int fr = lane & 15, fkb = lane >> 4;
  size_t arow0 = (size_t)(m0 + wr*32 + fr) * 128;
  size_t arow1 = arow0 + 16 * 128;
  size_t brow0 = (size_t)(n0 + wc*32 + fr) * 128;
  size_t brow1 = brow0 + 16 * 128;
  bf16x8 fa0h[4], fa1h[4], fa0l[4], fa1l[4];
  bf16x8 fb0h[4], fb1h[4], fb0l[4], fb1l[4];
  #pragma unroll
  for (int ks = 0; ks < 4; ++ks) {
    int ko = ks * 32 + fkb * 8;
    fa0h[ks] = *(const bf16x8*)(Ah + arow0 + ko);
    fa1h[ks] = *(const bf16x8*)(Ah + arow1 + ko);
    fa0l[ks] = *(const bf16x8*)(Al + arow0 + ko);
    fa1l[ks] = *(const bf16x8*)(Al + arow1 + ko);
    fb0h[ks] = *(const bf16x8*)(Bh + brow0 + ko);
    fb1h[ks] = *(const bf16x8*)(Bh + brow1 + ko);
    fb0l[ks] = *(const bf16x8*)(Bl + brow0 + ko);
    fb1l[ks] = *(const bf16x8*)(Bl + brow1 + ko);
  }
  f32x4 acc00 = {0,0,0,0}, acc01 = {0,0,0,0}, acc10 = {0,0,0,0}, acc11 = {0,0,0,0};
  #pragma unroll
  for (int ks = 0; ks < 4; ++ks) {
    acc00 = MFMA(fa0h[ks], fb0h[ks], acc00);
    acc00 = MFMA(fa0h[ks], fb0l[ks], acc00);
    acc00 = MFMA(fa0l[ks], fb0h[ks], acc00);
    acc01 = MFMA(fa0h[ks], fb1h[ks], acc01);
    acc01 = MFMA(fa0h[ks], fb1l[ks], acc01);
    acc01 = MFMA(fa0l[ks], fb1h[ks], acc01);
    acc10 = MFMA(fa1h[ks], fb0h[ks], acc10);
    acc10 = MFMA(fa1h[ks], fb0l[ks], acc10);
    acc10 = MFMA(fa1l[ks], fb0h[ks], acc10);
    acc11 = MFMA(fa1h[ks], fb1h[ks], acc11);
    acc11 = MFMA(fa1h[ks], fb1l[ks], acc11);
    acc11 = MFMA(fa1l[ks], fb1h[ks], acc11);
  }
  #pragma unroll
  for (int i = 0; i < 2; ++i) {
    #pragma unroll
    for (int j = 0; j < 2; ++j) {
      const f32x4& a = (i == 0) ? (j == 0 ? acc00 : acc01) : (j == 0 ? acc10 : acc11);
      #pragma unroll
      for (int r = 0; r < 4; ++r) {
        int row = m0 + wr*32 + i*16 + (lane >> 4)*4 + r;
        int col = col0 + n0 + wc*32 + j*16 + (lane & 15);
        float v = a[r];
        if (bias)  v += bias[col - col0];
        if (resid) v += resid[(size_t)row * Ldc + col];
        if (relu)  v = fmaxf(v, 0.f);
        size_t o = (size_t)row * Ldc + col;
        if (C) C[o] = v;
        if (Ch) {
          if (Cl) {
            unsigned short hh, ll;
            hilo(v, hh, ll);
            Ch[o] = hh; Cl[o] = ll;
          } else {
            Ch[o] = bf16rne(v);
          }
        }
      }
    }
  }
}

// ---------------- MFMA GEMM 64x64 tile, 8 waves, in-block split-K2 (K=512) --------
__global__ __launch_bounds__(512) void bf_gemm_sk_kernel(
    const unsigned short* __restrict__ Ah, const unsigned short* __restrict__ Al,
    const unsigned short* __restrict__ Bh, const unsigned short* __restrict__ Bl,
    float* __restrict__ C, unsigned short* __restrict__ Ch, unsigned short* __restrict__ Cl,
    int Ldc, int col0, int Kd, const float* __restrict__ bias,
    const float* __restrict__ resid, int relu) {
  __shared__ float red[64][65];
  int tid = threadIdx.x;
  int m0 = blockIdx.y * 64, n0 = blockIdx.x * 64;
  int wid = tid >> 6, lane = tid & 63;
  int kg = wid >> 2;
  int w4 = wid & 3;
  int wr = w4 >> 1, wc = w4 & 1;
  int fr = lane & 15, fkb = lane >> 4;
  int Kh = Kd >> 1;
  size_t arow0 = (size_t)(m0 + wr*32 + fr) * Kd + (size_t)kg * Kh;
  size_t arow1 = arow0 + (size_t)16 * Kd;
  size_t brow0 = (size_t)(n0 + wc*32 + fr) * Kd + (size_t)kg * Kh;
  size_t brow1 = brow0 + (size_t)16 * Kd;
  f32x4 acc00 = {0,0,0,0}, acc01 = {0,0,0,0}, acc10 = {0,0,0,0}, acc11 = {0,0,0,0};
  int ko = fkb * 8;
  bf16x8 a0h = *(const bf16x8*)(Ah + arow0 + ko);
  bf16x8 a1h = *(const bf16x8*)(Ah + arow1 + ko);
  bf16x8 a0l = *(const bf16x8*)(Al + arow0 + ko);
  bf16x8 a1l = *(const bf16x8*)(Al + arow1 + ko);
  bf16x8 b0h = *(const bf16x8*)(Bh + brow0 + ko);
  bf16x8 b1h = *(const bf16x8*)(Bh + brow1 + ko);
  bf16x8 b0l = *(const bf16x8*)(Bl + brow0 + ko);
  bf16x8 b1l = *(const bf16x8*)(Bl + brow1 + ko);
  for (int k0 = 32; k0 < Kh; k0 += 32) {
    int kn = k0 + fkb * 8;
    bf16x8 na0h = *(const bf16x8*)(Ah + arow0 + kn);
    bf16x8 na1h = *(const bf16x8*)(Ah + arow1 + kn);
    bf16x8 na0l = *(const bf16x8*)(Al + arow0 + kn);
    bf16x8 na1l = *(const bf16x8*)(Al + arow1 + kn);
    bf16x8 nb0h = *(const bf16x8*)(Bh + brow0 + kn);
    bf16x8 nb1h = *(const bf16x8*)(Bh + brow1 + kn);
    bf16x8 nb0l = *(const bf16x8*)(Bl + brow0 + kn);
    bf16x8 nb1l = *(const bf16x8*)(Bl + brow1 + kn);
    acc00 = MFMA(a0h, b0h, acc00); acc00 = MFMA(a0h, b0l, acc00); acc00 = MFMA(a0l, b0h, acc00);
    acc01 = MFMA(a0h, b1h, acc01); acc01 = MFMA(a0h, b1l, acc01); acc01 = MFMA(a0l, b1h, acc01);
    acc10 = MFMA(a1h, b0h, acc10); acc10 = MFMA(a1h, b0l, acc10); acc10 = MFMA(a1l, b0h, acc10);
    acc11 = MFMA(a1h, b1h, acc11); acc11 = MFMA(a1h, b1l, acc11); acc11 = MFMA(a1l, b1h, acc11);
    a0h = na0h; a1h = na1h; a0l = na0l; a1l = na1l;
    b0h = nb0h; b1h = nb1h; b0l = nb0l; b1l = nb1l;
  }
  acc00 = MFMA(a0h, b0h, acc00); acc00 = MFMA(a0h, b0l, acc00); acc00 = MFMA(a0l, b0h, acc00);
  acc01 = MFMA(a0h, b1h, acc01); acc01 = MFMA(a0h, b1l, acc01); acc01 = MFMA(a0l, b1h, acc01);
  acc10 = MFMA(a1h, b0h, acc10); acc10 = MFMA(a1h, b0l, acc10); acc10 = MFMA(a1l, b0h, acc10);
  acc11 = MFMA(a1h, b1h, acc11); acc11 = MFMA(a1h, b1l, acc11); acc11 = MFMA(a1l, b1h, acc11);
  if (kg == 1) {
    #pragma unroll
    for (int i = 0; i < 2; ++i) {
      #pragma unroll
      for (int j = 0; j < 2; ++j) {
        const f32x4& a = (i == 0) ? (j == 0 ? acc00 : acc01) : (j == 0 ? acc10 : acc11);
        #pragma unroll
        for (int r = 0; r < 4; ++r) {
          int lr = wr*32 + i*16 + (lane >> 4)*4 + r;
          int lc = wc*32 + j*16 + (lane & 15);
          red[lr][lc] = a[r];
        }
      }
    }
  }
  __syncthreads();
  if (kg == 0) {
    #pragma unroll
    for (int i = 0; i < 2; ++i) {
      #pragma unroll
      for (int j = 0; j < 2; ++j) {
        const f32x4& a = (i == 0) ? (j == 0 ? acc00 : acc01) : (j == 0 ? acc10 : acc11);
        #pragma unroll
        for (int r = 0; r < 4; ++r) {
          int lr = wr*32 + i*16 + (lane >> 4)*4 + r;
          int lc = wc*32 + j*16 + (lane & 15);
          int row = m0 + lr;
          int col = col0 + n0 + lc;
          float v = a[r] + red[lr][lc];
          if (bias)  v += bias[col - col0];
          if (resid) v += resid[(size_t)row * Ldc + col];
          if (relu)  v = fmaxf(v, 0.f);
          size_t o = (size_t)row * Ldc + col;
          if (C) C[o] = v;
          if (Ch) {
            unsigned short hh, ll;
            hilo(v, hh, ll);
            Ch[o] = hh; Cl[o] = ll;
          }
        }
      }
    }
  }
}

// ---------------- rstd[b,m] = 1/std (std==0 -> 1) ----------------
__global__ void rstd_kernel(const float* __restrict__ G0, const float* __restrict__ G1,
                            const float* __restrict__ mu, float* __restrict__ rstd) {
  int bm = blockIdx.x * 256 + threadIdx.x;
  int b = bm >> 9, m = bm & (MM - 1);
  size_t di = (size_t)b * MM * MM + (size_t)m * MM + m;
  float g = G0[di] + G1[di];
  float mm = mu[bm];
  float cov = (g - 1024.f * mm * mm) * (1.f / 1023.f);
  float sd = sqrtf(fmaxf(cov, 0.f));
  rstd[bm] = (sd == 0.f) ? 1.f : (1.f / sd);
}

// ---------------- neighbors: pair-extraction argsort positions 1..16 ----------------
// u64 keys (sortable_float<<32)|idx give exact (value, index) lexicographic order.
// Per-lane 8 keys sorted by a 19-CE network; 9 rounds extract the 2 global minima
// per round via a 6-level butterfly merge-2 (chain depth 54 vs 102 before).
__global__ void select_kernel(const float* __restrict__ G0, const float* __restrict__ G1,
                              const float* __restrict__ mu,
                              const float* __restrict__ rstd, int* __restrict__ nb) {
  int w = threadIdx.x >> 6, lane = threadIdx.x & 63;
  int bm = blockIdx.x * 4 + w;
  int b = bm >> 9, m = bm & (MM - 1);
  size_t rowoff = (size_t)b * MM * MM + (size_t)m * MM;
  const float* Gr0 = G0 + rowoff;
  const float* Gr1 = G1 + rowoff;
  const float* mub = mu + b * MM;
  const float* rsb = rstd + b * MM;
  float mm = mub[m], rm = rsb[m];
  unsigned long long k[8];
  #pragma unroll
  for (int j = 0; j < 8; ++j) {
    int n = lane + j * 64;
    float cov = ((Gr0[n] + Gr1[n]) - 1024.f * mm * mub[n]) * (1.f / 1023.f);
    float val = cov * rm * rsb[n];
    union { float f; unsigned u; } cv; cv.f = val;
    unsigned s = cv.u ^ ((unsigned)((int)cv.u >> 31) | 0x80000000u);
    k[j] = ((unsigned long long)s << 32) | (unsigned)n;
  }
  // 8-element sorting network (19 CEs), ascending
  #define CE(i, j) { unsigned long long lo = k[i] < k[j] ? k[i] : k[j]; \
                     unsigned long long hi = k[i] < k[j] ? k[j] : k[i]; \
                     k[i] = lo; k[j] = hi; }
  CE(0,1) CE(2,3) CE(4,5) CE(6,7)
  CE(0,2) CE(1,3) CE(4,6) CE(5,7)
  CE(1,2) CE(5,6) CE(0,4) CE(3,7)
  CE(1,5) CE(2,6)
  CE(1,4) CE(3,6)
  CE(2,4) CE(3,5)
  CE(3,4)
  #undef CE
  const unsigned long long UMX = 0xFFFFFFFFFFFFFFFFull;
  int* out = nb + (size_t)bm * KK;
  #pragma unroll 1
  for (int r = 0; r < 9; ++r) {
    unsigned long long c1 = k[0], c2 = k[1];
    #pragma unroll
    for (int lvl = 1; lvl <= 32; lvl <<= 1) {
      unsigned long long o1 = __shfl_xor(c1, lvl);
      unsigned long long o2 = __shfl_xor(c2, lvl);
      unsigned long long lo = c1 < o1 ? c1 : o1;
      unsigned long long hi = c1 < o1 ? o1 : c1;
      unsigned long long m2 = c2 < o2 ? c2 : o2;
      c1 = lo;
      c2 = hi < m2 ? hi : m2;
    }
    if (lane == 0) {
      if (r == 0) {
        out[0] = (int)(unsigned)(c2 & 0xFFFFFFFFu);
      } else if (r < 8) {
        out[2*r - 1] = (int)(unsigned)(c1 & 0xFFFFFFFFu);
        out[2*r]     = (int)(unsigned)(c2 & 0xFFFFFFFFu);
      } else {
        out[15] = (int)(unsigned)(c1 & 0xFFFFFFFFu);
      }
    }
    if (r < 8) {
      bool hit = (k[0] == c1) || (k[0] == c2);
      k[0] = hit ? k[1] : k[0];
      k[1] = hit ? k[2] : k[1];
      k[2] = hit ? k[3] : k[2];
      k[3] = hit ? k[4] : k[3];
      k[4] = hit ? k[5] : k[4];
      k[5] = hit ? k[6] : k[5];
      k[6] = hit ? k[7] : k[6];
      k[7] = hit ? UMX  : k[7];
      bool hit2 = (k[0] == c1) || (k[0] == c2);
      k[0] = hit2 ? k[1] : k[0];
      k[1] = hit2 ? k[2] : k[1];
      k[2] = hit2 ? k[3] : k[2];
      k[3] = hit2 ? k[4] : k[3];
      k[4] = hit2 ? k[5] : k[4];
      k[5] = hit2 ? k[6] : k[5];
      k[6] = hit2 ? k[7] : k[6];
      k[7] = hit2 ? UMX  : k[7];
    }
  }
}

// ---------------- degree counts ----------------
__global__ void count_kernel(const int* __restrict__ nb, int* __restrict__ cnt) {
  int e = blockIdx.x * 256 + threadIdx.x;
  int b = e >> 13, i = e & 8191;
  int dst = b * MM + nb[(size_t)b * 8192 + i];
  atomicAdd(&cnt[dst], 1);
}

// ---------------- scan + cursor + dinv ----------------
__global__ void scan_kernel(const int* __restrict__ cnt, int* __restrict__ offs,
                            int* __restrict__ curs, float* __restrict__ dinv) {
  __shared__ int part[256];
  int tid = threadIdx.x;
  int base = tid * 32;
  int local[32];
  int s = 0;
  #pragma unroll
  for (int i = 0; i < 32; ++i) { local[i] = cnt[base + i]; s += local[i]; }
  part[tid] = s;
  __syncthreads();
  for (int off = 1; off < 256; off <<= 1) {
    int v = (tid >= off) ? part[tid - off] : 0;
    __syncthreads();
    part[tid] += v;
    __syncthreads();
  }
  int run = part[tid] - s;
  #pragma unroll
  for (int i = 0; i < 32; ++i) {
    int n = base + i;
    offs[n] = run; curs[n] = run;
    run += local[i];
    dinv[n] = rsqrtf((float)(local[i] + 1));
  }
  if (tid == 255) offs[NNODE] = run;
}

// ---------------- scatter reverse edge lists ----------------
__global__ void scatter_kernel(const int* __restrict__ nb, int* __restrict__ curs,
                               int* __restrict__ lists) {
  int e = blockIdx.x * 256 + threadIdx.x;
  int b = e >> 13, i = e & 8191;
  int dst = b * MM + nb[(size_t)b * 8192 + i];
  int src = b * MM + (i & (MM - 1));
  int pos = atomicAdd(&curs[dst], 1);
  lists[pos] = src;
}

// ---------------- GCN aggregation: fp32 gather in, bf16 hi/lo out ----------------
__global__ void agg_kernel(const float* __restrict__ xw, const float* __restrict__ dinv,
                           const int* __restrict__ offs, const int* __restrict__ lists,
                           const float* __restrict__ bias,
                           unsigned short* __restrict__ outh,
                           unsigned short* __restrict__ outl) {
  int n = blockIdx.x * 2 + (threadIdx.x >> 7);
  int c = threadIdx.x & 127;
  float dn = dinv[n];
  float s = dn * xw[(size_t)n * DD + c];
  int e0 = offs[n], e1 = offs[n + 1];
  for (int e = e0; e < e1; ++e) {
    int src = lists[e];
    s += dinv[src] * xw[(size_t)src * DD + c];
  }
  float v = fmaxf(dn * s + bias[c], 0.f);
  unsigned short hh, ll;
  hilo(v, hh, ll);
  size_t o = (size_t)n * DD + c;
  outh[o] = hh; outl[o] = ll;
}

// ---------------- MFMA flash attention ----------------
__global__ __launch_bounds__(256) void attn_mfma_kernel(
    const unsigned short* __restrict__ Qb16, const unsigned short* __restrict__ KV16,
    int kvoff,
    unsigned short* __restrict__ outh, unsigned short* __restrict__ outl) {
  __shared__ unsigned short Kl[512 * 16];     // [key][16d], row 32B
  __shared__ unsigned short VT[16 * 520];     // [d][520 keys], row 1040B
  __shared__ unsigned short Pl[64 * 136];     // [q][136 keys], row 272B
  int bx = blockIdx.x;
  int qc = bx & 7;
  int h  = (bx >> 3) & 7;
  int b  = bx >> 6;
  int tid = threadIdx.x;

  for (int u = tid; u < 1024; u += 256) {
    int row = u >> 1, half = u & 1;
    const unsigned short* src = KV16 + (size_t)(b * MM + row) * 512 + kvoff + h * 16 + half * 8;
    *(uint4*)&Kl[row * 16 + half * 8] = *(const uint4*)src;
  }
  for (int key = tid; key < 512; key += 256) {
    const unsigned short* src = KV16 + (size_t)(b * MM + key) * 512 + kvoff + 128 + h * 16;
    unsigned short tmp[16];
    *(uint4*)&tmp[0] = *(const uint4*)src;
    *(uint4*)&tmp[8] = *(const uint4*)(src + 8);
    #pragma unroll
    for (int d = 0; d < 16; ++d) VT[d * 520 + key] = tmp[d];
  }
  __syncthreads();

  int wid = tid >> 6, lane = tid & 63;
  int lq = lane & 15, g = lane >> 4;
  bf16x8 zz = {0,0,0,0,0,0,0,0};
  bf16x8 qf = zz;
  if (lane < 32) {
    int qrow = b * MM + qc * 64 + wid * 16 + lq;
    qf = *(const bf16x8*)(Qb16 + (size_t)qrow * 128 + h * 16 + g * 8);
  }
  float m = -1e30f, lp = 0.f;
  f32x4 o = {0,0,0,0};
  int prow = (wid * 16 + lq) * 136;

  for (int c4 = 0; c4 < 4; ++c4) {
    int kbase = c4 * 128;
    f32x4 s[8];
    f32x4 zc = {0,0,0,0};
    #pragma unroll
    for (int t = 0; t < 8; ++t) {
      bf16x8 kf = zz;
      if (lane < 32) kf = *(const bf16x8*)&Kl[(kbase + t * 16 + lq) * 16 + g * 8];
      s[t] = MFMA(kf, qf, zc);
    }
    float tm = -1e30f;
    #pragma unroll
    for (int t = 0; t < 8; ++t) {
      tm = fmaxf(tm, fmaxf(fmaxf(s[t][0], s[t][1]), fmaxf(s[t][2], s[t][3])));
    }
    tm = fmaxf(tm, __shfl_xor(tm, 16));
    tm = fmaxf(tm, __shfl_xor(tm, 32));
    float nm = fmaxf(m, 0.25f * tm);
    float esc = __expf(m - nm);
    m = nm;
    float ls = 0.f;
    #pragma unroll
    for (int t = 0; t < 8; ++t) {
      float p0 = __expf(0.25f * s[t][0] - nm);
      float p1 = __expf(0.25f * s[t][1] - nm);
      float p2 = __expf(0.25f * s[t][2] - nm);
      float p3 = __expf(0.25f * s[t][3] - nm);
      ls += (p0 + p1) + (p2 + p3);
      unsigned w0 = (unsigned)bf16rne(p0) | ((unsigned)bf16rne(p1) << 16);
      unsigned w1 = (unsigned)bf16rne(p2) | ((unsigned)bf16rne(p3) << 16);
      int kc = t * 16 + g * 4;
      *(unsigned*)&Pl[prow + kc]     = w0;
      *(unsigned*)&Pl[prow + kc + 2] = w1;
    }
    lp = lp * esc + ls;
    float e0 = __shfl(esc, g * 4 + 0);
    float e1 = __shfl(esc, g * 4 + 1);
    float e2 = __shfl(esc, g * 4 + 2);
    float e3 = __shfl(esc, g * 4 + 3);
    o[0] *= e0; o[1] *= e1; o[2] *= e2; o[3] *= e3;
    #pragma unroll
    for (int c = 0; c < 4; ++c) {
      bf16x8 pf = *(const bf16x8*)&Pl[prow + c * 32 + g * 8];
      bf16x8 vf = *(const bf16x8*)&VT[lq * 520 + kbase + c * 32 + g * 8];
      o = MFMA(pf, vf, o);
    }
  }
  lp += __shfl_xor(lp, 16);
  lp += __shfl_xor(lp, 32);
  float linv = 1.f / lp;
  float l0 = __shfl(linv, g * 4 + 0);
  float l1 = __shfl(linv, g * 4 + 1);
  float l2 = __shfl(linv, g * 4 + 2);
  float l3 = __shfl(linv, g * 4 + 3);
  float vv[4] = {o[0] * l0, o[1] * l1, o[2] * l2, o[3] * l3};
  #pragma unroll
  for (int r = 0; r < 4; ++r) {
    int qrow = b * MM + qc * 64 + wid * 16 + g * 4 + r;
    size_t off = (size_t)qrow * DD + h * 16 + lq;
    unsigned short hh, ll;
    hilo(vv[r], hh, ll);
    outh[off] = hh; outl[off] = ll;
  }
}

// ---------------- layernorm over D=128: fp32 out + optional bf16 hi/lo out --------
__global__ void ln_kernel(const float* __restrict__ x, const float* __restrict__ g,
                          const float* __restrict__ bb, float* __restrict__ out,
                          unsigned short* __restrict__ outh,
                          unsigned short* __restrict__ outl) {
  int row = blockIdx.x * 4 + (threadIdx.x >> 6);
  int lane = threadIdx.x & 63;
  float2 xv = *(const float2*)&x[(size_t)row * DD + lane * 2];
  float s = xv.x + xv.y;
  #pragma unroll
  for (int off = 1; off < 64; off <<= 1) s += __shfl_xor(s, off);
  float mu = s * (1.f / 128.f);
  float d0 = xv.x - mu, d1 = xv.y - mu;
  float sq = d0 * d0 + d1 * d1;
  #pragma unroll
  for (int off = 1; off < 64; off <<= 1) sq += __shfl_xor(sq, off);
  float rs = rsqrtf(sq * (1.f / 128.f) + 1e-5f);
  float2 gg = *(const float2*)&g[lane * 2];
  float2 bv = *(const float2*)&bb[lane * 2];
  float2 y;
  y.x = d0 * rs * gg.x + bv.x;
  y.y = d1 * rs * gg.y + bv.y;
  *(float2*)&out[(size_t)row * DD + lane * 2] = y;
  if (outh) {
    unsigned short h0, l0, h1, l1;
    hilo(y.x, h0, l0); hilo(y.y, h1, l1);
    unsigned hh = (unsigned)h0 | ((unsigned)h1 << 16);
    unsigned ll = (unsigned)l0 | ((unsigned)l1 << 16);
    *(unsigned*)&outh[(size_t)row * DD + lane * 2] = hh;
    *(unsigned*)&outl[(size_t)row * DD + lane * 2] = ll;
  }
}

extern "C" void kernel_launch(void* const* d_in, const int* in_sizes, int n_in,
                              void* d_out, int out_size, void* d_ws, size_t ws_size,
                              hipStream_t stream) {
  (void)in_sizes; (void)n_in; (void)out_size; (void)ws_size;
  const float* enc  = (const float*)d_in[0];
  const float* xenc = (const float*)d_in[1];
  const float* gw1  = (const float*)d_in[2];
  const float* gb1  = (const float*)d_in[3];
  const float* gw2  = (const float*)d_in[4];
  const float* gb2  = (const float*)d_in[5];
  const float* Wq   = (const float*)d_in[6];
  const float* Wk   = (const float*)d_in[7];
  const float* Wv   = (const float*)d_in[8];
  const float* Wo   = (const float*)d_in[9];
  const float* ln1g = (const float*)d_in[10];
  const float* ln1b = (const float*)d_in[11];
  const float* W1   = (const float*)d_in[12];
  const float* b1   = (const float*)d_in[13];
  const float* W2   = (const float*)d_in[14];
  const float* b2   = (const float*)d_in[15];
  const float* ln2g = (const float*)d_in[16];
  const float* ln2b = (const float*)d_in[17];
  float* outp = (float*)d_out;

  char* w = (char*)d_ws;
  auto alloc = [&](size_t bytes) -> char* {
    char* p = w;
    w += (bytes + 255) & ~(size_t)255;
    return p;
  };
  float* mu    = (float*)alloc((size_t)NNODE * 4);
  float* rstd  = (float*)alloc((size_t)NNODE * 4);
  float* dinv  = (float*)alloc((size_t)NNODE * 4);
  float* mpart = (float*)alloc((size_t)8 * NNODE * 4);
  int*   nb    = (int*)  alloc((size_t)NEDGE * 4);
  int*   cnt   = (int*)  alloc((size_t)NNODE * 4);
  int*   offs  = (int*)  alloc((size_t)(NNODE + 1) * 4);
  int*   curs  = (int*)  alloc((size_t)NNODE * 4);
  int*   lists = (int*)  alloc((size_t)NEDGE * 4);
  float* gram  = (float*)alloc((size_t)BB * MM * MM * 4);   // 16MB: G0; later Qb16+KV16
  float* gram2 = (float*)alloc((size_t)BB * MM * MM * 4);   // 16MB: G1; later ff hi/lo
  float* bufx  = (float*)alloc((size_t)NNODE * DD * 4);
  float* bufxl = (float*)alloc((size_t)NNODE * DD * 4);
  float* bufh  = (float*)alloc((size_t)NNODE * DD * 4);
  float* bufh1 = (float*)alloc((size_t)NNODE * DD * 4);
  unsigned short* xth  = (unsigned short*)alloc((size_t)BB * MM * LL * 2);  // 16MB
  unsigned short* xtl  = (unsigned short*)alloc((size_t)BB * MM * LL * 2);  // 16MB
  unsigned short* wTh  = (unsigned short*)alloc((size_t)425984 * 2);
  unsigned short* wTl  = (unsigned short*)alloc((size_t)425984 * 2);
  unsigned short* ench = (unsigned short*)alloc((size_t)NNODE * DD * 2);
  unsigned short* encl = (unsigned short*)alloc((size_t)NNODE * DD * 2);
  unsigned short* x1h  = (unsigned short*)alloc((size_t)NNODE * DD * 2);
  unsigned short* x1l  = (unsigned short*)alloc((size_t)NNODE * DD * 2);
  unsigned short* kvbh = (unsigned short*)alloc((size_t)NNODE * DD * 2);
  unsigned short* kvbl = (unsigned short*)alloc((size_t)NNODE * DD * 2);
  unsigned short* xlh  = (unsigned short*)alloc((size_t)NNODE * DD * 2);
  unsigned short* xll  = (unsigned short*)alloc((size_t)NNODE * DD * 2);
  unsigned short* h1h  = (unsigned short*)alloc((size_t)NNODE * DD * 2);
  unsigned short* h1l  = (unsigned short*)alloc((size_t)NNODE * DD * 2);
  unsigned short* sdh  = (unsigned short*)alloc((size_t)NNODE * DD * 2);
  unsigned short* sdl  = (unsigned short*)alloc((size_t)NNODE * DD * 2);

  // Phase aliases (valid after graph-build consumes G0/G1):
  unsigned short* Qb16 = (unsigned short*)gram;                       // 2 MB [NNODE][128]
  unsigned short* KV16 = (unsigned short*)(gram + (size_t)1048576);   // 8 MB [NNODE][512]
  unsigned short* ffh = (unsigned short*)gram2;                         // 8MB
  unsigned short* ffl = (unsigned short*)gram2 + (size_t)NNODE * NDFF;  // 8MB

  const unsigned short* gw1Th = wTh,         *gw1Tl = wTl;
  const unsigned short* gw2Th = wTh + 16384, *gw2Tl = wTl + 16384;
  const unsigned short* KVTh01 = wTh + (size_t)2 * 16384;   // [Wk0;Wv0;Wk1;Wv1] [512][128]
  const unsigned short* KVTl01 = wTl + (size_t)2 * 16384;
  auto WqTh = [&](int l) { return wTh + (size_t)(6 + l) * 16384; };
  auto WqTl = [&](int l) { return wTl + (size_t)(6 + l) * 16384; };
  auto WoTh = [&](int l) { return wTh + (size_t)(8 + l) * 16384; };
  auto WoTl = [&](int l) { return wTl + (size_t)(8 + l) * 16384; };
  auto W1Th = [&](int l) { return wTh + 163840 + (size_t)l * 65536; };
  auto W1Tl = [&](int l) { return wTl + 163840 + (size_t)l * 65536; };
  auto W2Th = [&](int l) { return wTh + 294912 + (size_t)l * 65536; };
  auto W2Tl = [&](int l) { return wTl + 294912 + (size_t)l * 65536; };

  auto gemm = [&](const unsigned short* Ah, const unsigned short* Al,
                  const unsigned short* Bh, const unsigned short* Bl,
                  float* C, unsigned short* Ch, unsigned short* Cl,
                  int Mr, int Ncols, int Ldc, int col0, int Kd,
                  const float* bias, const float* resid, int relu) {
    dim3 g(Ncols / 64, Mr / 64);
    if (Kd == 128) {
      bf_gemm_k128_kernel<<<g, 256, 0, stream>>>(Ah, Al, Bh, Bl, C, Ch, Cl, Ldc, col0,
                                                 bias, resid, relu);
    } else {
      bf_gemm_sk_kernel<<<g, 512, 0, stream>>>(Ah, Al, Bh, Bl, C, Ch, Cl, Ldc, col0, Kd,
                                               bias, resid, relu);
    }
  };

  // ---- transposes & splits ----
  transpose_x_kernel<<<dim3(16, 32, 16), 256, 0, stream>>>(xenc, xth, xtl);
  transpose_w_kernel<<<dim3(16, 16, 14), 256, 0, stream>>>(gw1, gw2, Wq, Wk, Wv, Wo, W1, W2, wTh, wTl);
  split_kernel<<<(NNODE * DD / 4) / 256, 256, 0, stream>>>(enc, ench, encl);

  // ---- graph build ----
  colmean_part_kernel<<<dim3(32, 8), 256, 0, stream>>>(xenc, mpart);
  colmean_finish_kernel<<<NNODE / 256, 256, 0, stream>>>(mpart, mu);
  gram_kernel<<<dim3(36, BB, 2), 256, 0, stream>>>(xth, xtl, gram, gram2);
  rstd_kernel<<<NNODE / 256, 256, 0, stream>>>(gram, gram2, mu, rstd);
  select_kernel<<<NNODE / 4, 256, 0, stream>>>(gram, gram2, mu, rstd, nb);
  hipMemsetAsync(cnt, 0, (size_t)NNODE * 4, stream);
  count_kernel<<<NEDGE / 256, 256, 0, stream>>>(nb, cnt);
  scan_kernel<<<1, 256, 0, stream>>>(cnt, offs, curs, dinv);
  scatter_kernel<<<NEDGE / 256, 256, 0, stream>>>(nb, curs, lists);

  // ---- 2-layer GCN (xw scratch uses bufx) ----
  gemm(ench, encl, gw1Th, gw1Tl, bufx, nullptr, nullptr, NNODE, DD, DD, 0, DD,
       nullptr, nullptr, 0);
  agg_kernel<<<NNODE / 2, 256, 0, stream>>>(bufx, dinv, offs, lists, gb1, x1h, x1l);
  gemm(x1h, x1l, gw2Th, gw2Tl, bufx, nullptr, nullptr, NNODE, DD, DD, 0, DD,
       nullptr, nullptr, 0);
  agg_kernel<<<NNODE / 2, 256, 0, stream>>>(bufx, dinv, offs, lists, gb2, kvbh, kvbl);

  // ---- fused KV projection for BOTH layers -> single bf16 [NNODE][512] ----
  gemm(kvbh, kvbl, KVTh01, KVTl01, nullptr, KV16, nullptr, NNODE, 512, 512, 0, DD,
       nullptr, nullptr, 0);

  // ---- transformer encoder layers ----
  for (int l = 0; l < 2; ++l) {
    const float* hq = (l == 0) ? enc : bufh1;
    const unsigned short* hqh = (l == 0) ? ench : h1h;
    const unsigned short* hql = (l == 0) ? encl : h1l;
    gemm(hqh, hql, WqTh(l), WqTl(l), nullptr, Qb16, nullptr, NNODE, DD, DD, 0, DD,
         nullptr, nullptr, 0);                                         // q bf16
    attn_mfma_kernel<<<BB * HH * 8, 256, 0, stream>>>(Qb16, KV16, l * 256, sdh, sdl);
    gemm(sdh, sdl, WoTh(l), WoTl(l), bufx, nullptr, nullptr, NNODE, DD, DD, 0, DD,
         nullptr, hq, 0);
    ln_kernel<<<NNODE / 4, 256, 0, stream>>>(bufx, ln1g + l * DD, ln1b + l * DD, bufxl, xlh, xll);
    gemm(xlh, xll, W1Th(l), W1Tl(l), nullptr, ffh, ffl, NNODE, NDFF, NDFF, 0, DD,
         b1 + l * NDFF, nullptr, 1);
    gemm(ffh, ffl, W2Th(l), W2Tl(l), bufh, nullptr, nullptr, NNODE, DD, DD, 0, NDFF,
         b2 + l * DD, bufxl, 0);
    if (l == 1) {
      ln_kernel<<<NNODE / 4, 256, 0, stream>>>(bufh, ln2g + l * DD, ln2b + l * DD,
                                               outp, nullptr, nullptr);
    } else {
      ln_kernel<<<NNODE / 4, 256, 0, stream>>>(bufh, ln2g + l * DD, ln2b + l * DD,
                                               bufh1, h1h, h1l);
    }
  }
}

// Round 17
// 390.095 us; speedup vs baseline: 1.0627x; 1.0627x over previous
//
#include <hip/hip_runtime.h>
#include <math.h>

#define BB 16
#define MM 512
#define LL 1024
#define DD 128
#define KK 16
#define HH 8
#define DHH 16
#define NDFF 512
#define NNODE (BB*MM)      // 8192
#define NEDGE (NNODE*KK)   // 131072

typedef __attribute__((ext_vector_type(8))) short bf16x8;
typedef __attribute__((ext_vector_type(4))) float f32x4;
#define MFMA(a,b,c) __builtin_amdgcn_mfma_f32_16x16x32_bf16(a,b,c,0,0,0)

__device__ inline unsigned short bf16rne(float x) {
  union { float f; unsigned u; } v; v.f = x;
  return (unsigned short)((v.u + 0x7FFFu + ((v.u >> 16) & 1u)) >> 16);
}
__device__ inline float bf16tof(unsigned short h) {
  union { unsigned u; float f; } v; v.u = ((unsigned)h) << 16; return v.f;
}
__device__ inline void hilo(float x, unsigned short& h, unsigned short& l) {
  h = bf16rne(x);
  l = bf16rne(x - bf16tof(h));
}

// async global->LDS, 16B per lane (linear dest = wave-uniform base + lane*16)
__device__ inline void async16(const void* g, void* l) {
  __builtin_amdgcn_global_load_lds(
      (const __attribute__((address_space(1))) unsigned int*)g,
      (__attribute__((address_space(3))) unsigned int*)l, 16, 0, 0);
}

// ---------------- transpose x_enc [b][l][m] -> chunked k-major bf16 hi/lo ----------
__global__ __launch_bounds__(256) void transpose_x_kernel(const float* __restrict__ X,
                                                          unsigned short* __restrict__ XTh,
                                                          unsigned short* __restrict__ XTl) {
  __shared__ float t[32][33];
  int b = blockIdx.z;
  int m0 = blockIdx.x * 32, l0 = blockIdx.y * 32;
  int c = threadIdx.x & 31, r = threadIdx.x >> 5;   // r 0..7
  const float* Xb = X + (size_t)b * LL * MM;
  #pragma unroll
  for (int i = 0; i < 4; ++i)
    t[r + i*8][c] = Xb[(size_t)(l0 + r + i*8) * MM + m0 + c];
  __syncthreads();
  int R = m0 >> 6;
  int rbase = m0 & 63;
  size_t base = ((size_t)(b * 8 + R)) * 65536 + (size_t)(l0 >> 5) * 2048
              + (size_t)(c >> 3) * 512 + (c & 7);
  #pragma unroll
  for (int i = 0; i < 4; ++i) {
    unsigned short h, l;
    hilo(t[c][r + i*8], h, l);
    size_t idx = base + (size_t)(rbase + r + i*8) * 8;
    XTh[idx] = h; XTl[idx] = l;
  }
}

// ---------------- transpose weights [K][N] -> bf16 hi/lo [N][K] ----------------
__global__ __launch_bounds__(256) void transpose_w_kernel(
    const float* __restrict__ gw1, const float* __restrict__ gw2,
    const float* __restrict__ Wq, const float* __restrict__ Wk,
    const float* __restrict__ Wv, const float* __restrict__ Wo,
    const float* __restrict__ W1, const float* __restrict__ W2,
    unsigned short* __restrict__ wTh, unsigned short* __restrict__ wTl) {
  int z = blockIdx.z;
  const float* src; int K, N; size_t doff;
  if (z < 10) {
    K = 128; N = 128;
    switch (z) {
      case 0: src = gw1;         doff = 0;         break;
      case 1: src = gw2;         doff = 16384;     break;
      case 2: src = Wk;          doff = 2*16384;   break;
      case 3: src = Wv;          doff = 3*16384;   break;
      case 4: src = Wk + 16384;  doff = 4*16384;   break;
      case 5: src = Wv + 16384;  doff = 5*16384;   break;
      case 6: src = Wq;          doff = 6*16384;   break;
      case 7: src = Wq + 16384;  doff = 7*16384;   break;
      case 8: src = Wo;          doff = 8*16384;   break;
      default: src = Wo + 16384; doff = 9*16384;   break;
    }
  } else if (z < 12) {
    K = 128; N = 512; doff = 163840 + (size_t)(z - 10) * 65536;
    src = W1 + (size_t)(z - 10) * 65536;
  } else {
    K = 512; N = 128; doff = 294912 + (size_t)(z - 12) * 65536;
    src = W2 + (size_t)(z - 12) * 65536;
  }
  int k0 = blockIdx.x * 32, n0 = blockIdx.y * 32;
  if (k0 >= K || n0 >= N) return;
  __shared__ float t[32][33];
  int c = threadIdx.x & 31, r = threadIdx.x >> 5;
  #pragma unroll
  for (int i = 0; i < 4; ++i)
    t[r + i*8][c] = src[(size_t)(k0 + r + i*8) * N + n0 + c];
  __syncthreads();
  #pragma unroll
  for (int i = 0; i < 4; ++i) {
    size_t idx = doff + (size_t)(n0 + r + i*8) * K + k0 + c;
    unsigned short h, l;
    hilo(t[c][r + i*8], h, l);
    wTh[idx] = h; wTl[idx] = l;
  }
}

// ---------------- plain fp32 -> bf16 hi/lo split (for enc) ----------------
__global__ void split_kernel(const float* __restrict__ in,
                             unsigned short* __restrict__ h,
                             unsigned short* __restrict__ l) {
  int i = blockIdx.x * 256 + threadIdx.x;     // per float4
  float4 v = ((const float4*)in)[i];
  unsigned short h0,h1,h2,h3,l0,l1,l2,l3;
  hilo(v.x,h0,l0); hilo(v.y,h1,l1); hilo(v.z,h2,l2); hilo(v.w,h3,l3);
  uint2 hh, ll;
  hh.x = (unsigned)h0 | ((unsigned)h1 << 16); hh.y = (unsigned)h2 | ((unsigned)h3 << 16);
  ll.x = (unsigned)l0 | ((unsigned)l1 << 16); ll.y = (unsigned)l2 | ((unsigned)l3 << 16);
  ((uint2*)h)[i] = hh; ((uint2*)l)[i] = ll;
}

// ---------------- column means (original layout) ----------------
__global__ void colmean_part_kernel(const float* __restrict__ X, float* __restrict__ part) {
  int bm = blockIdx.x * 256 + threadIdx.x;
  int b = bm >> 9, m = bm & (MM - 1);
  int l0 = blockIdx.y * 128;
  const float* p = X + (size_t)b * LL * MM + (size_t)l0 * MM + m;
  float s = 0.f;
  #pragma unroll 8
  for (int l = 0; l < 128; ++l) s += p[(size_t)l * MM];
  part[(size_t)blockIdx.y * NNODE + bm] = s;
}

__global__ void colmean_finish_kernel(const float* __restrict__ part, float* __restrict__ mu) {
  int bm = blockIdx.x * 256 + threadIdx.x;
  float s = 0.f;
  #pragma unroll
  for (int j = 0; j < 8; ++j) s += part[(size_t)j * NNODE + bm];
  mu[bm] = s * (1.f / 1024.f);
}

// ---------------- MFMA gram, LDS-staged via global_load_lds, z-split partials -----
__global__ __launch_bounds__(256) void gram_kernel(const unsigned short* __restrict__ XTh,
                                                   const unsigned short* __restrict__ XTl,
                                                   float* __restrict__ G0,
                                                   float* __restrict__ G1) {
  __shared__ unsigned short lAh[2048], lAl[2048], lBh[2048], lBl[2048];
  int b = blockIdx.y, z = blockIdx.z;
  int pi = blockIdx.x;
  int ti = 0, rem = pi;
  while (rem >= 8 - ti) { rem -= 8 - ti; ++ti; }
  int tj = ti + rem;
  int tid = threadIdx.x;
  int wid = tid >> 6, lane = tid & 63;
  int wr = wid >> 1, wc = wid & 1;
  int fr = lane & 15, fkb = lane >> 4;
  size_t abase = ((size_t)(b * 8 + ti)) * 65536 + (size_t)z * 16 * 2048;
  size_t bbase = ((size_t)(b * 8 + tj)) * 65536 + (size_t)z * 16 * 2048;
  int toff = tid * 8;
  int aoff0 = fkb * 512 + (wr*32 + fr) * 8;
  int aoff1 = aoff0 + 128;
  int boff0 = fkb * 512 + (wc*32 + fr) * 8;
  int boff1 = boff0 + 128;
  f32x4 acc00 = {0,0,0,0}, acc01 = {0,0,0,0}, acc10 = {0,0,0,0}, acc11 = {0,0,0,0};
  for (int s = 0; s < 16; ++s) {
    size_t ao = abase + (size_t)s * 2048 + toff;
    size_t bo = bbase + (size_t)s * 2048 + toff;
    async16(XTh + ao, lAh + toff);
    async16(XTl + ao, lAl + toff);
    async16(XTh + bo, lBh + toff);
    async16(XTl + bo, lBl + toff);
    __syncthreads();
    bf16x8 a0h = *(const bf16x8*)(lAh + aoff0);
    bf16x8 a1h = *(const bf16x8*)(lAh + aoff1);
    bf16x8 a0l = *(const bf16x8*)(lAl + aoff0);
    bf16x8 a1l = *(const bf16x8*)(lAl + aoff1);
    bf16x8 b0h = *(const bf16x8*)(lBh + boff0);
    bf16x8 b1h = *(const bf16x8*)(lBh + boff1);
    bf16x8 b0l = *(const bf16x8*)(lBl + boff0);
    bf16x8 b1l = *(const bf16x8*)(lBl + boff1);
    acc00 = MFMA(a0h, b0h, acc00); acc00 = MFMA(a0h, b0l, acc00); acc00 = MFMA(a0l, b0h, acc00);
    acc01 = MFMA(a0h, b1h, acc01); acc01 = MFMA(a0h, b1l, acc01); acc01 = MFMA(a0l, b1h, acc01);
    acc10 = MFMA(a1h, b0h, acc10); acc10 = MFMA(a1h, b0l, acc10); acc10 = MFMA(a1l, b0h, acc10);
    acc11 = MFMA(a1h, b1h, acc11); acc11 = MFMA(a1h, b1l, acc11); acc11 = MFMA(a1l, b1h, acc11);
    __syncthreads();
  }
  int m0 = ti * 64, n0 = tj * 64;
  float* G = (z ? G1 : G0) + (size_t)b * MM * MM;
  int mirror = (ti != tj);
  #pragma unroll
  for (int i = 0; i < 2; ++i) {
    #pragma unroll
    for (int j = 0; j < 2; ++j) {
      const f32x4& a = (i == 0) ? (j == 0 ? acc00 : acc01) : (j == 0 ? acc10 : acc11);
      #pragma unroll
      for (int r = 0; r < 4; ++r) {
        int row = m0 + wr*32 + i*16 + (lane >> 4)*4 + r;
        int col = n0 + wc*32 + j*16 + (lane & 15);
        float v = a[r];
        G[(size_t)row * MM + col] = v;
        if (mirror) G[(size_t)col * MM + row] = v;
      }
    }
  }
}

// ---------------- MFMA GEMM, K=128 fully unrolled: all 32 frags loaded up front ---
// Epilogue: fp32 C, bf16 hi/lo (Ch+Cl), or single bf16 (Ch only, Cl==null).
__global__ __launch_bounds__(256) void bf_gemm_k128_kernel(
    const unsigned short* __restrict__ Ah, const unsigned short* __restrict__ Al,
    const unsigned short* __restrict__ Bh, const unsigned short* __restrict__ Bl,
    float* __restrict__ C, unsigned short* __restrict__ Ch, unsigned short* __restrict__ Cl,
    int Ldc, int col0, const float* __restrict__ bias,
    const float* __restrict__ resid, int relu) {
  int tid = threadIdx.x;
  int m0 = blockIdx.y * 64, n0 = blockIdx.x * 64;
  int wid = tid >> 6, lane = tid & 63;
  int wr = wid >> 1, wc = wid & 1;
  int fr = lane & 15, fkb = lane >> 4;
  size_t arow0 = (size_t)(m0 + wr*32 + fr) * 128;
  size_t arow1 = arow0 + 16 * 128;
  size_t brow0 = (size_t)(n0 + wc*32 + fr) * 128;
  size_t brow1 = brow0 + 16 * 128;
  bf16x8 fa0h[4], fa1h[4], fa0l[4], fa1l[4];
  bf16x8 fb0h[4], fb1h[4], fb0l[4], fb1l[4];
  #pragma unroll
  for (int ks = 0; ks < 4; ++ks) {
    int ko = ks * 32 + fkb * 8;
    fa0h[ks] = *(const bf16x8*)(Ah + arow0 + ko);
    fa1h[ks] = *(const bf16x8*)(Ah + arow1 + ko);
    fa0l[ks] = *(const bf16x8*)(Al + arow0 + ko);
    fa1l[ks] = *(const bf16x8*)(Al + arow1 + ko);
    fb0h[ks] = *(const bf16x8*)(Bh + brow0 + ko);
    fb1h[ks] = *(const bf16x8*)(Bh + brow1 + ko);
    fb0l[ks] = *(const bf16x8*)(Bl + brow0 + ko);
    fb1l[ks] = *(const bf16x8*)(Bl + brow1 + ko);
  }
  f32x4 acc00 = {0,0,0,0}, acc01 = {0,0,0,0}, acc10 = {0,0,0,0}, acc11 = {0,0,0,0};
  #pragma unroll
  for (int ks = 0; ks < 4; ++ks) {
    acc00 = MFMA(fa0h[ks], fb0h[ks], acc00);
    acc00 = MFMA(fa0h[ks], fb0l[ks], acc00);
    acc00 = MFMA(fa0l[ks], fb0h[ks], acc00);
    acc01 = MFMA(fa0h[ks], fb1h[ks], acc01);
    acc01 = MFMA(fa0h[ks], fb1l[ks], acc01);
    acc01 = MFMA(fa0l[ks], fb1h[ks], acc01);
    acc10 = MFMA(fa1h[ks], fb0h[ks], acc10);
    acc10 = MFMA(fa1h[ks], fb0l[ks], acc10);
    acc10 = MFMA(fa1l[ks], fb0h[ks], acc10);
    acc11 = MFMA(fa1h[ks], fb1h[ks], acc11);
    acc11 = MFMA(fa1h[ks], fb1l[ks], acc11);
    acc11 = MFMA(fa1l[ks], fb1h[ks], acc11);
  }
  #pragma unroll
  for (int i = 0; i < 2; ++i) {
    #pragma unroll
    for (int j = 0; j < 2; ++j) {
      const f32x4& a = (i == 0) ? (j == 0 ? acc00 : acc01) : (j == 0 ? acc10 : acc11);
      #pragma unroll
      for (int r = 0; r < 4; ++r) {
        int row = m0 + wr*32 + i*16 + (lane >> 4)*4 + r;
        int col = col0 + n0 + wc*32 + j*16 + (lane & 15);
        float v = a[r];
        if (bias)  v += bias[col - col0];
        if (resid) v += resid[(size_t)row * Ldc + col];
        if (relu)  v = fmaxf(v, 0.f);
        size_t o = (size_t)row * Ldc + col;
        if (C) C[o] = v;
        if (Ch) {
          if (Cl) {
            unsigned short hh, ll;
            hilo(v, hh, ll);
            Ch[o] = hh; Cl[o] = ll;
          } else {
            Ch[o] = bf16rne(v);
          }
        }
      }
    }
  }
}

// ---------------- MFMA GEMM 64x64 tile, 8 waves, in-block split-K2 (K=512) --------
__global__ __launch_bounds__(512) void bf_gemm_sk_kernel(
    const unsigned short* __restrict__ Ah, const unsigned short* __restrict__ Al,
    const unsigned short* __restrict__ Bh, const unsigned short* __restrict__ Bl,
    float* __restrict__ C, unsigned short* __restrict__ Ch, unsigned short* __restrict__ Cl,
    int Ldc, int col0, int Kd, const float* __restrict__ bias,
    const float* __restrict__ resid, int relu) {
  __shared__ float red[64][65];
  int tid = threadIdx.x;
  int m0 = blockIdx.y * 64, n0 = blockIdx.x * 64;
  int wid = tid >> 6, lane = tid & 63;
  int kg = wid >> 2;
  int w4 = wid & 3;
  int wr = w4 >> 1, wc = w4 & 1;
  int fr = lane & 15, fkb = lane >> 4;
  int Kh = Kd >> 1;
  size_t arow0 = (size_t)(m0 + wr*32 + fr) * Kd + (size_t)kg * Kh;
  size_t arow1 = arow0 + (size_t)16 * Kd;
  size_t brow0 = (size_t)(n0 + wc*32 + fr) * Kd + (size_t)kg * Kh;
  size_t brow1 = brow0 + (size_t)16 * Kd;
  f32x4 acc00 = {0,0,0,0}, acc01 = {0,0,0,0}, acc10 = {0,0,0,0}, acc11 = {0,0,0,0};
  int ko = fkb * 8;
  bf16x8 a0h = *(const bf16x8*)(Ah + arow0 + ko);
  bf16x8 a1h = *(const bf16x8*)(Ah + arow1 + ko);
  bf16x8 a0l = *(const bf16x8*)(Al + arow0 + ko);
  bf16x8 a1l = *(const bf16x8*)(Al + arow1 + ko);
  bf16x8 b0h = *(const bf16x8*)(Bh + brow0 + ko);
  bf16x8 b1h = *(const bf16x8*)(Bh + brow1 + ko);
  bf16x8 b0l = *(const bf16x8*)(Bl + brow0 + ko);
  bf16x8 b1l = *(const bf16x8*)(Bl + brow1 + ko);
  for (int k0 = 32; k0 < Kh; k0 += 32) {
    int kn = k0 + fkb * 8;
    bf16x8 na0h = *(const bf16x8*)(Ah + arow0 + kn);
    bf16x8 na1h = *(const bf16x8*)(Ah + arow1 + kn);
    bf16x8 na0l = *(const bf16x8*)(Al + arow0 + kn);
    bf16x8 na1l = *(const bf16x8*)(Al + arow1 + kn);
    bf16x8 nb0h = *(const bf16x8*)(Bh + brow0 + kn);
    bf16x8 nb1h = *(const bf16x8*)(Bh + brow1 + kn);
    bf16x8 nb0l = *(const bf16x8*)(Bl + brow0 + kn);
    bf16x8 nb1l = *(const bf16x8*)(Bl + brow1 + kn);
    acc00 = MFMA(a0h, b0h, acc00); acc00 = MFMA(a0h, b0l, acc00); acc00 = MFMA(a0l, b0h, acc00);
    acc01 = MFMA(a0h, b1h, acc01); acc01 = MFMA(a0h, b1l, acc01); acc01 = MFMA(a0l, b1h, acc01);
    acc10 = MFMA(a1h, b0h, acc10); acc10 = MFMA(a1h, b0l, acc10); acc10 = MFMA(a1l, b0h, acc10);
    acc11 = MFMA(a1h, b1h, acc11); acc11 = MFMA(a1h, b1l, acc11); acc11 = MFMA(a1l, b1h, acc11);
    a0h = na0h; a1h = na1h; a0l = na0l; a1l = na1l;
    b0h = nb0h; b1h = nb1h; b0l = nb0l; b1l = nb1l;
  }
  acc00 = MFMA(a0h, b0h, acc00); acc00 = MFMA(a0h, b0l, acc00); acc00 = MFMA(a0l, b0h, acc00);
  acc01 = MFMA(a0h, b1h, acc01); acc01 = MFMA(a0h, b1l, acc01); acc01 = MFMA(a0l, b1h, acc01);
  acc10 = MFMA(a1h, b0h, acc10); acc10 = MFMA(a1h, b0l, acc10); acc10 = MFMA(a1l, b0h, acc10);
  acc11 = MFMA(a1h, b1h, acc11); acc11 = MFMA(a1h, b1l, acc11); acc11 = MFMA(a1l, b1h, acc11);
  if (kg == 1) {
    #pragma unroll
    for (int i = 0; i < 2; ++i) {
      #pragma unroll
      for (int j = 0; j < 2; ++j) {
        const f32x4& a = (i == 0) ? (j == 0 ? acc00 : acc01) : (j == 0 ? acc10 : acc11);
        #pragma unroll
        for (int r = 0; r < 4; ++r) {
          int lr = wr*32 + i*16 + (lane >> 4)*4 + r;
          int lc = wc*32 + j*16 + (lane & 15);
          red[lr][lc] = a[r];
        }
      }
    }
  }
  __syncthreads();
  if (kg == 0) {
    #pragma unroll
    for (int i = 0; i < 2; ++i) {
      #pragma unroll
      for (int j = 0; j < 2; ++j) {
        const f32x4& a = (i == 0) ? (j == 0 ? acc00 : acc01) : (j == 0 ? acc10 : acc11);
        #pragma unroll
        for (int r = 0; r < 4; ++r) {
          int lr = wr*32 + i*16 + (lane >> 4)*4 + r;
          int lc = wc*32 + j*16 + (lane & 15);
          int row = m0 + lr;
          int col = col0 + n0 + lc;
          float v = a[r] + red[lr][lc];
          if (bias)  v += bias[col - col0];
          if (resid) v += resid[(size_t)row * Ldc + col];
          if (relu)  v = fmaxf(v, 0.f);
          size_t o = (size_t)row * Ldc + col;
          if (C) C[o] = v;
          if (Ch) {
            unsigned short hh, ll;
            hilo(v, hh, ll);
            Ch[o] = hh; Cl[o] = ll;
          }
        }
      }
    }
  }
}

// ---------------- rstd[b,m] = 1/std (std==0 -> 1) ----------------
__global__ void rstd_kernel(const float* __restrict__ G0, const float* __restrict__ G1,
                            const float* __restrict__ mu, float* __restrict__ rstd) {
  int bm = blockIdx.x * 256 + threadIdx.x;
  int b = bm >> 9, m = bm & (MM - 1);
  size_t di = (size_t)b * MM * MM + (size_t)m * MM + m;
  float g = G0[di] + G1[di];
  float mm = mu[bm];
  float cov = (g - 1024.f * mm * mm) * (1.f / 1023.f);
  float sd = sqrtf(fmaxf(cov, 0.f));
  rstd[bm] = (sd == 0.f) ? 1.f : (1.f / sd);
}

// ---------------- neighbors: ascending stable argsort positions 1..16 ----------------
__global__ void select_kernel(const float* __restrict__ G0, const float* __restrict__ G1,
                              const float* __restrict__ mu,
                              const float* __restrict__ rstd, int* __restrict__ nb) {
  int w = threadIdx.x >> 6, lane = threadIdx.x & 63;
  int bm = blockIdx.x * 4 + w;
  int b = bm >> 9, m = bm & (MM - 1);
  size_t rowoff = (size_t)b * MM * MM + (size_t)m * MM;
  const float* Gr0 = G0 + rowoff;
  const float* Gr1 = G1 + rowoff;
  const float* mub = mu + b * MM;
  const float* rsb = rstd + b * MM;
  float mm = mub[m], rm = rsb[m];
  float vals[8];
  int excl = 0;
  #pragma unroll
  for (int j = 0; j < 8; ++j) {
    int n = lane + j * 64;
    float cov = ((Gr0[n] + Gr1[n]) - 1024.f * mm * mub[n]) * (1.f / 1023.f);
    vals[j] = cov * rm * rsb[n];
  }
  int* out = nb + (size_t)bm * KK;
  for (int it = 0; it < KK + 1; ++it) {
    float bv = 1e30f; int bi = 1 << 30;
    #pragma unroll
    for (int j = 0; j < 8; ++j) {
      if (!((excl >> j) & 1)) {
        int n = lane + j * 64;
        if (vals[j] < bv) { bv = vals[j]; bi = n; }
      }
    }
    for (int off = 32; off; off >>= 1) {
      float v2 = __shfl_down(bv, off);
      int   i2 = __shfl_down(bi, off);
      if (v2 < bv || (v2 == bv && i2 < bi)) { bv = v2; bi = i2; }
    }
    bi = __shfl(bi, 0);
    if ((bi & 63) == lane) excl |= 1 << (bi >> 6);
    if (it > 0 && lane == 0) out[it - 1] = bi;
  }
}

// ---------------- degree counts ----------------
__global__ void count_kernel(const int* __restrict__ nb, int* __restrict__ cnt) {
  int e = blockIdx.x * 256 + threadIdx.x;
  int b = e >> 13, i = e & 8191;
  int dst = b * MM + nb[(size_t)b * 8192 + i];
  atomicAdd(&cnt[dst], 1);
}

// ---------------- scan + cursor + dinv ----------------
__global__ void scan_kernel(const int* __restrict__ cnt, int* __restrict__ offs,
                            int* __restrict__ curs, float* __restrict__ dinv) {
  __shared__ int part[256];
  int tid = threadIdx.x;
  int base = tid * 32;
  int local[32];
  int s = 0;
  #pragma unroll
  for (int i = 0; i < 32; ++i) { local[i] = cnt[base + i]; s += local[i]; }
  part[tid] = s;
  __syncthreads();
  for (int off = 1; off < 256; off <<= 1) {
    int v = (tid >= off) ? part[tid - off] : 0;
    __syncthreads();
    part[tid] += v;
    __syncthreads();
  }
  int run = part[tid] - s;
  #pragma unroll
  for (int i = 0; i < 32; ++i) {
    int n = base + i;
    offs[n] = run; curs[n] = run;
    run += local[i];
    dinv[n] = rsqrtf((float)(local[i] + 1));
  }
  if (tid == 255) offs[NNODE] = run;
}

// ---------------- scatter reverse edge lists ----------------
__global__ void scatter_kernel(const int* __restrict__ nb, int* __restrict__ curs,
                               int* __restrict__ lists) {
  int e = blockIdx.x * 256 + threadIdx.x;
  int b = e >> 13, i = e & 8191;
  int dst = b * MM + nb[(size_t)b * 8192 + i];
  int src = b * MM + (i & (MM - 1));
  int pos = atomicAdd(&curs[dst], 1);
  lists[pos] = src;
}

// ---------------- GCN aggregation: fp32 gather in, bf16 hi/lo out ----------------
__global__ void agg_kernel(const float* __restrict__ xw, const float* __restrict__ dinv,
                           const int* __restrict__ offs, const int* __restrict__ lists,
                           const float* __restrict__ bias,
                           unsigned short* __restrict__ outh,
                           unsigned short* __restrict__ outl) {
  int n = blockIdx.x * 2 + (threadIdx.x >> 7);
  int c = threadIdx.x & 127;
  float dn = dinv[n];
  float s = dn * xw[(size_t)n * DD + c];
  int e0 = offs[n], e1 = offs[n + 1];
  for (int e = e0; e < e1; ++e) {
    int src = lists[e];
    s += dinv[src] * xw[(size_t)src * DD + c];
  }
  float v = fmaxf(dn * s + bias[c], 0.f);
  unsigned short hh, ll;
  hilo(v, hh, ll);
  size_t o = (size_t)n * DD + c;
  outh[o] = hh; outl[o] = ll;
}

// ---------------- MFMA flash attention ----------------
__global__ __launch_bounds__(256) void attn_mfma_kernel(
    const unsigned short* __restrict__ Qb16, const unsigned short* __restrict__ KV16,
    int kvoff,
    unsigned short* __restrict__ outh, unsigned short* __restrict__ outl) {
  __shared__ unsigned short Kl[512 * 16];     // [key][16d], row 32B
  __shared__ unsigned short VT[16 * 520];     // [d][520 keys], row 1040B
  __shared__ unsigned short Pl[64 * 136];     // [q][136 keys], row 272B
  int bx = blockIdx.x;
  int qc = bx & 7;
  int h  = (bx >> 3) & 7;
  int b  = bx >> 6;
  int tid = threadIdx.x;

  for (int u = tid; u < 1024; u += 256) {
    int row = u >> 1, half = u & 1;
    const unsigned short* src = KV16 + (size_t)(b * MM + row) * 512 + kvoff + h * 16 + half * 8;
    *(uint4*)&Kl[row * 16 + half * 8] = *(const uint4*)src;
  }
  for (int key = tid; key < 512; key += 256) {
    const unsigned short* src = KV16 + (size_t)(b * MM + key) * 512 + kvoff + 128 + h * 16;
    unsigned short tmp[16];
    *(uint4*)&tmp[0] = *(const uint4*)src;
    *(uint4*)&tmp[8] = *(const uint4*)(src + 8);
    #pragma unroll
    for (int d = 0; d < 16; ++d) VT[d * 520 + key] = tmp[d];
  }
  __syncthreads();

  int wid = tid >> 6, lane = tid & 63;
  int lq = lane & 15, g = lane >> 4;
  bf16x8 zz = {0,0,0,0,0,0,0,0};
  bf16x8 qf = zz;
  if (lane < 32) {
    int qrow = b * MM + qc * 64 + wid * 16 + lq;
    qf = *(const bf16x8*)(Qb16 + (size_t)qrow * 128 + h * 16 + g * 8);
  }
  float m = -1e30f, lp = 0.f;
  f32x4 o = {0,0,0,0};
  int prow = (wid * 16 + lq) * 136;

  for (int c4 = 0; c4 < 4; ++c4) {
    int kbase = c4 * 128;
    f32x4 s[8];
    f32x4 zc = {0,0,0,0};
    #pragma unroll
    for (int t = 0; t < 8; ++t) {
      bf16x8 kf = zz;
      if (lane < 32) kf = *(const bf16x8*)&Kl[(kbase + t * 16 + lq) * 16 + g * 8];
      s[t] = MFMA(kf, qf, zc);
    }
    float tm = -1e30f;
    #pragma unroll
    for (int t = 0; t < 8; ++t) {
      tm = fmaxf(tm, fmaxf(fmaxf(s[t][0], s[t][1]), fmaxf(s[t][2], s[t][3])));
    }
    tm = fmaxf(tm, __shfl_xor(tm, 16));
    tm = fmaxf(tm, __shfl_xor(tm, 32));
    float nm = fmaxf(m, 0.25f * tm);
    float esc = __expf(m - nm);
    m = nm;
    float ls = 0.f;
    #pragma unroll
    for (int t = 0; t < 8; ++t) {
      float p0 = __expf(0.25f * s[t][0] - nm);
      float p1 = __expf(0.25f * s[t][1] - nm);
      float p2 = __expf(0.25f * s[t][2] - nm);
      float p3 = __expf(0.25f * s[t][3] - nm);
      ls += (p0 + p1) + (p2 + p3);
      unsigned w0 = (unsigned)bf16rne(p0) | ((unsigned)bf16rne(p1) << 16);
      unsigned w1 = (unsigned)bf16rne(p2) | ((unsigned)bf16rne(p3) << 16);
      int kc = t * 16 + g * 4;
      *(unsigned*)&Pl[prow + kc]     = w0;
      *(unsigned*)&Pl[prow + kc + 2] = w1;
    }
    lp = lp * esc + ls;
    float e0 = __shfl(esc, g * 4 + 0);
    float e1 = __shfl(esc, g * 4 + 1);
    float e2 = __shfl(esc, g * 4 + 2);
    float e3 = __shfl(esc, g * 4 + 3);
    o[0] *= e0; o[1] *= e1; o[2] *= e2; o[3] *= e3;
    #pragma unroll
    for (int c = 0; c < 4; ++c) {
      bf16x8 pf = *(const bf16x8*)&Pl[prow + c * 32 + g * 8];
      bf16x8 vf = *(const bf16x8*)&VT[lq * 520 + kbase + c * 32 + g * 8];
      o = MFMA(pf, vf, o);
    }
  }
  lp += __shfl_xor(lp, 16);
  lp += __shfl_xor(lp, 32);
  float linv = 1.f / lp;
  float l0 = __shfl(linv, g * 4 + 0);
  float l1 = __shfl(linv, g * 4 + 1);
  float l2 = __shfl(linv, g * 4 + 2);
  float l3 = __shfl(linv, g * 4 + 3);
  float vv[4] = {o[0] * l0, o[1] * l1, o[2] * l2, o[3] * l3};
  #pragma unroll
  for (int r = 0; r < 4; ++r) {
    int qrow = b * MM + qc * 64 + wid * 16 + g * 4 + r;
    size_t off = (size_t)qrow * DD + h * 16 + lq;
    unsigned short hh, ll;
    hilo(vv[r], hh, ll);
    outh[off] = hh; outl[off] = ll;
  }
}

// ---------------- layernorm over D=128: fp32 out + optional bf16 hi/lo out --------
__global__ void ln_kernel(const float* __restrict__ x, const float* __restrict__ g,
                          const float* __restrict__ bb, float* __restrict__ out,
                          unsigned short* __restrict__ outh,
                          unsigned short* __restrict__ outl) {
  int row = blockIdx.x * 4 + (threadIdx.x >> 6);
  int lane = threadIdx.x & 63;
  float2 xv = *(const float2*)&x[(size_t)row * DD + lane * 2];
  float s = xv.x + xv.y;
  #pragma unroll
  for (int off = 1; off < 64; off <<= 1) s += __shfl_xor(s, off);
  float mu = s * (1.f / 128.f);
  float d0 = xv.x - mu, d1 = xv.y - mu;
  float sq = d0 * d0 + d1 * d1;
  #pragma unroll
  for (int off = 1; off < 64; off <<= 1) sq += __shfl_xor(sq, off);
  float rs = rsqrtf(sq * (1.f / 128.f) + 1e-5f);
  float2 gg = *(const float2*)&g[lane * 2];
  float2 bv = *(const float2*)&bb[lane * 2];
  float2 y;
  y.x = d0 * rs * gg.x + bv.x;
  y.y = d1 * rs * gg.y + bv.y;
  *(float2*)&out[(size_t)row * DD + lane * 2] = y;
  if (outh) {
    unsigned short h0, l0, h1, l1;
    hilo(y.x, h0, l0); hilo(y.y, h1, l1);
    unsigned hh = (unsigned)h0 | ((unsigned)h1 << 16);
    unsigned ll = (unsigned)l0 | ((unsigned)l1 << 16);
    *(unsigned*)&outh[(size_t)row * DD + lane * 2] = hh;
    *(unsigned*)&outl[(size_t)row * DD + lane * 2] = ll;
  }
}

extern "C" void kernel_launch(void* const* d_in, const int* in_sizes, int n_in,
                              void* d_out, int out_size, void* d_ws, size_t ws_size,
                              hipStream_t stream) {
  (void)in_sizes; (void)n_in; (void)out_size; (void)ws_size;
  const float* enc  = (const float*)d_in[0];
  const float* xenc = (const float*)d_in[1];
  const float* gw1  = (const float*)d_in[2];
  const float* gb1  = (const float*)d_in[3];
  const float* gw2  = (const float*)d_in[4];
  const float* gb2  = (const float*)d_in[5];
  const float* Wq   = (const float*)d_in[6];
  const float* Wk   = (const float*)d_in[7];
  const float* Wv   = (const float*)d_in[8];
  const float* Wo   = (const float*)d_in[9];
  const float* ln1g = (const float*)d_in[10];
  const float* ln1b = (const float*)d_in[11];
  const float* W1   = (const float*)d_in[12];
  const float* b1   = (const float*)d_in[13];
  const float* W2   = (const float*)d_in[14];
  const float* b2   = (const float*)d_in[15];
  const float* ln2g = (const float*)d_in[16];
  const float* ln2b = (const float*)d_in[17];
  float* outp = (float*)d_out;

  char* w = (char*)d_ws;
  auto alloc = [&](size_t bytes) -> char* {
    char* p = w;
    w += (bytes + 255) & ~(size_t)255;
    return p;
  };
  float* mu    = (float*)alloc((size_t)NNODE * 4);
  float* rstd  = (float*)alloc((size_t)NNODE * 4);
  float* dinv  = (float*)alloc((size_t)NNODE * 4);
  float* mpart = (float*)alloc((size_t)8 * NNODE * 4);
  int*   nb    = (int*)  alloc((size_t)NEDGE * 4);
  int*   cnt   = (int*)  alloc((size_t)NNODE * 4);
  int*   offs  = (int*)  alloc((size_t)(NNODE + 1) * 4);
  int*   curs  = (int*)  alloc((size_t)NNODE * 4);
  int*   lists = (int*)  alloc((size_t)NEDGE * 4);
  float* gram  = (float*)alloc((size_t)BB * MM * MM * 4);   // 16MB: G0; later Qb16+KV16
  float* gram2 = (float*)alloc((size_t)BB * MM * MM * 4);   // 16MB: G1; later ff hi/lo
  float* bufx  = (float*)alloc((size_t)NNODE * DD * 4);
  float* bufxl = (float*)alloc((size_t)NNODE * DD * 4);
  float* bufh  = (float*)alloc((size_t)NNODE * DD * 4);
  float* bufh1 = (float*)alloc((size_t)NNODE * DD * 4);
  unsigned short* xth  = (unsigned short*)alloc((size_t)BB * MM * LL * 2);  // 16MB
  unsigned short* xtl  = (unsigned short*)alloc((size_t)BB * MM * LL * 2);  // 16MB
  unsigned short* wTh  = (unsigned short*)alloc((size_t)425984 * 2);
  unsigned short* wTl  = (unsigned short*)alloc((size_t)425984 * 2);
  unsigned short* ench = (unsigned short*)alloc((size_t)NNODE * DD * 2);
  unsigned short* encl = (unsigned short*)alloc((size_t)NNODE * DD * 2);
  unsigned short* x1h  = (unsigned short*)alloc((size_t)NNODE * DD * 2);
  unsigned short* x1l  = (unsigned short*)alloc((size_t)NNODE * DD * 2);
  unsigned short* kvbh = (unsigned short*)alloc((size_t)NNODE * DD * 2);
  unsigned short* kvbl = (unsigned short*)alloc((size_t)NNODE * DD * 2);
  unsigned short* xlh  = (unsigned short*)alloc((size_t)NNODE * DD * 2);
  unsigned short* xll  = (unsigned short*)alloc((size_t)NNODE * DD * 2);
  unsigned short* h1h  = (unsigned short*)alloc((size_t)NNODE * DD * 2);
  unsigned short* h1l  = (unsigned short*)alloc((size_t)NNODE * DD * 2);
  unsigned short* sdh  = (unsigned short*)alloc((size_t)NNODE * DD * 2);
  unsigned short* sdl  = (unsigned short*)alloc((size_t)NNODE * DD * 2);

  // Phase aliases (valid after graph-build consumes G0/G1):
  unsigned short* Qb16 = (unsigned short*)gram;                       // 2 MB [NNODE][128]
  unsigned short* KV16 = (unsigned short*)(gram + (size_t)1048576);   // 8 MB [NNODE][512]
  unsigned short* ffh = (unsigned short*)gram2;                         // 8MB
  unsigned short* ffl = (unsigned short*)gram2 + (size_t)NNODE * NDFF;  // 8MB

  const unsigned short* gw1Th = wTh,         *gw1Tl = wTl;
  const unsigned short* gw2Th = wTh + 16384, *gw2Tl = wTl + 16384;
  const unsigned short* KVTh01 = wTh + (size_t)2 * 16384;   // [Wk0;Wv0;Wk1;Wv1] [512][128]
  const unsigned short* KVTl01 = wTl + (size_t)2 * 16384;
  auto WqTh = [&](int l) { return wTh + (size_t)(6 + l) * 16384; };
  auto WqTl = [&](int l) { return wTl + (size_t)(6 + l) * 16384; };
  auto WoTh = [&](int l) { return wTh + (size_t)(8 + l) * 16384; };
  auto WoTl = [&](int l) { return wTl + (size_t)(8 + l) * 16384; };
  auto W1Th = [&](int l) { return wTh + 163840 + (size_t)l * 65536; };
  auto W1Tl = [&](int l) { return wTl + 163840 + (size_t)l * 65536; };
  auto W2Th = [&](int l) { return wTh + 294912 + (size_t)l * 65536; };
  auto W2Tl = [&](int l) { return wTl + 294912 + (size_t)l * 65536; };

  auto gemm = [&](const unsigned short* Ah, const unsigned short* Al,
                  const unsigned short* Bh, const unsigned short* Bl,
                  float* C, unsigned short* Ch, unsigned short* Cl,
                  int Mr, int Ncols, int Ldc, int col0, int Kd,
                  const float* bias, const float* resid, int relu) {
    dim3 g(Ncols / 64, Mr / 64);
    if (Kd == 128) {
      bf_gemm_k128_kernel<<<g, 256, 0, stream>>>(Ah, Al, Bh, Bl, C, Ch, Cl, Ldc, col0,
                                                 bias, resid, relu);
    } else {
      bf_gemm_sk_kernel<<<g, 512, 0, stream>>>(Ah, Al, Bh, Bl, C, Ch, Cl, Ldc, col0, Kd,
                                               bias, resid, relu);
    }
  };

  // ---- transposes & splits ----
  transpose_x_kernel<<<dim3(16, 32, 16), 256, 0, stream>>>(xenc, xth, xtl);
  transpose_w_kernel<<<dim3(16, 16, 14), 256, 0, stream>>>(gw1, gw2, Wq, Wk, Wv, Wo, W1, W2, wTh, wTl);
  split_kernel<<<(NNODE * DD / 4) / 256, 256, 0, stream>>>(enc, ench, encl);

  // ---- graph build ----
  colmean_part_kernel<<<dim3(32, 8), 256, 0, stream>>>(xenc, mpart);
  colmean_finish_kernel<<<NNODE / 256, 256, 0, stream>>>(mpart, mu);
  gram_kernel<<<dim3(36, BB, 2), 256, 0, stream>>>(xth, xtl, gram, gram2);
  rstd_kernel<<<NNODE / 256, 256, 0, stream>>>(gram, gram2, mu, rstd);
  select_kernel<<<NNODE / 4, 256, 0, stream>>>(gram, gram2, mu, rstd, nb);
  hipMemsetAsync(cnt, 0, (size_t)NNODE * 4, stream);
  count_kernel<<<NEDGE / 256, 256, 0, stream>>>(nb, cnt);
  scan_kernel<<<1, 256, 0, stream>>>(cnt, offs, curs, dinv);
  scatter_kernel<<<NEDGE / 256, 256, 0, stream>>>(nb, curs, lists);

  // ---- 2-layer GCN (xw scratch uses bufx) ----
  gemm(ench, encl, gw1Th, gw1Tl, bufx, nullptr, nullptr, NNODE, DD, DD, 0, DD,
       nullptr, nullptr, 0);
  agg_kernel<<<NNODE / 2, 256, 0, stream>>>(bufx, dinv, offs, lists, gb1, x1h, x1l);
  gemm(x1h, x1l, gw2Th, gw2Tl, bufx, nullptr, nullptr, NNODE, DD, DD, 0, DD,
       nullptr, nullptr, 0);
  agg_kernel<<<NNODE / 2, 256, 0, stream>>>(bufx, dinv, offs, lists, gb2, kvbh, kvbl);

  // ---- fused KV projection for BOTH layers -> single bf16 [NNODE][512] ----
  gemm(kvbh, kvbl, KVTh01, KVTl01, nullptr, KV16, nullptr, NNODE, 512, 512, 0, DD,
       nullptr, nullptr, 0);

  // ---- transformer encoder layers ----
  for (int l = 0; l < 2; ++l) {
    const float* hq = (l == 0) ? enc : bufh1;
    const unsigned short* hqh = (l == 0) ? ench : h1h;
    const unsigned short* hql = (l == 0) ? encl : h1l;
    gemm(hqh, hql, WqTh(l), WqTl(l), nullptr, Qb16, nullptr, NNODE, DD, DD, 0, DD,
         nullptr, nullptr, 0);                                         // q bf16
    attn_mfma_kernel<<<BB * HH * 8, 256, 0, stream>>>(Qb16, KV16, l * 256, sdh, sdl);
    gemm(sdh, sdl, WoTh(l), WoTl(l), bufx, nullptr, nullptr, NNODE, DD, DD, 0, DD,
         nullptr, hq, 0);
    ln_kernel<<<NNODE / 4, 256, 0, stream>>>(bufx, ln1g + l * DD, ln1b + l * DD, bufxl, xlh, xll);
    gemm(xlh, xll, W1Th(l), W1Tl(l), nullptr, ffh, ffl, NNODE, NDFF, NDFF, 0, DD,
         b1 + l * NDFF, nullptr, 1);
    gemm(ffh, ffl, W2Th(l), W2Tl(l), bufh, nullptr, nullptr, NNODE, DD, DD, 0, NDFF,
         b2 + l * DD, bufxl, 0);
    if (l == 1) {
      ln_kernel<<<NNODE / 4, 256, 0, stream>>>(bufh, ln2g + l * DD, ln2b + l * DD,
                                               outp, nullptr, nullptr);
    } else {
      ln_kernel<<<NNODE / 4, 256, 0, stream>>>(bufh, ln2g + l * DD, ln2b + l * DD,
                                               bufh1, h1h, h1l);
    }
  }
}

// Round 18
// 379.397 us; speedup vs baseline: 1.0926x; 1.0282x over previous
//
#include <hip/hip_runtime.h>
#include <math.h>

#define BB 16
#define MM 512
#define LL 1024
#define DD 128
#define KK 16
#define HH 8
#define DHH 16
#define NDFF 512
#define NNODE (BB*MM)      // 8192
#define NEDGE (NNODE*KK)   // 131072

typedef __attribute__((ext_vector_type(8))) short bf16x8;
typedef __attribute__((ext_vector_type(4))) float f32x4;
#define MFMA(a,b,c) __builtin_amdgcn_mfma_f32_16x16x32_bf16(a,b,c,0,0,0)

__device__ inline unsigned short bf16rne(float x) {
  union { float f; unsigned u; } v; v.f = x;
  return (unsigned short)((v.u + 0x7FFFu + ((v.u >> 16) & 1u)) >> 16);
}
__device__ inline float bf16tof(unsigned short h) {
  union { unsigned u; float f; } v; v.u = ((unsigned)h) << 16; return v.f;
}
__device__ inline void hilo(float x, unsigned short& h, unsigned short& l) {
  h = bf16rne(x);
  l = bf16rne(x - bf16tof(h));
}

// async global->LDS, 16B per lane (linear dest = wave-uniform base + lane*16)
__device__ inline void async16(const void* g, void* l) {
  __builtin_amdgcn_global_load_lds(
      (const __attribute__((address_space(1))) unsigned int*)g,
      (__attribute__((address_space(3))) unsigned int*)l, 16, 0, 0);
}

// ---------------- transpose x_enc [b][l][m] -> chunked k-major bf16 hi/lo ----------
__global__ __launch_bounds__(256) void transpose_x_kernel(const float* __restrict__ X,
                                                          unsigned short* __restrict__ XTh,
                                                          unsigned short* __restrict__ XTl) {
  __shared__ float t[32][33];
  int b = blockIdx.z;
  int m0 = blockIdx.x * 32, l0 = blockIdx.y * 32;
  int c = threadIdx.x & 31, r = threadIdx.x >> 5;   // r 0..7
  const float* Xb = X + (size_t)b * LL * MM;
  #pragma unroll
  for (int i = 0; i < 4; ++i)
    t[r + i*8][c] = Xb[(size_t)(l0 + r + i*8) * MM + m0 + c];
  __syncthreads();
  int R = m0 >> 6;
  int rbase = m0 & 63;
  size_t base = ((size_t)(b * 8 + R)) * 65536 + (size_t)(l0 >> 5) * 2048
              + (size_t)(c >> 3) * 512 + (c & 7);
  #pragma unroll
  for (int i = 0; i < 4; ++i) {
    unsigned short h, l;
    hilo(t[c][r + i*8], h, l);
    size_t idx = base + (size_t)(rbase + r + i*8) * 8;
    XTh[idx] = h; XTl[idx] = l;
  }
}

// ---------------- transpose weights [K][N] -> bf16 hi/lo [N][K] ----------------
__global__ __launch_bounds__(256) void transpose_w_kernel(
    const float* __restrict__ gw1, const float* __restrict__ gw2,
    const float* __restrict__ Wq, const float* __restrict__ Wk,
    const float* __restrict__ Wv, const float* __restrict__ Wo,
    const float* __restrict__ W1, const float* __restrict__ W2,
    unsigned short* __restrict__ wTh, unsigned short* __restrict__ wTl) {
  int z = blockIdx.z;
  const float* src; int K, N; size_t doff;
  if (z < 10) {
    K = 128; N = 128;
    switch (z) {
      case 0: src = gw1;         doff = 0;         break;
      case 1: src = gw2;         doff = 16384;     break;
      case 2: src = Wk;          doff = 2*16384;   break;
      case 3: src = Wv;          doff = 3*16384;   break;
      case 4: src = Wk + 16384;  doff = 4*16384;   break;
      case 5: src = Wv + 16384;  doff = 5*16384;   break;
      case 6: src = Wq;          doff = 6*16384;   break;
      case 7: src = Wq + 16384;  doff = 7*16384;   break;
      case 8: src = Wo;          doff = 8*16384;   break;
      default: src = Wo + 16384; doff = 9*16384;   break;
    }
  } else if (z < 12) {
    K = 128; N = 512; doff = 163840 + (size_t)(z - 10) * 65536;
    src = W1 + (size_t)(z - 10) * 65536;
  } else {
    K = 512; N = 128; doff = 294912 + (size_t)(z - 12) * 65536;
    src = W2 + (size_t)(z - 12) * 65536;
  }
  int k0 = blockIdx.x * 32, n0 = blockIdx.y * 32;
  if (k0 >= K || n0 >= N) return;
  __shared__ float t[32][33];
  int c = threadIdx.x & 31, r = threadIdx.x >> 5;
  #pragma unroll
  for (int i = 0; i < 4; ++i)
    t[r + i*8][c] = src[(size_t)(k0 + r + i*8) * N + n0 + c];
  __syncthreads();
  #pragma unroll
  for (int i = 0; i < 4; ++i) {
    size_t idx = doff + (size_t)(n0 + r + i*8) * K + k0 + c;
    unsigned short h, l;
    hilo(t[c][r + i*8], h, l);
    wTh[idx] = h; wTl[idx] = l;
  }
}

// ---------------- plain fp32 -> bf16 hi/lo split (for enc) ----------------
__global__ void split_kernel(const float* __restrict__ in,
                             unsigned short* __restrict__ h,
                             unsigned short* __restrict__ l) {
  int i = blockIdx.x * 256 + threadIdx.x;     // per float4
  float4 v = ((const float4*)in)[i];
  unsigned short h0,h1,h2,h3,l0,l1,l2,l3;
  hilo(v.x,h0,l0); hilo(v.y,h1,l1); hilo(v.z,h2,l2); hilo(v.w,h3,l3);
  uint2 hh, ll;
  hh.x = (unsigned)h0 | ((unsigned)h1 << 16); hh.y = (unsigned)h2 | ((unsigned)h3 << 16);
  ll.x = (unsigned)l0 | ((unsigned)l1 << 16); ll.y = (unsigned)l2 | ((unsigned)l3 << 16);
  ((uint2*)h)[i] = hh; ((uint2*)l)[i] = ll;
}

// ---------------- column means (original layout) ----------------
__global__ void colmean_part_kernel(const float* __restrict__ X, float* __restrict__ part) {
  int bm = blockIdx.x * 256 + threadIdx.x;
  int b = bm >> 9, m = bm & (MM - 1);
  int l0 = blockIdx.y * 128;
  const float* p = X + (size_t)b * LL * MM + (size_t)l0 * MM + m;
  float s = 0.f;
  #pragma unroll 8
  for (int l = 0; l < 128; ++l) s += p[(size_t)l * MM];
  part[(size_t)blockIdx.y * NNODE + bm] = s;
}

__global__ void colmean_finish_kernel(const float* __restrict__ part, float* __restrict__ mu) {
  int bm = blockIdx.x * 256 + threadIdx.x;
  float s = 0.f;
  #pragma unroll
  for (int j = 0; j < 8; ++j) s += part[(size_t)j * NNODE + bm];
  mu[bm] = s * (1.f / 1024.f);
}

// ---------------- MFMA gram, LDS-staged via global_load_lds, z-split partials -----
__global__ __launch_bounds__(256) void gram_kernel(const unsigned short* __restrict__ XTh,
                                                   const unsigned short* __restrict__ XTl,
                                                   float* __restrict__ G0,
                                                   float* __restrict__ G1) {
  __shared__ unsigned short lAh[2048], lAl[2048], lBh[2048], lBl[2048];
  int b = blockIdx.y, z = blockIdx.z;
  int pi = blockIdx.x;
  int ti = 0, rem = pi;
  while (rem >= 8 - ti) { rem -= 8 - ti; ++ti; }
  int tj = ti + rem;
  int tid = threadIdx.x;
  int wid = tid >> 6, lane = tid & 63;
  int wr = wid >> 1, wc = wid & 1;
  int fr = lane & 15, fkb = lane >> 4;
  size_t abase = ((size_t)(b * 8 + ti)) * 65536 + (size_t)z * 16 * 2048;
  size_t bbase = ((size_t)(b * 8 + tj)) * 65536 + (size_t)z * 16 * 2048;
  int toff = tid * 8;
  int aoff0 = fkb * 512 + (wr*32 + fr) * 8;
  int aoff1 = aoff0 + 128;
  int boff0 = fkb * 512 + (wc*32 + fr) * 8;
  int boff1 = boff0 + 128;
  f32x4 acc00 = {0,0,0,0}, acc01 = {0,0,0,0}, acc10 = {0,0,0,0}, acc11 = {0,0,0,0};
  for (int s = 0; s < 16; ++s) {
    size_t ao = abase + (size_t)s * 2048 + toff;
    size_t bo = bbase + (size_t)s * 2048 + toff;
    async16(XTh + ao, lAh + toff);
    async16(XTl + ao, lAl + toff);
    async16(XTh + bo, lBh + toff);
    async16(XTl + bo, lBl + toff);
    __syncthreads();
    bf16x8 a0h = *(const bf16x8*)(lAh + aoff0);
    bf16x8 a1h = *(const bf16x8*)(lAh + aoff1);
    bf16x8 a0l = *(const bf16x8*)(lAl + aoff0);
    bf16x8 a1l = *(const bf16x8*)(lAl + aoff1);
    bf16x8 b0h = *(const bf16x8*)(lBh + boff0);
    bf16x8 b1h = *(const bf16x8*)(lBh + boff1);
    bf16x8 b0l = *(const bf16x8*)(lBl + boff0);
    bf16x8 b1l = *(const bf16x8*)(lBl + boff1);
    acc00 = MFMA(a0h, b0h, acc00); acc00 = MFMA(a0h, b0l, acc00); acc00 = MFMA(a0l, b0h, acc00);
    acc01 = MFMA(a0h, b1h, acc01); acc01 = MFMA(a0h, b1l, acc01); acc01 = MFMA(a0l, b1h, acc01);
    acc10 = MFMA(a1h, b0h, acc10); acc10 = MFMA(a1h, b0l, acc10); acc10 = MFMA(a1l, b0h, acc10);
    acc11 = MFMA(a1h, b1h, acc11); acc11 = MFMA(a1h, b1l, acc11); acc11 = MFMA(a1l, b1h, acc11);
    __syncthreads();
  }
  int m0 = ti * 64, n0 = tj * 64;
  float* G = (z ? G1 : G0) + (size_t)b * MM * MM;
  int mirror = (ti != tj);
  #pragma unroll
  for (int i = 0; i < 2; ++i) {
    #pragma unroll
    for (int j = 0; j < 2; ++j) {
      const f32x4& a = (i == 0) ? (j == 0 ? acc00 : acc01) : (j == 0 ? acc10 : acc11);
      #pragma unroll
      for (int r = 0; r < 4; ++r) {
        int row = m0 + wr*32 + i*16 + (lane >> 4)*4 + r;
        int col = n0 + wc*32 + j*16 + (lane & 15);
        float v = a[r];
        G[(size_t)row * MM + col] = v;
        if (mirror) G[(size_t)col * MM + row] = v;
      }
    }
  }
}

// ---------------- MFMA GEMM, K=128 fully unrolled: all 32 frags loaded up front ---
// Epilogue: fp32 C, bf16 hi/lo (Ch+Cl), or single bf16 (Ch only, Cl==null).
__global__ __launch_bounds__(256) void bf_gemm_k128_kernel(
    const unsigned short* __restrict__ Ah, const unsigned short* __restrict__ Al,
    const unsigned short* __restrict__ Bh, const unsigned short* __restrict__ Bl,
    float* __restrict__ C, unsigned short* __restrict__ Ch, unsigned short* __restrict__ Cl,
    int Ldc, int col0, const float* __restrict__ bias,
    const float* __restrict__ resid, int relu) {
  int tid = threadIdx.x;
  int m0 = blockIdx.y * 64, n0 = blockIdx.x * 64;
  int wid = tid >> 6, lane = tid & 63;
  int wr = wid >> 1, wc = wid & 1;
  int fr = lane & 15, fkb = lane >> 4;
  size_t arow0 = (size_t)(m0 + wr*32 + fr) * 128;
  size_t arow1 = arow0 + 16 * 128;
  size_t brow0 = (size_t)(n0 + wc*32 + fr) * 128;
  size_t brow1 = brow0 + 16 * 128;
  bf16x8 fa0h[4], fa1h[4], fa0l[4], fa1l[4];
  bf16x8 fb0h[4], fb1h[4], fb0l[4], fb1l[4];
  #pragma unroll
  for (int ks = 0; ks < 4; ++ks) {
    int ko = ks * 32 + fkb * 8;
    fa0h[ks] = *(const bf16x8*)(Ah + arow0 + ko);
    fa1h[ks] = *(const bf16x8*)(Ah + arow1 + ko);
    fa0l[ks] = *(const bf16x8*)(Al + arow0 + ko);
    fa1l[ks] = *(const bf16x8*)(Al + arow1 + ko);
    fb0h[ks] = *(const bf16x8*)(Bh + brow0 + ko);
    fb1h[ks] = *(const bf16x8*)(Bh + brow1 + ko);
    fb0l[ks] = *(const bf16x8*)(Bl + brow0 + ko);
    fb1l[ks] = *(const bf16x8*)(Bl + brow1 + ko);
  }
  f32x4 acc00 = {0,0,0,0}, acc01 = {0,0,0,0}, acc10 = {0,0,0,0}, acc11 = {0,0,0,0};
  #pragma unroll
  for (int ks = 0; ks < 4; ++ks) {
    acc00 = MFMA(fa0h[ks], fb0h[ks], acc00);
    acc00 = MFMA(fa0h[ks], fb0l[ks], acc00);
    acc00 = MFMA(fa0l[ks], fb0h[ks], acc00);
    acc01 = MFMA(fa0h[ks], fb1h[ks], acc01);
    acc01 = MFMA(fa0h[ks], fb1l[ks], acc01);
    acc01 = MFMA(fa0l[ks], fb1h[ks], acc01);
    acc10 = MFMA(fa1h[ks], fb0h[ks], acc10);
    acc10 = MFMA(fa1h[ks], fb0l[ks], acc10);
    acc10 = MFMA(fa1l[ks], fb0h[ks], acc10);
    acc11 = MFMA(fa1h[ks], fb1h[ks], acc11);
    acc11 = MFMA(fa1h[ks], fb1l[ks], acc11);
    acc11 = MFMA(fa1l[ks], fb1h[ks], acc11);
  }
  #pragma unroll
  for (int i = 0; i < 2; ++i) {
    #pragma unroll
    for (int j = 0; j < 2; ++j) {
      const f32x4& a = (i == 0) ? (j == 0 ? acc00 : acc01) : (j == 0 ? acc10 : acc11);
      #pragma unroll
      for (int r = 0; r < 4; ++r) {
        int row = m0 + wr*32 + i*16 + (lane >> 4)*4 + r;
        int col = col0 + n0 + wc*32 + j*16 + (lane & 15);
        float v = a[r];
        if (bias)  v += bias[col - col0];
        if (resid) v += resid[(size_t)row * Ldc + col];
        if (relu)  v = fmaxf(v, 0.f);
        size_t o = (size_t)row * Ldc + col;
        if (C) C[o] = v;
        if (Ch) {
          if (Cl) {
            unsigned short hh, ll;
            hilo(v, hh, ll);
            Ch[o] = hh; Cl[o] = ll;
          } else {
            Ch[o] = bf16rne(v);
          }
        }
      }
    }
  }
}

// ---------------- MFMA GEMM 64x64 tile, 8 waves, in-block split-K2 (K=512) --------
__global__ __launch_bounds__(512) void bf_gemm_sk_kernel(
    const unsigned short* __restrict__ Ah, const unsigned short* __restrict__ Al,
    const unsigned short* __restrict__ Bh, const unsigned short* __restrict__ Bl,
    float* __restrict__ C, unsigned short* __restrict__ Ch, unsigned short* __restrict__ Cl,
    int Ldc, int col0, int Kd, const float* __restrict__ bias,
    const float* __restrict__ resid, int relu) {
  __shared__ float red[64][65];
  int tid = threadIdx.x;
  int m0 = blockIdx.y * 64, n0 = blockIdx.x * 64;
  int wid = tid >> 6, lane = tid & 63;
  int kg = wid >> 2;
  int w4 = wid & 3;
  int wr = w4 >> 1, wc = w4 & 1;
  int fr = lane & 15, fkb = lane >> 4;
  int Kh = Kd >> 1;
  size_t arow0 = (size_t)(m0 + wr*32 + fr) * Kd + (size_t)kg * Kh;
  size_t arow1 = arow0 + (size_t)16 * Kd;
  size_t brow0 = (size_t)(n0 + wc*32 + fr) * Kd + (size_t)kg * Kh;
  size_t brow1 = brow0 + (size_t)16 * Kd;
  f32x4 acc00 = {0,0,0,0}, acc01 = {0,0,0,0}, acc10 = {0,0,0,0}, acc11 = {0,0,0,0};
  int ko = fkb * 8;
  bf16x8 a0h = *(const bf16x8*)(Ah + arow0 + ko);
  bf16x8 a1h = *(const bf16x8*)(Ah + arow1 + ko);
  bf16x8 a0l = *(const bf16x8*)(Al + arow0 + ko);
  bf16x8 a1l = *(const bf16x8*)(Al + arow1 + ko);
  bf16x8 b0h = *(const bf16x8*)(Bh + brow0 + ko);
  bf16x8 b1h = *(const bf16x8*)(Bh + brow1 + ko);
  bf16x8 b0l = *(const bf16x8*)(Bl + brow0 + ko);
  bf16x8 b1l = *(const bf16x8*)(Bl + brow1 + ko);
  for (int k0 = 32; k0 < Kh; k0 += 32) {
    int kn = k0 + fkb * 8;
    bf16x8 na0h = *(const bf16x8*)(Ah + arow0 + kn);
    bf16x8 na1h = *(const bf16x8*)(Ah + arow1 + kn);
    bf16x8 na0l = *(const bf16x8*)(Al + arow0 + kn);
    bf16x8 na1l = *(const bf16x8*)(Al + arow1 + kn);
    bf16x8 nb0h = *(const bf16x8*)(Bh + brow0 + kn);
    bf16x8 nb1h = *(const bf16x8*)(Bh + brow1 + kn);
    bf16x8 nb0l = *(const bf16x8*)(Bl + brow0 + kn);
    bf16x8 nb1l = *(const bf16x8*)(Bl + brow1 + kn);
    acc00 = MFMA(a0h, b0h, acc00); acc00 = MFMA(a0h, b0l, acc00); acc00 = MFMA(a0l, b0h, acc00);
    acc01 = MFMA(a0h, b1h, acc01); acc01 = MFMA(a0h, b1l, acc01); acc01 = MFMA(a0l, b1h, acc01);
    acc10 = MFMA(a1h, b0h, acc10); acc10 = MFMA(a1h, b0l, acc10); acc10 = MFMA(a1l, b0h, acc10);
    acc11 = MFMA(a1h, b1h, acc11); acc11 = MFMA(a1h, b1l, acc11); acc11 = MFMA(a1l, b1h, acc11);
    a0h = na0h; a1h = na1h; a0l = na0l; a1l = na1l;
    b0h = nb0h; b1h = nb1h; b0l = nb0l; b1l = nb1l;
  }
  acc00 = MFMA(a0h, b0h, acc00); acc00 = MFMA(a0h, b0l, acc00); acc00 = MFMA(a0l, b0h, acc00);
  acc01 = MFMA(a0h, b1h, acc01); acc01 = MFMA(a0h, b1l, acc01); acc01 = MFMA(a0l, b1h, acc01);
  acc10 = MFMA(a1h, b0h, acc10); acc10 = MFMA(a1h, b0l, acc10); acc10 = MFMA(a1l, b0h, acc10);
  acc11 = MFMA(a1h, b1h, acc11); acc11 = MFMA(a1h, b1l, acc11); acc11 = MFMA(a1l, b1h, acc11);
  if (kg == 1) {
    #pragma unroll
    for (int i = 0; i < 2; ++i) {
      #pragma unroll
      for (int j = 0; j < 2; ++j) {
        const f32x4& a = (i == 0) ? (j == 0 ? acc00 : acc01) : (j == 0 ? acc10 : acc11);
        #pragma unroll
        for (int r = 0; r < 4; ++r) {
          int lr = wr*32 + i*16 + (lane >> 4)*4 + r;
          int lc = wc*32 + j*16 + (lane & 15);
          red[lr][lc] = a[r];
        }
      }
    }
  }
  __syncthreads();
  if (kg == 0) {
    #pragma unroll
    for (int i = 0; i < 2; ++i) {
      #pragma unroll
      for (int j = 0; j < 2; ++j) {
        const f32x4& a = (i == 0) ? (j == 0 ? acc00 : acc01) : (j == 0 ? acc10 : acc11);
        #pragma unroll
        for (int r = 0; r < 4; ++r) {
          int lr = wr*32 + i*16 + (lane >> 4)*4 + r;
          int lc = wc*32 + j*16 + (lane & 15);
          int row = m0 + lr;
          int col = col0 + n0 + lc;
          float v = a[r] + red[lr][lc];
          if (bias)  v += bias[col - col0];
          if (resid) v += resid[(size_t)row * Ldc + col];
          if (relu)  v = fmaxf(v, 0.f);
          size_t o = (size_t)row * Ldc + col;
          if (C) C[o] = v;
          if (Ch) {
            unsigned short hh, ll;
            hilo(v, hh, ll);
            Ch[o] = hh; Cl[o] = ll;
          }
        }
      }
    }
  }
}

// ---------------- rstd[b,m] = 1/std (std==0 -> 1) ----------------
__global__ void rstd_kernel(const float* __restrict__ G0, const float* __restrict__ G1,
                            const float* __restrict__ mu, float* __restrict__ rstd) {
  int bm = blockIdx.x * 256 + threadIdx.x;
  int b = bm >> 9, m = bm & (MM - 1);
  size_t di = (size_t)b * MM * MM + (size_t)m * MM + m;
  float g = G0[di] + G1[di];
  float mm = mu[bm];
  float cov = (g - 1024.f * mm * mm) * (1.f / 1023.f);
  float sd = sqrtf(fmaxf(cov, 0.f));
  rstd[bm] = (sd == 0.f) ? 1.f : (1.f / sd);
}

// ---------------- neighbors: packed-u32 argsort positions 1..16 ----------------
// key = (sortable_fp32(value) & ~511) | n  -> one u32 min-reduce carries both value
// and index (6 ds ops/round instead of 12). Ties in truncated value resolve by
// smaller n (same lexicographic rule as before).
__global__ void select_kernel(const float* __restrict__ G0, const float* __restrict__ G1,
                              const float* __restrict__ mu,
                              const float* __restrict__ rstd, int* __restrict__ nb) {
  int w = threadIdx.x >> 6, lane = threadIdx.x & 63;
  int bm = blockIdx.x * 4 + w;
  int b = bm >> 9, m = bm & (MM - 1);
  size_t rowoff = (size_t)b * MM * MM + (size_t)m * MM;
  const float* Gr0 = G0 + rowoff;
  const float* Gr1 = G1 + rowoff;
  const float* mub = mu + b * MM;
  const float* rsb = rstd + b * MM;
  float mm = mub[m], rm = rsb[m];
  unsigned key[8];
  int excl = 0;
  #pragma unroll
  for (int j = 0; j < 8; ++j) {
    int n = lane + j * 64;
    float cov = ((Gr0[n] + Gr1[n]) - 1024.f * mm * mub[n]) * (1.f / 1023.f);
    float val = cov * rm * rsb[n];
    union { float f; unsigned u; } cv; cv.f = val;
    unsigned s = cv.u ^ ((unsigned)((int)cv.u >> 31) | 0x80000000u);
    key[j] = (s & 0xFFFFFE00u) | (unsigned)n;
  }
  int* out = nb + (size_t)bm * KK;
  for (int it = 0; it < KK + 1; ++it) {
    unsigned bk = 0xFFFFFFFFu;
    #pragma unroll
    for (int j = 0; j < 8; ++j) {
      if (!((excl >> j) & 1)) bk = bk < key[j] ? bk : key[j];
    }
    #pragma unroll
    for (int off = 32; off; off >>= 1) {
      unsigned ok = __shfl_down(bk, off);
      bk = bk < ok ? bk : ok;
    }
    bk = __shfl(bk, 0);
    int n = (int)(bk & 511u);
    if ((n & 63) == lane) excl |= 1 << (n >> 6);
    if (it > 0 && lane == 0) out[it - 1] = n;
  }
}

// ---------------- degree counts ----------------
__global__ void count_kernel(const int* __restrict__ nb, int* __restrict__ cnt) {
  int e = blockIdx.x * 256 + threadIdx.x;
  int b = e >> 13, i = e & 8191;
  int dst = b * MM + nb[(size_t)b * 8192 + i];
  atomicAdd(&cnt[dst], 1);
}

// ---------------- scan + cursor + dinv ----------------
__global__ void scan_kernel(const int* __restrict__ cnt, int* __restrict__ offs,
                            int* __restrict__ curs, float* __restrict__ dinv) {
  __shared__ int part[256];
  int tid = threadIdx.x;
  int base = tid * 32;
  int local[32];
  int s = 0;
  #pragma unroll
  for (int i = 0; i < 32; ++i) { local[i] = cnt[base + i]; s += local[i]; }
  part[tid] = s;
  __syncthreads();
  for (int off = 1; off < 256; off <<= 1) {
    int v = (tid >= off) ? part[tid - off] : 0;
    __syncthreads();
    part[tid] += v;
    __syncthreads();
  }
  int run = part[tid] - s;
  #pragma unroll
  for (int i = 0; i < 32; ++i) {
    int n = base + i;
    offs[n] = run; curs[n] = run;
    run += local[i];
    dinv[n] = rsqrtf((float)(local[i] + 1));
  }
  if (tid == 255) offs[NNODE] = run;
}

// ---------------- scatter reverse edge lists ----------------
__global__ void scatter_kernel(const int* __restrict__ nb, int* __restrict__ curs,
                               int* __restrict__ lists) {
  int e = blockIdx.x * 256 + threadIdx.x;
  int b = e >> 13, i = e & 8191;
  int dst = b * MM + nb[(size_t)b * 8192 + i];
  int src = b * MM + (i & (MM - 1));
  int pos = atomicAdd(&curs[dst], 1);
  lists[pos] = src;
}

// ---------------- GCN aggregation: fp32 gather in, bf16 hi/lo out ----------------
__global__ void agg_kernel(const float* __restrict__ xw, const float* __restrict__ dinv,
                           const int* __restrict__ offs, const int* __restrict__ lists,
                           const float* __restrict__ bias,
                           unsigned short* __restrict__ outh,
                           unsigned short* __restrict__ outl) {
  int n = blockIdx.x * 2 + (threadIdx.x >> 7);
  int c = threadIdx.x & 127;
  float dn = dinv[n];
  float s = dn * xw[(size_t)n * DD + c];
  int e0 = offs[n], e1 = offs[n + 1];
  for (int e = e0; e < e1; ++e) {
    int src = lists[e];
    s += dinv[src] * xw[(size_t)src * DD + c];
  }
  float v = fmaxf(dn * s + bias[c], 0.f);
  unsigned short hh, ll;
  hilo(v, hh, ll);
  size_t o = (size_t)n * DD + c;
  outh[o] = hh; outl[o] = ll;
}

// ---------------- MFMA flash attention ----------------
__global__ __launch_bounds__(256) void attn_mfma_kernel(
    const unsigned short* __restrict__ Qb16, const unsigned short* __restrict__ KV16,
    int kvoff,
    unsigned short* __restrict__ outh, unsigned short* __restrict__ outl) {
  __shared__ unsigned short Kl[512 * 16];     // [key][16d], row 32B
  __shared__ unsigned short VT[16 * 520];     // [d][520 keys], row 1040B
  __shared__ unsigned short Pl[64 * 136];     // [q][136 keys], row 272B
  int bx = blockIdx.x;
  int qc = bx & 7;
  int h  = (bx >> 3) & 7;
  int b  = bx >> 6;
  int tid = threadIdx.x;

  for (int u = tid; u < 1024; u += 256) {
    int row = u >> 1, half = u & 1;
    const unsigned short* src = KV16 + (size_t)(b * MM + row) * 512 + kvoff + h * 16 + half * 8;
    *(uint4*)&Kl[row * 16 + half * 8] = *(const uint4*)src;
  }
  for (int key = tid; key < 512; key += 256) {
    const unsigned short* src = KV16 + (size_t)(b * MM + key) * 512 + kvoff + 128 + h * 16;
    unsigned short tmp[16];
    *(uint4*)&tmp[0] = *(const uint4*)src;
    *(uint4*)&tmp[8] = *(const uint4*)(src + 8);
    #pragma unroll
    for (int d = 0; d < 16; ++d) VT[d * 520 + key] = tmp[d];
  }
  __syncthreads();

  int wid = tid >> 6, lane = tid & 63;
  int lq = lane & 15, g = lane >> 4;
  bf16x8 zz = {0,0,0,0,0,0,0,0};
  bf16x8 qf = zz;
  if (lane < 32) {
    int qrow = b * MM + qc * 64 + wid * 16 + lq;
    qf = *(const bf16x8*)(Qb16 + (size_t)qrow * 128 + h * 16 + g * 8);
  }
  float m = -1e30f, lp = 0.f;
  f32x4 o = {0,0,0,0};
  int prow = (wid * 16 + lq) * 136;

  for (int c4 = 0; c4 < 4; ++c4) {
    int kbase = c4 * 128;
    f32x4 s[8];
    f32x4 zc = {0,0,0,0};
    #pragma unroll
    for (int t = 0; t < 8; ++t) {
      bf16x8 kf = zz;
      if (lane < 32) kf = *(const bf16x8*)&Kl[(kbase + t * 16 + lq) * 16 + g * 8];
      s[t] = MFMA(kf, qf, zc);
    }
    float tm = -1e30f;
    #pragma unroll
    for (int t = 0; t < 8; ++t) {
      tm = fmaxf(tm, fmaxf(fmaxf(s[t][0], s[t][1]), fmaxf(s[t][2], s[t][3])));
    }
    tm = fmaxf(tm, __shfl_xor(tm, 16));
    tm = fmaxf(tm, __shfl_xor(tm, 32));
    float nm = fmaxf(m, 0.25f * tm);
    float esc = __expf(m - nm);
    m = nm;
    float ls = 0.f;
    #pragma unroll
    for (int t = 0; t < 8; ++t) {
      float p0 = __expf(0.25f * s[t][0] - nm);
      float p1 = __expf(0.25f * s[t][1] - nm);
      float p2 = __expf(0.25f * s[t][2] - nm);
      float p3 = __expf(0.25f * s[t][3] - nm);
      ls += (p0 + p1) + (p2 + p3);
      unsigned w0 = (unsigned)bf16rne(p0) | ((unsigned)bf16rne(p1) << 16);
      unsigned w1 = (unsigned)bf16rne(p2) | ((unsigned)bf16rne(p3) << 16);
      int kc = t * 16 + g * 4;
      *(unsigned*)&Pl[prow + kc]     = w0;
      *(unsigned*)&Pl[prow + kc + 2] = w1;
    }
    lp = lp * esc + ls;
    float e0 = __shfl(esc, g * 4 + 0);
    float e1 = __shfl(esc, g * 4 + 1);
    float e2 = __shfl(esc, g * 4 + 2);
    float e3 = __shfl(esc, g * 4 + 3);
    o[0] *= e0; o[1] *= e1; o[2] *= e2; o[3] *= e3;
    #pragma unroll
    for (int c = 0; c < 4; ++c) {
      bf16x8 pf = *(const bf16x8*)&Pl[prow + c * 32 + g * 8];
      bf16x8 vf = *(const bf16x8*)&VT[lq * 520 + kbase + c * 32 + g * 8];
      o = MFMA(pf, vf, o);
    }
  }
  lp += __shfl_xor(lp, 16);
  lp += __shfl_xor(lp, 32);
  float linv = 1.f / lp;
  float l0 = __shfl(linv, g * 4 + 0);
  float l1 = __shfl(linv, g * 4 + 1);
  float l2 = __shfl(linv, g * 4 + 2);
  float l3 = __shfl(linv, g * 4 + 3);
  float vv[4] = {o[0] * l0, o[1] * l1, o[2] * l2, o[3] * l3};
  #pragma unroll
  for (int r = 0; r < 4; ++r) {
    int qrow = b * MM + qc * 64 + wid * 16 + g * 4 + r;
    size_t off = (size_t)qrow * DD + h * 16 + lq;
    unsigned short hh, ll;
    hilo(vv[r], hh, ll);
    outh[off] = hh; outl[off] = ll;
  }
}

// ---------------- layernorm over D=128: fp32 out + optional bf16 hi/lo out --------
__global__ void ln_kernel(const float* __restrict__ x, const float* __restrict__ g,
                          const float* __restrict__ bb, float* __restrict__ out,
                          unsigned short* __restrict__ outh,
                          unsigned short* __restrict__ outl) {
  int row = blockIdx.x * 4 + (threadIdx.x >> 6);
  int lane = threadIdx.x & 63;
  float2 xv = *(const float2*)&x[(size_t)row * DD + lane * 2];
  float s = xv.x + xv.y;
  #pragma unroll
  for (int off = 1; off < 64; off <<= 1) s += __shfl_xor(s, off);
  float mu = s * (1.f / 128.f);
  float d0 = xv.x - mu, d1 = xv.y - mu;
  float sq = d0 * d0 + d1 * d1;
  #pragma unroll
  for (int off = 1; off < 64; off <<= 1) sq += __shfl_xor(sq, off);
  float rs = rsqrtf(sq * (1.f / 128.f) + 1e-5f);
  float2 gg = *(const float2*)&g[lane * 2];
  float2 bv = *(const float2*)&bb[lane * 2];
  float2 y;
  y.x = d0 * rs * gg.x + bv.x;
  y.y = d1 * rs * gg.y + bv.y;
  *(float2*)&out[(size_t)row * DD + lane * 2] = y;
  if (outh) {
    unsigned short h0, l0, h1, l1;
    hilo(y.x, h0, l0); hilo(y.y, h1, l1);
    unsigned hh = (unsigned)h0 | ((unsigned)h1 << 16);
    unsigned ll = (unsigned)l0 | ((unsigned)l1 << 16);
    *(unsigned*)&outh[(size_t)row * DD + lane * 2] = hh;
    *(unsigned*)&outl[(size_t)row * DD + lane * 2] = ll;
  }
}

extern "C" void kernel_launch(void* const* d_in, const int* in_sizes, int n_in,
                              void* d_out, int out_size, void* d_ws, size_t ws_size,
                              hipStream_t stream) {
  (void)in_sizes; (void)n_in; (void)out_size; (void)ws_size;
  const float* enc  = (const float*)d_in[0];
  const float* xenc = (const float*)d_in[1];
  const float* gw1  = (const float*)d_in[2];
  const float* gb1  = (const float*)d_in[3];
  const float* gw2  = (const float*)d_in[4];
  const float* gb2  = (const float*)d_in[5];
  const float* Wq   = (const float*)d_in[6];
  const float* Wk   = (const float*)d_in[7];
  const float* Wv   = (const float*)d_in[8];
  const float* Wo   = (const float*)d_in[9];
  const float* ln1g = (const float*)d_in[10];
  const float* ln1b = (const float*)d_in[11];
  const float* W1   = (const float*)d_in[12];
  const float* b1   = (const float*)d_in[13];
  const float* W2   = (const float*)d_in[14];
  const float* b2   = (const float*)d_in[15];
  const float* ln2g = (const float*)d_in[16];
  const float* ln2b = (const float*)d_in[17];
  float* outp = (float*)d_out;

  char* w = (char*)d_ws;
  auto alloc = [&](size_t bytes) -> char* {
    char* p = w;
    w += (bytes + 255) & ~(size_t)255;
    return p;
  };
  float* mu    = (float*)alloc((size_t)NNODE * 4);
  float* rstd  = (float*)alloc((size_t)NNODE * 4);
  float* dinv  = (float*)alloc((size_t)NNODE * 4);
  float* mpart = (float*)alloc((size_t)8 * NNODE * 4);
  int*   nb    = (int*)  alloc((size_t)NEDGE * 4);
  int*   cnt   = (int*)  alloc((size_t)NNODE * 4);
  int*   offs  = (int*)  alloc((size_t)(NNODE + 1) * 4);
  int*   curs  = (int*)  alloc((size_t)NNODE * 4);
  int*   lists = (int*)  alloc((size_t)NEDGE * 4);
  float* gram  = (float*)alloc((size_t)BB * MM * MM * 4);   // 16MB: G0; later Qb16+KV16
  float* gram2 = (float*)alloc((size_t)BB * MM * MM * 4);   // 16MB: G1; later ff hi/lo
  float* bufx  = (float*)alloc((size_t)NNODE * DD * 4);
  float* bufxl = (float*)alloc((size_t)NNODE * DD * 4);
  float* bufh  = (float*)alloc((size_t)NNODE * DD * 4);
  float* bufh1 = (float*)alloc((size_t)NNODE * DD * 4);
  unsigned short* xth  = (unsigned short*)alloc((size_t)BB * MM * LL * 2);  // 16MB
  unsigned short* xtl  = (unsigned short*)alloc((size_t)BB * MM * LL * 2);  // 16MB
  unsigned short* wTh  = (unsigned short*)alloc((size_t)425984 * 2);
  unsigned short* wTl  = (unsigned short*)alloc((size_t)425984 * 2);
  unsigned short* ench = (unsigned short*)alloc((size_t)NNODE * DD * 2);
  unsigned short* encl = (unsigned short*)alloc((size_t)NNODE * DD * 2);
  unsigned short* x1h  = (unsigned short*)alloc((size_t)NNODE * DD * 2);
  unsigned short* x1l  = (unsigned short*)alloc((size_t)NNODE * DD * 2);
  unsigned short* kvbh = (unsigned short*)alloc((size_t)NNODE * DD * 2);
  unsigned short* kvbl = (unsigned short*)alloc((size_t)NNODE * DD * 2);
  unsigned short* xlh  = (unsigned short*)alloc((size_t)NNODE * DD * 2);
  unsigned short* xll  = (unsigned short*)alloc((size_t)NNODE * DD * 2);
  unsigned short* h1h  = (unsigned short*)alloc((size_t)NNODE * DD * 2);
  unsigned short* h1l  = (unsigned short*)alloc((size_t)NNODE * DD * 2);
  unsigned short* sdh  = (unsigned short*)alloc((size_t)NNODE * DD * 2);
  unsigned short* sdl  = (unsigned short*)alloc((size_t)NNODE * DD * 2);

  // Phase aliases (valid after graph-build consumes G0/G1):
  unsigned short* Qb16 = (unsigned short*)gram;                       // 2 MB [NNODE][128]
  unsigned short* KV16 = (unsigned short*)(gram + (size_t)1048576);   // 8 MB [NNODE][512]
  unsigned short* ffh = (unsigned short*)gram2;                         // 8MB
  unsigned short* ffl = (unsigned short*)gram2 + (size_t)NNODE * NDFF;  // 8MB

  const unsigned short* gw1Th = wTh,         *gw1Tl = wTl;
  const unsigned short* gw2Th = wTh + 16384, *gw2Tl = wTl + 16384;
  const unsigned short* KVTh01 = wTh + (size_t)2 * 16384;   // [Wk0;Wv0;Wk1;Wv1] [512][128]
  const unsigned short* KVTl01 = wTl + (size_t)2 * 16384;
  auto WqTh = [&](int l) { return wTh + (size_t)(6 + l) * 16384; };
  auto WqTl = [&](int l) { return wTl + (size_t)(6 + l) * 16384; };
  auto WoTh = [&](int l) { return wTh + (size_t)(8 + l) * 16384; };
  auto WoTl = [&](int l) { return wTl + (size_t)(8 + l) * 16384; };
  auto W1Th = [&](int l) { return wTh + 163840 + (size_t)l * 65536; };
  auto W1Tl = [&](int l) { return wTl + 163840 + (size_t)l * 65536; };
  auto W2Th = [&](int l) { return wTh + 294912 + (size_t)l * 65536; };
  auto W2Tl = [&](int l) { return wTl + 294912 + (size_t)l * 65536; };

  auto gemm = [&](const unsigned short* Ah, const unsigned short* Al,
                  const unsigned short* Bh, const unsigned short* Bl,
                  float* C, unsigned short* Ch, unsigned short* Cl,
                  int Mr, int Ncols, int Ldc, int col0, int Kd,
                  const float* bias, const float* resid, int relu) {
    dim3 g(Ncols / 64, Mr / 64);
    if (Kd == 128) {
      bf_gemm_k128_kernel<<<g, 256, 0, stream>>>(Ah, Al, Bh, Bl, C, Ch, Cl, Ldc, col0,
                                                 bias, resid, relu);
    } else {
      bf_gemm_sk_kernel<<<g, 512, 0, stream>>>(Ah, Al, Bh, Bl, C, Ch, Cl, Ldc, col0, Kd,
                                               bias, resid, relu);
    }
  };

  // ---- transposes & splits ----
  transpose_x_kernel<<<dim3(16, 32, 16), 256, 0, stream>>>(xenc, xth, xtl);
  transpose_w_kernel<<<dim3(16, 16, 14), 256, 0, stream>>>(gw1, gw2, Wq, Wk, Wv, Wo, W1, W2, wTh, wTl);
  split_kernel<<<(NNODE * DD / 4) / 256, 256, 0, stream>>>(enc, ench, encl);

  // ---- graph build ----
  colmean_part_kernel<<<dim3(32, 8), 256, 0, stream>>>(xenc, mpart);
  colmean_finish_kernel<<<NNODE / 256, 256, 0, stream>>>(mpart, mu);
  gram_kernel<<<dim3(36, BB, 2), 256, 0, stream>>>(xth, xtl, gram, gram2);
  rstd_kernel<<<NNODE / 256, 256, 0, stream>>>(gram, gram2, mu, rstd);
  select_kernel<<<NNODE / 4, 256, 0, stream>>>(gram, gram2, mu, rstd, nb);
  hipMemsetAsync(cnt, 0, (size_t)NNODE * 4, stream);
  count_kernel<<<NEDGE / 256, 256, 0, stream>>>(nb, cnt);
  scan_kernel<<<1, 256, 0, stream>>>(cnt, offs, curs, dinv);
  scatter_kernel<<<NEDGE / 256, 256, 0, stream>>>(nb, curs, lists);

  // ---- 2-layer GCN (xw scratch uses bufx) ----
  gemm(ench, encl, gw1Th, gw1Tl, bufx, nullptr, nullptr, NNODE, DD, DD, 0, DD,
       nullptr, nullptr, 0);
  agg_kernel<<<NNODE / 2, 256, 0, stream>>>(bufx, dinv, offs, lists, gb1, x1h, x1l);
  gemm(x1h, x1l, gw2Th, gw2Tl, bufx, nullptr, nullptr, NNODE, DD, DD, 0, DD,
       nullptr, nullptr, 0);
  agg_kernel<<<NNODE / 2, 256, 0, stream>>>(bufx, dinv, offs, lists, gb2, kvbh, kvbl);

  // ---- fused KV projection for BOTH layers -> single bf16 [NNODE][512] ----
  gemm(kvbh, kvbl, KVTh01, KVTl01, nullptr, KV16, nullptr, NNODE, 512, 512, 0, DD,
       nullptr, nullptr, 0);

  // ---- transformer encoder layers ----
  for (int l = 0; l < 2; ++l) {
    const float* hq = (l == 0) ? enc : bufh1;
    const unsigned short* hqh = (l == 0) ? ench : h1h;
    const unsigned short* hql = (l == 0) ? encl : h1l;
    gemm(hqh, hql, WqTh(l), WqTl(l), nullptr, Qb16, nullptr, NNODE, DD, DD, 0, DD,
         nullptr, nullptr, 0);                                         // q bf16
    attn_mfma_kernel<<<BB * HH * 8, 256, 0, stream>>>(Qb16, KV16, l * 256, sdh, sdl);
    gemm(sdh, sdl, WoTh(l), WoTl(l), bufx, nullptr, nullptr, NNODE, DD, DD, 0, DD,
         nullptr, hq, 0);
    ln_kernel<<<NNODE / 4, 256, 0, stream>>>(bufx, ln1g + l * DD, ln1b + l * DD, bufxl, xlh, xll);
    gemm(xlh, xll, W1Th(l), W1Tl(l), nullptr, ffh, ffl, NNODE, NDFF, NDFF, 0, DD,
         b1 + l * NDFF, nullptr, 1);
    gemm(ffh, ffl, W2Th(l), W2Tl(l), bufh, nullptr, nullptr, NNODE, DD, DD, 0, NDFF,
         b2 + l * DD, bufxl, 0);
    if (l == 1) {
      ln_kernel<<<NNODE / 4, 256, 0, stream>>>(bufh, ln2g + l * DD, ln2b + l * DD,
                                               outp, nullptr, nullptr);
    } else {
      ln_kernel<<<NNODE / 4, 256, 0, stream>>>(bufh, ln2g + l * DD, ln2b + l * DD,
                                               bufh1, h1h, h1l);
    }
  }
}

// Round 19
// 377.963 us; speedup vs baseline: 1.0968x; 1.0038x over previous
//
#include <hip/hip_runtime.h>
#include <math.h>

#define BB 16
#define MM 512
#define LL 1024
#define DD 128
#define KK 16
#define HH 8
#define DHH 16
#define NDFF 512
#define NNODE (BB*MM)      // 8192
#define NEDGE (NNODE*KK)   // 131072

typedef __attribute__((ext_vector_type(8))) short bf16x8;
typedef __attribute__((ext_vector_type(4))) float f32x4;
#define MFMA(a,b,c) __builtin_amdgcn_mfma_f32_16x16x32_bf16(a,b,c,0,0,0)

__device__ inline unsigned short bf16rne(float x) {
  union { float f; unsigned u; } v; v.f = x;
  return (unsigned short)((v.u + 0x7FFFu + ((v.u >> 16) & 1u)) >> 16);
}
__device__ inline float bf16tof(unsigned short h) {
  union { unsigned u; float f; } v; v.u = ((unsigned)h) << 16; return v.f;
}
__device__ inline void hilo(float x, unsigned short& h, unsigned short& l) {
  h = bf16rne(x);
  l = bf16rne(x - bf16tof(h));
}

// async global->LDS, 16B per lane (linear dest = wave-uniform base + lane*16)
__device__ inline void async16(const void* g, void* l) {
  __builtin_amdgcn_global_load_lds(
      (const __attribute__((address_space(1))) unsigned int*)g,
      (__attribute__((address_space(3))) unsigned int*)l, 16, 0, 0);
}

// ---------------- transpose x_enc [b][l][m] -> chunked k-major bf16 hi/lo ----------
__global__ __launch_bounds__(256) void transpose_x_kernel(const float* __restrict__ X,
                                                          unsigned short* __restrict__ XTh,
                                                          unsigned short* __restrict__ XTl) {
  __shared__ float t[32][33];
  int b = blockIdx.z;
  int m0 = blockIdx.x * 32, l0 = blockIdx.y * 32;
  int c = threadIdx.x & 31, r = threadIdx.x >> 5;   // r 0..7
  const float* Xb = X + (size_t)b * LL * MM;
  #pragma unroll
  for (int i = 0; i < 4; ++i)
    t[r + i*8][c] = Xb[(size_t)(l0 + r + i*8) * MM + m0 + c];
  __syncthreads();
  int R = m0 >> 6;
  int rbase = m0 & 63;
  size_t base = ((size_t)(b * 8 + R)) * 65536 + (size_t)(l0 >> 5) * 2048
              + (size_t)(c >> 3) * 512 + (c & 7);
  #pragma unroll
  for (int i = 0; i < 4; ++i) {
    unsigned short h, l;
    hilo(t[c][r + i*8], h, l);
    size_t idx = base + (size_t)(rbase + r + i*8) * 8;
    XTh[idx] = h; XTl[idx] = l;
  }
}

// ---------------- transpose weights [K][N] -> bf16 hi/lo [N][K] ----------------
__global__ __launch_bounds__(256) void transpose_w_kernel(
    const float* __restrict__ gw1, const float* __restrict__ gw2,
    const float* __restrict__ Wq, const float* __restrict__ Wk,
    const float* __restrict__ Wv, const float* __restrict__ Wo,
    const float* __restrict__ W1, const float* __restrict__ W2,
    unsigned short* __restrict__ wTh, unsigned short* __restrict__ wTl) {
  int z = blockIdx.z;
  const float* src; int K, N; size_t doff;
  if (z < 10) {
    K = 128; N = 128;
    switch (z) {
      case 0: src = gw1;         doff = 0;         break;
      case 1: src = gw2;         doff = 16384;     break;
      case 2: src = Wk;          doff = 2*16384;   break;
      case 3: src = Wv;          doff = 3*16384;   break;
      case 4: src = Wk + 16384;  doff = 4*16384;   break;
      case 5: src = Wv + 16384;  doff = 5*16384;   break;
      case 6: src = Wq;          doff = 6*16384;   break;
      case 7: src = Wq + 16384;  doff = 7*16384;   break;
      case 8: src = Wo;          doff = 8*16384;   break;
      default: src = Wo + 16384; doff = 9*16384;   break;
    }
  } else if (z < 12) {
    K = 128; N = 512; doff = 163840 + (size_t)(z - 10) * 65536;
    src = W1 + (size_t)(z - 10) * 65536;
  } else {
    K = 512; N = 128; doff = 294912 + (size_t)(z - 12) * 65536;
    src = W2 + (size_t)(z - 12) * 65536;
  }
  int k0 = blockIdx.x * 32, n0 = blockIdx.y * 32;
  if (k0 >= K || n0 >= N) return;
  __shared__ float t[32][33];
  int c = threadIdx.x & 31, r = threadIdx.x >> 5;
  #pragma unroll
  for (int i = 0; i < 4; ++i)
    t[r + i*8][c] = src[(size_t)(k0 + r + i*8) * N + n0 + c];
  __syncthreads();
  #pragma unroll
  for (int i = 0; i < 4; ++i) {
    size_t idx = doff + (size_t)(n0 + r + i*8) * K + k0 + c;
    unsigned short h, l;
    hilo(t[c][r + i*8], h, l);
    wTh[idx] = h; wTl[idx] = l;
  }
}

// ---------------- plain fp32 -> bf16 hi/lo split (for enc) ----------------
__global__ void split_kernel(const float* __restrict__ in,
                             unsigned short* __restrict__ h,
                             unsigned short* __restrict__ l) {
  int i = blockIdx.x * 256 + threadIdx.x;     // per float4
  float4 v = ((const float4*)in)[i];
  unsigned short h0,h1,h2,h3,l0,l1,l2,l3;
  hilo(v.x,h0,l0); hilo(v.y,h1,l1); hilo(v.z,h2,l2); hilo(v.w,h3,l3);
  uint2 hh, ll;
  hh.x = (unsigned)h0 | ((unsigned)h1 << 16); hh.y = (unsigned)h2 | ((unsigned)h3 << 16);
  ll.x = (unsigned)l0 | ((unsigned)l1 << 16); ll.y = (unsigned)l2 | ((unsigned)l3 << 16);
  ((uint2*)h)[i] = hh; ((uint2*)l)[i] = ll;
}

// ---------------- column means (original layout) ----------------
__global__ void colmean_part_kernel(const float* __restrict__ X, float* __restrict__ part) {
  int bm = blockIdx.x * 256 + threadIdx.x;
  int b = bm >> 9, m = bm & (MM - 1);
  int l0 = blockIdx.y * 128;
  const float* p = X + (size_t)b * LL * MM + (size_t)l0 * MM + m;
  float s = 0.f;
  #pragma unroll 8
  for (int l = 0; l < 128; ++l) s += p[(size_t)l * MM];
  part[(size_t)blockIdx.y * NNODE + bm] = s;
}

__global__ void colmean_finish_kernel(const float* __restrict__ part, float* __restrict__ mu) {
  int bm = blockIdx.x * 256 + threadIdx.x;
  float s = 0.f;
  #pragma unroll
  for (int j = 0; j < 8; ++j) s += part[(size_t)j * NNODE + bm];
  mu[bm] = s * (1.f / 1024.f);
}

// ---------------- MFMA gram, BK=64 per barrier (8 iters), z-split partials -----
__global__ __launch_bounds__(256) void gram_kernel(const unsigned short* __restrict__ XTh,
                                                   const unsigned short* __restrict__ XTl,
                                                   float* __restrict__ G0,
                                                   float* __restrict__ G1) {
  __shared__ unsigned short lAh[4096], lAl[4096], lBh[4096], lBl[4096];
  int b = blockIdx.y, z = blockIdx.z;
  int pi = blockIdx.x;
  int ti = 0, rem = pi;
  while (rem >= 8 - ti) { rem -= 8 - ti; ++ti; }
  int tj = ti + rem;
  int tid = threadIdx.x;
  int wid = tid >> 6, lane = tid & 63;
  int wr = wid >> 1, wc = wid & 1;
  int fr = lane & 15, fkb = lane >> 4;
  size_t abase = ((size_t)(b * 8 + ti)) * 65536 + (size_t)z * 16 * 2048;
  size_t bbase = ((size_t)(b * 8 + tj)) * 65536 + (size_t)z * 16 * 2048;
  int toff = tid * 8;
  int aoff0 = fkb * 512 + (wr*32 + fr) * 8;
  int aoff1 = aoff0 + 128;
  int boff0 = fkb * 512 + (wc*32 + fr) * 8;
  int boff1 = boff0 + 128;
  f32x4 acc00 = {0,0,0,0}, acc01 = {0,0,0,0}, acc10 = {0,0,0,0}, acc11 = {0,0,0,0};
  for (int s = 0; s < 8; ++s) {
    size_t ao = abase + (size_t)s * 4096 + toff;
    size_t bo = bbase + (size_t)s * 4096 + toff;
    async16(XTh + ao, lAh + toff);
    async16(XTh + ao + 2048, lAh + toff + 2048);
    async16(XTl + ao, lAl + toff);
    async16(XTl + ao + 2048, lAl + toff + 2048);
    async16(XTh + bo, lBh + toff);
    async16(XTh + bo + 2048, lBh + toff + 2048);
    async16(XTl + bo, lBl + toff);
    async16(XTl + bo + 2048, lBl + toff + 2048);
    __syncthreads();
    #pragma unroll
    for (int kk = 0; kk < 2; ++kk) {
      int kb = kk * 2048;
      bf16x8 a0h = *(const bf16x8*)(lAh + kb + aoff0);
      bf16x8 a1h = *(const bf16x8*)(lAh + kb + aoff1);
      bf16x8 a0l = *(const bf16x8*)(lAl + kb + aoff0);
      bf16x8 a1l = *(const bf16x8*)(lAl + kb + aoff1);
      bf16x8 b0h = *(const bf16x8*)(lBh + kb + boff0);
      bf16x8 b1h = *(const bf16x8*)(lBh + kb + boff1);
      bf16x8 b0l = *(const bf16x8*)(lBl + kb + boff0);
      bf16x8 b1l = *(const bf16x8*)(lBl + kb + boff1);
      acc00 = MFMA(a0h, b0h, acc00); acc00 = MFMA(a0h, b0l, acc00); acc00 = MFMA(a0l, b0h, acc00);
      acc01 = MFMA(a0h, b1h, acc01); acc01 = MFMA(a0h, b1l, acc01); acc01 = MFMA(a0l, b1h, acc01);
      acc10 = MFMA(a1h, b0h, acc10); acc10 = MFMA(a1h, b0l, acc10); acc10 = MFMA(a1l, b0h, acc10);
      acc11 = MFMA(a1h, b1h, acc11); acc11 = MFMA(a1h, b1l, acc11); acc11 = MFMA(a1l, b1h, acc11);
    }
    __syncthreads();
  }
  int m0 = ti * 64, n0 = tj * 64;
  float* G = (z ? G1 : G0) + (size_t)b * MM * MM;
  int mirror = (ti != tj);
  #pragma unroll
  for (int i = 0; i < 2; ++i) {
    #pragma unroll
    for (int j = 0; j < 2; ++j) {
      const f32x4& a = (i == 0) ? (j == 0 ? acc00 : acc01) : (j == 0 ? acc10 : acc11);
      #pragma unroll
      for (int r = 0; r < 4; ++r) {
        int row = m0 + wr*32 + i*16 + (lane >> 4)*4 + r;
        int col = n0 + wc*32 + j*16 + (lane & 15);
        float v = a[r];
        G[(size_t)row * MM + col] = v;
        if (mirror) G[(size_t)col * MM + row] = v;
      }
    }
  }
}

// ---------------- MFMA GEMM, K=128 fully unrolled: all 32 frags loaded up front ---
// Epilogue: fp32 C, bf16 hi/lo (Ch+Cl), or single bf16 (Ch only, Cl==null).
__global__ __launch_bounds__(256) void bf_gemm_k128_kernel(
    const unsigned short* __restrict__ Ah, const unsigned short* __restrict__ Al,
    const unsigned short* __restrict__ Bh, const unsigned short* __restrict__ Bl,
    float* __restrict__ C, unsigned short* __restrict__ Ch, unsigned short* __restrict__ Cl,
    int Ldc, int col0, const float* __restrict__ bias,
    const float* __restrict__ resid, int relu) {
  int tid = threadIdx.x;
  int m0 = blockIdx.y * 64, n0 = blockIdx.x * 64;
  int wid = tid >> 6, lane = tid & 63;
  int wr = wid >> 1, wc = wid & 1;
  int fr = lane & 15, fkb = lane >> 4;
  size_t arow0 = (size_t)(m0 + wr*32 + fr) * 128;
  size_t arow1 = arow0 + 16 * 128;
  size_t brow0 = (size_t)(n0 + wc*32 + fr) * 128;
  size_t brow1 = brow0 + 16 * 128;
  bf16x8 fa0h[4], fa1h[4], fa0l[4], fa1l[4];
  bf16x8 fb0h[4], fb1h[4], fb0l[4], fb1l[4];
  #pragma unroll
  for (int ks = 0; ks < 4; ++ks) {
    int ko = ks * 32 + fkb * 8;
    fa0h[ks] = *(const bf16x8*)(Ah + arow0 + ko);
    fa1h[ks] = *(const bf16x8*)(Ah + arow1 + ko);
    fa0l[ks] = *(const bf16x8*)(Al + arow0 + ko);
    fa1l[ks] = *(const bf16x8*)(Al + arow1 + ko);
    fb0h[ks] = *(const bf16x8*)(Bh + brow0 + ko);
    fb1h[ks] = *(const bf16x8*)(Bh + brow1 + ko);
    fb0l[ks] = *(const bf16x8*)(Bl + brow0 + ko);
    fb1l[ks] = *(const bf16x8*)(Bl + brow1 + ko);
  }
  f32x4 acc00 = {0,0,0,0}, acc01 = {0,0,0,0}, acc10 = {0,0,0,0}, acc11 = {0,0,0,0};
  #pragma unroll
  for (int ks = 0; ks < 4; ++ks) {
    acc00 = MFMA(fa0h[ks], fb0h[ks], acc00);
    acc00 = MFMA(fa0h[ks], fb0l[ks], acc00);
    acc00 = MFMA(fa0l[ks], fb0h[ks], acc00);
    acc01 = MFMA(fa0h[ks], fb1h[ks], acc01);
    acc01 = MFMA(fa0h[ks], fb1l[ks], acc01);
    acc01 = MFMA(fa0l[ks], fb1h[ks], acc01);
    acc10 = MFMA(fa1h[ks], fb0h[ks], acc10);
    acc10 = MFMA(fa1h[ks], fb0l[ks], acc10);
    acc10 = MFMA(fa1l[ks], fb0h[ks], acc10);
    acc11 = MFMA(fa1h[ks], fb1h[ks], acc11);
    acc11 = MFMA(fa1h[ks], fb1l[ks], acc11);
    acc11 = MFMA(fa1l[ks], fb1h[ks], acc11);
  }
  #pragma unroll
  for (int i = 0; i < 2; ++i) {
    #pragma unroll
    for (int j = 0; j < 2; ++j) {
      const f32x4& a = (i == 0) ? (j == 0 ? acc00 : acc01) : (j == 0 ? acc10 : acc11);
      #pragma unroll
      for (int r = 0; r < 4; ++r) {
        int row = m0 + wr*32 + i*16 + (lane >> 4)*4 + r;
        int col = col0 + n0 + wc*32 + j*16 + (lane & 15);
        float v = a[r];
        if (bias)  v += bias[col - col0];
        if (resid) v += resid[(size_t)row * Ldc + col];
        if (relu)  v = fmaxf(v, 0.f);
        size_t o = (size_t)row * Ldc + col;
        if (C) C[o] = v;
        if (Ch) {
          if (Cl) {
            unsigned short hh, ll;
            hilo(v, hh, ll);
            Ch[o] = hh; Cl[o] = ll;
          } else {
            Ch[o] = bf16rne(v);
          }
        }
      }
    }
  }
}

// ---------------- MFMA GEMM 64x64 tile, 8 waves, in-block split-K2 (K=512) --------
__global__ __launch_bounds__(512) void bf_gemm_sk_kernel(
    const unsigned short* __restrict__ Ah, const unsigned short* __restrict__ Al,
    const unsigned short* __restrict__ Bh, const unsigned short* __restrict__ Bl,
    float* __restrict__ C, unsigned short* __restrict__ Ch, unsigned short* __restrict__ Cl,
    int Ldc, int col0, int Kd, const float* __restrict__ bias,
    const float* __restrict__ resid, int relu) {
  __shared__ float red[64][65];
  int tid = threadIdx.x;
  int m0 = blockIdx.y * 64, n0 = blockIdx.x * 64;
  int wid = tid >> 6, lane = tid & 63;
  int kg = wid >> 2;
  int w4 = wid & 3;
  int wr = w4 >> 1, wc = w4 & 1;
  int fr = lane & 15, fkb = lane >> 4;
  int Kh = Kd >> 1;
  size_t arow0 = (size_t)(m0 + wr*32 + fr) * Kd + (size_t)kg * Kh;
  size_t arow1 = arow0 + (size_t)16 * Kd;
  size_t brow0 = (size_t)(n0 + wc*32 + fr) * Kd + (size_t)kg * Kh;
  size_t brow1 = brow0 + (size_t)16 * Kd;
  f32x4 acc00 = {0,0,0,0}, acc01 = {0,0,0,0}, acc10 = {0,0,0,0}, acc11 = {0,0,0,0};
  int ko = fkb * 8;
  bf16x8 a0h = *(const bf16x8*)(Ah + arow0 + ko);
  bf16x8 a1h = *(const bf16x8*)(Ah + arow1 + ko);
  bf16x8 a0l = *(const bf16x8*)(Al + arow0 + ko);
  bf16x8 a1l = *(const bf16x8*)(Al + arow1 + ko);
  bf16x8 b0h = *(const bf16x8*)(Bh + brow0 + ko);
  bf16x8 b1h = *(const bf16x8*)(Bh + brow1 + ko);
  bf16x8 b0l = *(const bf16x8*)(Bl + brow0 + ko);
  bf16x8 b1l = *(const bf16x8*)(Bl + brow1 + ko);
  for (int k0 = 32; k0 < Kh; k0 += 32) {
    int kn = k0 + fkb * 8;
    bf16x8 na0h = *(const bf16x8*)(Ah + arow0 + kn);
    bf16x8 na1h = *(const bf16x8*)(Ah + arow1 + kn);
    bf16x8 na0l = *(const bf16x8*)(Al + arow0 + kn);
    bf16x8 na1l = *(const bf16x8*)(Al + arow1 + kn);
    bf16x8 nb0h = *(const bf16x8*)(Bh + brow0 + kn);
    bf16x8 nb1h = *(const bf16x8*)(Bh + brow1 + kn);
    bf16x8 nb0l = *(const bf16x8*)(Bl + brow0 + kn);
    bf16x8 nb1l = *(const bf16x8*)(Bl + brow1 + kn);
    acc00 = MFMA(a0h, b0h, acc00); acc00 = MFMA(a0h, b0l, acc00); acc00 = MFMA(a0l, b0h, acc00);
    acc01 = MFMA(a0h, b1h, acc01); acc01 = MFMA(a0h, b1l, acc01); acc01 = MFMA(a0l, b1h, acc01);
    acc10 = MFMA(a1h, b0h, acc10); acc10 = MFMA(a1h, b0l, acc10); acc10 = MFMA(a1l, b0h, acc10);
    acc11 = MFMA(a1h, b1h, acc11); acc11 = MFMA(a1h, b1l, acc11); acc11 = MFMA(a1l, b1h, acc11);
    a0h = na0h; a1h = na1h; a0l = na0l; a1l = na1l;
    b0h = nb0h; b1h = nb1h; b0l = nb0l; b1l = nb1l;
  }
  acc00 = MFMA(a0h, b0h, acc00); acc00 = MFMA(a0h, b0l, acc00); acc00 = MFMA(a0l, b0h, acc00);
  acc01 = MFMA(a0h, b1h, acc01); acc01 = MFMA(a0h, b1l, acc01); acc01 = MFMA(a0l, b1h, acc01);
  acc10 = MFMA(a1h, b0h, acc10); acc10 = MFMA(a1h, b0l, acc10); acc10 = MFMA(a1l, b0h, acc10);
  acc11 = MFMA(a1h, b1h, acc11); acc11 = MFMA(a1h, b1l, acc11); acc11 = MFMA(a1l, b1h, acc11);
  if (kg == 1) {
    #pragma unroll
    for (int i = 0; i < 2; ++i) {
      #pragma unroll
      for (int j = 0; j < 2; ++j) {
        const f32x4& a = (i == 0) ? (j == 0 ? acc00 : acc01) : (j == 0 ? acc10 : acc11);
        #pragma unroll
        for (int r = 0; r < 4; ++r) {
          int lr = wr*32 + i*16 + (lane >> 4)*4 + r;
          int lc = wc*32 + j*16 + (lane & 15);
          red[lr][lc] = a[r];
        }
      }
    }
  }
  __syncthreads();
  if (kg == 0) {
    #pragma unroll
    for (int i = 0; i < 2; ++i) {
      #pragma unroll
      for (int j = 0; j < 2; ++j) {
        const f32x4& a = (i == 0) ? (j == 0 ? acc00 : acc01) : (j == 0 ? acc10 : acc11);
        #pragma unroll
        for (int r = 0; r < 4; ++r) {
          int lr = wr*32 + i*16 + (lane >> 4)*4 + r;
          int lc = wc*32 + j*16 + (lane & 15);
          int row = m0 + lr;
          int col = col0 + n0 + lc;
          float v = a[r] + red[lr][lc];
          if (bias)  v += bias[col - col0];
          if (resid) v += resid[(size_t)row * Ldc + col];
          if (relu)  v = fmaxf(v, 0.f);
          size_t o = (size_t)row * Ldc + col;
          if (C) C[o] = v;
          if (Ch) {
            unsigned short hh, ll;
            hilo(v, hh, ll);
            Ch[o] = hh; Cl[o] = ll;
          }
        }
      }
    }
  }
}

// ---------------- rstd[b,m] = 1/std (std==0 -> 1) ----------------
__global__ void rstd_kernel(const float* __restrict__ G0, const float* __restrict__ G1,
                            const float* __restrict__ mu, float* __restrict__ rstd) {
  int bm = blockIdx.x * 256 + threadIdx.x;
  int b = bm >> 9, m = bm & (MM - 1);
  size_t di = (size_t)b * MM * MM + (size_t)m * MM + m;
  float g = G0[di] + G1[di];
  float mm = mu[bm];
  float cov = (g - 1024.f * mm * mm) * (1.f / 1023.f);
  float sd = sqrtf(fmaxf(cov, 0.f));
  rstd[bm] = (sd == 0.f) ? 1.f : (1.f / sd);
}

// ---------------- neighbors: packed-u32 argsort positions 1..16 ----------------
// key = (sortable_fp32(value) & ~511) | n  -> one u32 min-reduce carries both value
// and index. Ties in truncated value resolve by smaller n (same lexicographic rule).
__global__ void select_kernel(const float* __restrict__ G0, const float* __restrict__ G1,
                              const float* __restrict__ mu,
                              const float* __restrict__ rstd, int* __restrict__ nb) {
  int w = threadIdx.x >> 6, lane = threadIdx.x & 63;
  int bm = blockIdx.x * 4 + w;
  int b = bm >> 9, m = bm & (MM - 1);
  size_t rowoff = (size_t)b * MM * MM + (size_t)m * MM;
  const float* Gr0 = G0 + rowoff;
  const float* Gr1 = G1 + rowoff;
  const float* mub = mu + b * MM;
  const float* rsb = rstd + b * MM;
  float mm = mub[m], rm = rsb[m];
  unsigned key[8];
  int excl = 0;
  #pragma unroll
  for (int j = 0; j < 8; ++j) {
    int n = lane + j * 64;
    float cov = ((Gr0[n] + Gr1[n]) - 1024.f * mm * mub[n]) * (1.f / 1023.f);
    float val = cov * rm * rsb[n];
    union { float f; unsigned u; } cv; cv.f = val;
    unsigned s = cv.u ^ ((unsigned)((int)cv.u >> 31) | 0x80000000u);
    key[j] = (s & 0xFFFFFE00u) | (unsigned)n;
  }
  int* out = nb + (size_t)bm * KK;
  for (int it = 0; it < KK + 1; ++it) {
    unsigned bk = 0xFFFFFFFFu;
    #pragma unroll
    for (int j = 0; j < 8; ++j) {
      if (!((excl >> j) & 1)) bk = bk < key[j] ? bk : key[j];
    }
    #pragma unroll
    for (int off = 32; off; off >>= 1) {
      unsigned ok = __shfl_down(bk, off);
      bk = bk < ok ? bk : ok;
    }
    bk = __shfl(bk, 0);
    int n = (int)(bk & 511u);
    if ((n & 63) == lane) excl |= 1 << (n >> 6);
    if (it > 0 && lane == 0) out[it - 1] = n;
  }
}

// ---------------- degree counts ----------------
__global__ void count_kernel(const int* __restrict__ nb, int* __restrict__ cnt) {
  int e = blockIdx.x * 256 + threadIdx.x;
  int b = e >> 13, i = e & 8191;
  int dst = b * MM + nb[(size_t)b * 8192 + i];
  atomicAdd(&cnt[dst], 1);
}

// ---------------- scan + cursor + dinv ----------------
__global__ void scan_kernel(const int* __restrict__ cnt, int* __restrict__ offs,
                            int* __restrict__ curs, float* __restrict__ dinv) {
  __shared__ int part[256];
  int tid = threadIdx.x;
  int base = tid * 32;
  int local[32];
  int s = 0;
  #pragma unroll
  for (int i = 0; i < 32; ++i) { local[i] = cnt[base + i]; s += local[i]; }
  part[tid] = s;
  __syncthreads();
  for (int off = 1; off < 256; off <<= 1) {
    int v = (tid >= off) ? part[tid - off] : 0;
    __syncthreads();
    part[tid] += v;
    __syncthreads();
  }
  int run = part[tid] - s;
  #pragma unroll
  for (int i = 0; i < 32; ++i) {
    int n = base + i;
    offs[n] = run; curs[n] = run;
    run += local[i];
    dinv[n] = rsqrtf((float)(local[i] + 1));
  }
  if (tid == 255) offs[NNODE] = run;
}

// ---------------- scatter reverse edge lists ----------------
__global__ void scatter_kernel(const int* __restrict__ nb, int* __restrict__ curs,
                               int* __restrict__ lists) {
  int e = blockIdx.x * 256 + threadIdx.x;
  int b = e >> 13, i = e & 8191;
  int dst = b * MM + nb[(size_t)b * 8192 + i];
  int src = b * MM + (i & (MM - 1));
  int pos = atomicAdd(&curs[dst], 1);
  lists[pos] = src;
}

// ---------------- GCN aggregation: fp32 gather in, bf16 hi/lo out ----------------
__global__ void agg_kernel(const float* __restrict__ xw, const float* __restrict__ dinv,
                           const int* __restrict__ offs, const int* __restrict__ lists,
                           const float* __restrict__ bias,
                           unsigned short* __restrict__ outh,
                           unsigned short* __restrict__ outl) {
  int n = blockIdx.x * 2 + (threadIdx.x >> 7);
  int c = threadIdx.x & 127;
  float dn = dinv[n];
  float s = dn * xw[(size_t)n * DD + c];
  int e0 = offs[n], e1 = offs[n + 1];
  for (int e = e0; e < e1; ++e) {
    int src = lists[e];
    s += dinv[src] * xw[(size_t)src * DD + c];
  }
  float v = fmaxf(dn * s + bias[c], 0.f);
  unsigned short hh, ll;
  hilo(v, hh, ll);
  size_t o = (size_t)n * DD + c;
  outh[o] = hh; outl[o] = ll;
}

// ---------------- MFMA flash attention ----------------
__global__ __launch_bounds__(256) void attn_mfma_kernel(
    const unsigned short* __restrict__ Qb16, const unsigned short* __restrict__ KV16,
    int kvoff,
    unsigned short* __restrict__ outh, unsigned short* __restrict__ outl) {
  __shared__ unsigned short Kl[512 * 16];     // [key][16d], row 32B
  __shared__ unsigned short VT[16 * 520];     // [d][520 keys], row 1040B
  __shared__ unsigned short Pl[64 * 136];     // [q][136 keys], row 272B
  int bx = blockIdx.x;
  int qc = bx & 7;
  int h  = (bx >> 3) & 7;
  int b  = bx >> 6;
  int tid = threadIdx.x;

  for (int u = tid; u < 1024; u += 256) {
    int row = u >> 1, half = u & 1;
    const unsigned short* src = KV16 + (size_t)(b * MM + row) * 512 + kvoff + h * 16 + half * 8;
    *(uint4*)&Kl[row * 16 + half * 8] = *(const uint4*)src;
  }
  for (int key = tid; key < 512; key += 256) {
    const unsigned short* src = KV16 + (size_t)(b * MM + key) * 512 + kvoff + 128 + h * 16;
    unsigned short tmp[16];
    *(uint4*)&tmp[0] = *(const uint4*)src;
    *(uint4*)&tmp[8] = *(const uint4*)(src + 8);
    #pragma unroll
    for (int d = 0; d < 16; ++d) VT[d * 520 + key] = tmp[d];
  }
  __syncthreads();

  int wid = tid >> 6, lane = tid & 63;
  int lq = lane & 15, g = lane >> 4;
  bf16x8 zz = {0,0,0,0,0,0,0,0};
  bf16x8 qf = zz;
  if (lane < 32) {
    int qrow = b * MM + qc * 64 + wid * 16 + lq;
    qf = *(const bf16x8*)(Qb16 + (size_t)qrow * 128 + h * 16 + g * 8);
  }
  float m = -1e30f, lp = 0.f;
  f32x4 o = {0,0,0,0};
  int prow = (wid * 16 + lq) * 136;

  for (int c4 = 0; c4 < 4; ++c4) {
    int kbase = c4 * 128;
    f32x4 s[8];
    f32x4 zc = {0,0,0,0};
    #pragma unroll
    for (int t = 0; t < 8; ++t) {
      bf16x8 kf = zz;
      if (lane < 32) kf = *(const bf16x8*)&Kl[(kbase + t * 16 + lq) * 16 + g * 8];
      s[t] = MFMA(kf, qf, zc);
    }
    float tm = -1e30f;
    #pragma unroll
    for (int t = 0; t < 8; ++t) {
      tm = fmaxf(tm, fmaxf(fmaxf(s[t][0], s[t][1]), fmaxf(s[t][2], s[t][3])));
    }
    tm = fmaxf(tm, __shfl_xor(tm, 16));
    tm = fmaxf(tm, __shfl_xor(tm, 32));
    float nm = fmaxf(m, 0.25f * tm);
    float esc = __expf(m - nm);
    m = nm;
    float ls = 0.f;
    #pragma unroll
    for (int t = 0; t < 8; ++t) {
      float p0 = __expf(0.25f * s[t][0] - nm);
      float p1 = __expf(0.25f * s[t][1] - nm);
      float p2 = __expf(0.25f * s[t][2] - nm);
      float p3 = __expf(0.25f * s[t][3] - nm);
      ls += (p0 + p1) + (p2 + p3);
      unsigned w0 = (unsigned)bf16rne(p0) | ((unsigned)bf16rne(p1) << 16);
      unsigned w1 = (unsigned)bf16rne(p2) | ((unsigned)bf16rne(p3) << 16);
      int kc = t * 16 + g * 4;
      *(unsigned*)&Pl[prow + kc]     = w0;
      *(unsigned*)&Pl[prow + kc + 2] = w1;
    }
    lp = lp * esc + ls;
    float e0 = __shfl(esc, g * 4 + 0);
    float e1 = __shfl(esc, g * 4 + 1);
    float e2 = __shfl(esc, g * 4 + 2);
    float e3 = __shfl(esc, g * 4 + 3);
    o[0] *= e0; o[1] *= e1; o[2] *= e2; o[3] *= e3;
    #pragma unroll
    for (int c = 0; c < 4; ++c) {
      bf16x8 pf = *(const bf16x8*)&Pl[prow + c * 32 + g * 8];
      bf16x8 vf = *(const bf16x8*)&VT[lq * 520 + kbase + c * 32 + g * 8];
      o = MFMA(pf, vf, o);
    }
  }
  lp += __shfl_xor(lp, 16);
  lp += __shfl_xor(lp, 32);
  float linv = 1.f / lp;
  float l0 = __shfl(linv, g * 4 + 0);
  float l1 = __shfl(linv, g * 4 + 1);
  float l2 = __shfl(linv, g * 4 + 2);
  float l3 = __shfl(linv, g * 4 + 3);
  float vv[4] = {o[0] * l0, o[1] * l1, o[2] * l2, o[3] * l3};
  #pragma unroll
  for (int r = 0; r < 4; ++r) {
    int qrow = b * MM + qc * 64 + wid * 16 + g * 4 + r;
    size_t off = (size_t)qrow * DD + h * 16 + lq;
    unsigned short hh, ll;
    hilo(vv[r], hh, ll);
    outh[off] = hh; outl[off] = ll;
  }
}

// ---------------- layernorm over D=128: fp32 out + optional bf16 hi/lo out --------
__global__ void ln_kernel(const float* __restrict__ x, const float* __restrict__ g,
                          const float* __restrict__ bb, float* __restrict__ out,
                          unsigned short* __restrict__ outh,
                          unsigned short* __restrict__ outl) {
  int row = blockIdx.x * 4 + (threadIdx.x >> 6);
  int lane = threadIdx.x & 63;
  float2 xv = *(const float2*)&x[(size_t)row * DD + lane * 2];
  float s = xv.x + xv.y;
  #pragma unroll
  for (int off = 1; off < 64; off <<= 1) s += __shfl_xor(s, off);
  float mu = s * (1.f / 128.f);
  float d0 = xv.x - mu, d1 = xv.y - mu;
  float sq = d0 * d0 + d1 * d1;
  #pragma unroll
  for (int off = 1; off < 64; off <<= 1) sq += __shfl_xor(sq, off);
  float rs = rsqrtf(sq * (1.f / 128.f) + 1e-5f);
  float2 gg = *(const float2*)&g[lane * 2];
  float2 bv = *(const float2*)&bb[lane * 2];
  float2 y;
  y.x = d0 * rs * gg.x + bv.x;
  y.y = d1 * rs * gg.y + bv.y;
  *(float2*)&out[(size_t)row * DD + lane * 2] = y;
  if (outh) {
    unsigned short h0, l0, h1, l1;
    hilo(y.x, h0, l0); hilo(y.y, h1, l1);
    unsigned hh = (unsigned)h0 | ((unsigned)h1 << 16);
    unsigned ll = (unsigned)l0 | ((unsigned)l1 << 16);
    *(unsigned*)&outh[(size_t)row * DD + lane * 2] = hh;
    *(unsigned*)&outl[(size_t)row * DD + lane * 2] = ll;
  }
}

extern "C" void kernel_launch(void* const* d_in, const int* in_sizes, int n_in,
                              void* d_out, int out_size, void* d_ws, size_t ws_size,
                              hipStream_t stream) {
  (void)in_sizes; (void)n_in; (void)out_size; (void)ws_size;
  const float* enc  = (const float*)d_in[0];
  const float* xenc = (const float*)d_in[1];
  const float* gw1  = (const float*)d_in[2];
  const float* gb1  = (const float*)d_in[3];
  const float* gw2  = (const float*)d_in[4];
  const float* gb2  = (const float*)d_in[5];
  const float* Wq   = (const float*)d_in[6];
  const float* Wk   = (const float*)d_in[7];
  const float* Wv   = (const float*)d_in[8];
  const float* Wo   = (const float*)d_in[9];
  const float* ln1g = (const float*)d_in[10];
  const float* ln1b = (const float*)d_in[11];
  const float* W1   = (const float*)d_in[12];
  const float* b1   = (const float*)d_in[13];
  const float* W2   = (const float*)d_in[14];
  const float* b2   = (const float*)d_in[15];
  const float* ln2g = (const float*)d_in[16];
  const float* ln2b = (const float*)d_in[17];
  float* outp = (float*)d_out;

  char* w = (char*)d_ws;
  auto alloc = [&](size_t bytes) -> char* {
    char* p = w;
    w += (bytes + 255) & ~(size_t)255;
    return p;
  };
  float* mu    = (float*)alloc((size_t)NNODE * 4);
  float* rstd  = (float*)alloc((size_t)NNODE * 4);
  float* dinv  = (float*)alloc((size_t)NNODE * 4);
  float* mpart = (float*)alloc((size_t)8 * NNODE * 4);
  int*   nb    = (int*)  alloc((size_t)NEDGE * 4);
  int*   cnt   = (int*)  alloc((size_t)NNODE * 4);
  int*   offs  = (int*)  alloc((size_t)(NNODE + 1) * 4);
  int*   curs  = (int*)  alloc((size_t)NNODE * 4);
  int*   lists = (int*)  alloc((size_t)NEDGE * 4);
  float* gram  = (float*)alloc((size_t)BB * MM * MM * 4);   // 16MB: G0; later Qb16+KV16
  float* gram2 = (float*)alloc((size_t)BB * MM * MM * 4);   // 16MB: G1; later ff hi/lo
  float* bufx  = (float*)alloc((size_t)NNODE * DD * 4);
  float* bufxl = (float*)alloc((size_t)NNODE * DD * 4);
  float* bufh  = (float*)alloc((size_t)NNODE * DD * 4);
  float* bufh1 = (float*)alloc((size_t)NNODE * DD * 4);
  unsigned short* xth  = (unsigned short*)alloc((size_t)BB * MM * LL * 2);  // 16MB
  unsigned short* xtl  = (unsigned short*)alloc((size_t)BB * MM * LL * 2);  // 16MB
  unsigned short* wTh  = (unsigned short*)alloc((size_t)425984 * 2);
  unsigned short* wTl  = (unsigned short*)alloc((size_t)425984 * 2);
  unsigned short* ench = (unsigned short*)alloc((size_t)NNODE * DD * 2);
  unsigned short* encl = (unsigned short*)alloc((size_t)NNODE * DD * 2);
  unsigned short* x1h  = (unsigned short*)alloc((size_t)NNODE * DD * 2);
  unsigned short* x1l  = (unsigned short*)alloc((size_t)NNODE * DD * 2);
  unsigned short* kvbh = (unsigned short*)alloc((size_t)NNODE * DD * 2);
  unsigned short* kvbl = (unsigned short*)alloc((size_t)NNODE * DD * 2);
  unsigned short* xlh  = (unsigned short*)alloc((size_t)NNODE * DD * 2);
  unsigned short* xll  = (unsigned short*)alloc((size_t)NNODE * DD * 2);
  unsigned short* h1h  = (unsigned short*)alloc((size_t)NNODE * DD * 2);
  unsigned short* h1l  = (unsigned short*)alloc((size_t)NNODE * DD * 2);
  unsigned short* sdh  = (unsigned short*)alloc((size_t)NNODE * DD * 2);
  unsigned short* sdl  = (unsigned short*)alloc((size_t)NNODE * DD * 2);

  // Phase aliases (valid after graph-build consumes G0/G1):
  unsigned short* Qb16 = (unsigned short*)gram;                       // 2 MB [NNODE][128]
  unsigned short* KV16 = (unsigned short*)(gram + (size_t)1048576);   // 8 MB [NNODE][512]
  unsigned short* ffh = (unsigned short*)gram2;                         // 8MB
  unsigned short* ffl = (unsigned short*)gram2 + (size_t)NNODE * NDFF;  // 8MB

  const unsigned short* gw1Th = wTh,         *gw1Tl = wTl;
  const unsigned short* gw2Th = wTh + 16384, *gw2Tl = wTl + 16384;
  const unsigned short* KVTh01 = wTh + (size_t)2 * 16384;   // [Wk0;Wv0;Wk1;Wv1] [512][128]
  const unsigned short* KVTl01 = wTl + (size_t)2 * 16384;
  auto WqTh = [&](int l) { return wTh + (size_t)(6 + l) * 16384; };
  auto WqTl = [&](int l) { return wTl + (size_t)(6 + l) * 16384; };
  auto WoTh = [&](int l) { return wTh + (size_t)(8 + l) * 16384; };
  auto WoTl = [&](int l) { return wTl + (size_t)(8 + l) * 16384; };
  auto W1Th = [&](int l) { return wTh + 163840 + (size_t)l * 65536; };
  auto W1Tl = [&](int l) { return wTl + 163840 + (size_t)l * 65536; };
  auto W2Th = [&](int l) { return wTh + 294912 + (size_t)l * 65536; };
  auto W2Tl = [&](int l) { return wTl + 294912 + (size_t)l * 65536; };

  auto gemm = [&](const unsigned short* Ah, const unsigned short* Al,
                  const unsigned short* Bh, const unsigned short* Bl,
                  float* C, unsigned short* Ch, unsigned short* Cl,
                  int Mr, int Ncols, int Ldc, int col0, int Kd,
                  const float* bias, const float* resid, int relu) {
    dim3 g(Ncols / 64, Mr / 64);
    if (Kd == 128) {
      bf_gemm_k128_kernel<<<g, 256, 0, stream>>>(Ah, Al, Bh, Bl, C, Ch, Cl, Ldc, col0,
                                                 bias, resid, relu);
    } else {
      bf_gemm_sk_kernel<<<g, 512, 0, stream>>>(Ah, Al, Bh, Bl, C, Ch, Cl, Ldc, col0, Kd,
                                               bias, resid, relu);
    }
  };

  // ---- transposes & splits ----
  transpose_x_kernel<<<dim3(16, 32, 16), 256, 0, stream>>>(xenc, xth, xtl);
  transpose_w_kernel<<<dim3(16, 16, 14), 256, 0, stream>>>(gw1, gw2, Wq, Wk, Wv, Wo, W1, W2, wTh, wTl);
  split_kernel<<<(NNODE * DD / 4) / 256, 256, 0, stream>>>(enc, ench, encl);

  // ---- graph build ----
  colmean_part_kernel<<<dim3(32, 8), 256, 0, stream>>>(xenc, mpart);
  colmean_finish_kernel<<<NNODE / 256, 256, 0, stream>>>(mpart, mu);
  gram_kernel<<<dim3(36, BB, 2), 256, 0, stream>>>(xth, xtl, gram, gram2);
  rstd_kernel<<<NNODE / 256, 256, 0, stream>>>(gram, gram2, mu, rstd);
  select_kernel<<<NNODE / 4, 256, 0, stream>>>(gram, gram2, mu, rstd, nb);
  hipMemsetAsync(cnt, 0, (size_t)NNODE * 4, stream);
  count_kernel<<<NEDGE / 256, 256, 0, stream>>>(nb, cnt);
  scan_kernel<<<1, 256, 0, stream>>>(cnt, offs, curs, dinv);
  scatter_kernel<<<NEDGE / 256, 256, 0, stream>>>(nb, curs, lists);

  // ---- 2-layer GCN (xw scratch uses bufx) ----
  gemm(ench, encl, gw1Th, gw1Tl, bufx, nullptr, nullptr, NNODE, DD, DD, 0, DD,
       nullptr, nullptr, 0);
  agg_kernel<<<NNODE / 2, 256, 0, stream>>>(bufx, dinv, offs, lists, gb1, x1h, x1l);
  gemm(x1h, x1l, gw2Th, gw2Tl, bufx, nullptr, nullptr, NNODE, DD, DD, 0, DD,
       nullptr, nullptr, 0);
  agg_kernel<<<NNODE / 2, 256, 0, stream>>>(bufx, dinv, offs, lists, gb2, kvbh, kvbl);

  // ---- fused KV projection for BOTH layers -> single bf16 [NNODE][512] ----
  gemm(kvbh, kvbl, KVTh01, KVTl01, nullptr, KV16, nullptr, NNODE, 512, 512, 0, DD,
       nullptr, nullptr, 0);

  // ---- transformer encoder layers ----
  for (int l = 0; l < 2; ++l) {
    const float* hq = (l == 0) ? enc : bufh1;
    const unsigned short* hqh = (l == 0) ? ench : h1h;
    const unsigned short* hql = (l == 0) ? encl : h1l;
    gemm(hqh, hql, WqTh(l), WqTl(l), nullptr, Qb16, nullptr, NNODE, DD, DD, 0, DD,
         nullptr, nullptr, 0);                                         // q bf16
    attn_mfma_kernel<<<BB * HH * 8, 256, 0, stream>>>(Qb16, KV16, l * 256, sdh, sdl);
    gemm(sdh, sdl, WoTh(l), WoTl(l), bufx, nullptr, nullptr, NNODE, DD, DD, 0, DD,
         nullptr, hq, 0);
    ln_kernel<<<NNODE / 4, 256, 0, stream>>>(bufx, ln1g + l * DD, ln1b + l * DD, bufxl, xlh, xll);
    gemm(xlh, xll, W1Th(l), W1Tl(l), nullptr, ffh, ffl, NNODE, NDFF, NDFF, 0, DD,
         b1 + l * NDFF, nullptr, 1);
    gemm(ffh, ffl, W2Th(l), W2Tl(l), bufh, nullptr, nullptr, NNODE, DD, DD, 0, NDFF,
         b2 + l * DD, bufxl, 0);
    if (l == 1) {
      ln_kernel<<<NNODE / 4, 256, 0, stream>>>(bufh, ln2g + l * DD, ln2b + l * DD,
                                               outp, nullptr, nullptr);
    } else {
      ln_kernel<<<NNODE / 4, 256, 0, stream>>>(bufh, ln2g + l * DD, ln2b + l * DD,
                                               bufh1, h1h, h1l);
    }
  }
}

// Round 20
// 358.921 us; speedup vs baseline: 1.1550x; 1.0531x over previous
//
#include <hip/hip_runtime.h>
#include <math.h>

#define BB 16
#define MM 512
#define LL 1024
#define DD 128
#define KK 16
#define HH 8
#define DHH 16
#define NDFF 512
#define NNODE (BB*MM)      // 8192
#define NEDGE (NNODE*KK)   // 131072

typedef __attribute__((ext_vector_type(8))) short bf16x8;
typedef __attribute__((ext_vector_type(4))) float f32x4;
#define MFMA(a,b,c) __builtin_amdgcn_mfma_f32_16x16x32_bf16(a,b,c,0,0,0)

__device__ inline unsigned short bf16rne(float x) {
  union { float f; unsigned u; } v; v.f = x;
  return (unsigned short)((v.u + 0x7FFFu + ((v.u >> 16) & 1u)) >> 16);
}
__device__ inline float bf16tof(unsigned short h) {
  union { unsigned u; float f; } v; v.u = ((unsigned)h) << 16; return v.f;
}
__device__ inline void hilo(float x, unsigned short& h, unsigned short& l) {
  h = bf16rne(x);
  l = bf16rne(x - bf16tof(h));
}

// async global->LDS, 16B per lane (linear dest = wave-uniform base + lane*16)
__device__ inline void async16(const void* g, void* l) {
  __builtin_amdgcn_global_load_lds(
      (const __attribute__((address_space(1))) unsigned int*)g,
      (__attribute__((address_space(3))) unsigned int*)l, 16, 0, 0);
}

// ---------------- transpose x_enc [b][l][m] -> chunked k-major bf16 hi/lo ----------
__global__ __launch_bounds__(256) void transpose_x_kernel(const float* __restrict__ X,
                                                          unsigned short* __restrict__ XTh,
                                                          unsigned short* __restrict__ XTl) {
  __shared__ float t[32][33];
  int b = blockIdx.z;
  int m0 = blockIdx.x * 32, l0 = blockIdx.y * 32;
  int c = threadIdx.x & 31, r = threadIdx.x >> 5;   // r 0..7
  const float* Xb = X + (size_t)b * LL * MM;
  #pragma unroll
  for (int i = 0; i < 4; ++i)
    t[r + i*8][c] = Xb[(size_t)(l0 + r + i*8) * MM + m0 + c];
  __syncthreads();
  int R = m0 >> 6;
  int rbase = m0 & 63;
  size_t base = ((size_t)(b * 8 + R)) * 65536 + (size_t)(l0 >> 5) * 2048
              + (size_t)(c >> 3) * 512 + (c & 7);
  #pragma unroll
  for (int i = 0; i < 4; ++i) {
    unsigned short h, l;
    hilo(t[c][r + i*8], h, l);
    size_t idx = base + (size_t)(rbase + r + i*8) * 8;
    XTh[idx] = h; XTl[idx] = l;
  }
}

// ---------------- transpose weights [K][N] -> bf16 hi/lo [N][K] ----------------
__global__ __launch_bounds__(256) void transpose_w_kernel(
    const float* __restrict__ gw1, const float* __restrict__ gw2,
    const float* __restrict__ Wq, const float* __restrict__ Wk,
    const float* __restrict__ Wv, const float* __restrict__ Wo,
    const float* __restrict__ W1, const float* __restrict__ W2,
    unsigned short* __restrict__ wTh, unsigned short* __restrict__ wTl) {
  int z = blockIdx.z;
  const float* src; int K, N; size_t doff;
  if (z < 10) {
    K = 128; N = 128;
    switch (z) {
      case 0: src = gw1;         doff = 0;         break;
      case 1: src = gw2;         doff = 16384;     break;
      case 2: src = Wk;          doff = 2*16384;   break;
      case 3: src = Wv;          doff = 3*16384;   break;
      case 4: src = Wk + 16384;  doff = 4*16384;   break;
      case 5: src = Wv + 16384;  doff = 5*16384;   break;
      case 6: src = Wq;          doff = 6*16384;   break;
      case 7: src = Wq + 16384;  doff = 7*16384;   break;
      case 8: src = Wo;          doff = 8*16384;   break;
      default: src = Wo + 16384; doff = 9*16384;   break;
    }
  } else if (z < 12) {
    K = 128; N = 512; doff = 163840 + (size_t)(z - 10) * 65536;
    src = W1 + (size_t)(z - 10) * 65536;
  } else {
    K = 512; N = 128; doff = 294912 + (size_t)(z - 12) * 65536;
    src = W2 + (size_t)(z - 12) * 65536;
  }
  int k0 = blockIdx.x * 32, n0 = blockIdx.y * 32;
  if (k0 >= K || n0 >= N) return;
  __shared__ float t[32][33];
  int c = threadIdx.x & 31, r = threadIdx.x >> 5;
  #pragma unroll
  for (int i = 0; i < 4; ++i)
    t[r + i*8][c] = src[(size_t)(k0 + r + i*8) * N + n0 + c];
  __syncthreads();
  #pragma unroll
  for (int i = 0; i < 4; ++i) {
    size_t idx = doff + (size_t)(n0 + r + i*8) * K + k0 + c;
    unsigned short h, l;
    hilo(t[c][r + i*8], h, l);
    wTh[idx] = h; wTl[idx] = l;
  }
}

// ---------------- plain fp32 -> bf16 hi/lo split (for enc) ----------------
__global__ void split_kernel(const float* __restrict__ in,
                             unsigned short* __restrict__ h,
                             unsigned short* __restrict__ l) {
  int i = blockIdx.x * 256 + threadIdx.x;     // per float4
  float4 v = ((const float4*)in)[i];
  unsigned short h0,h1,h2,h3,l0,l1,l2,l3;
  hilo(v.x,h0,l0); hilo(v.y,h1,l1); hilo(v.z,h2,l2); hilo(v.w,h3,l3);
  uint2 hh, ll;
  hh.x = (unsigned)h0 | ((unsigned)h1 << 16); hh.y = (unsigned)h2 | ((unsigned)h3 << 16);
  ll.x = (unsigned)l0 | ((unsigned)l1 << 16); ll.y = (unsigned)l2 | ((unsigned)l3 << 16);
  ((uint2*)h)[i] = hh; ((uint2*)l)[i] = ll;
}

// ---------------- column means (original layout) ----------------
__global__ void colmean_part_kernel(const float* __restrict__ X, float* __restrict__ part) {
  int bm = blockIdx.x * 256 + threadIdx.x;
  int b = bm >> 9, m = bm & (MM - 1);
  int l0 = blockIdx.y * 128;
  const float* p = X + (size_t)b * LL * MM + (size_t)l0 * MM + m;
  float s = 0.f;
  #pragma unroll 8
  for (int l = 0; l < 128; ++l) s += p[(size_t)l * MM];
  part[(size_t)blockIdx.y * NNODE + bm] = s;
}

__global__ void colmean_finish_kernel(const float* __restrict__ part, float* __restrict__ mu) {
  int bm = blockIdx.x * 256 + threadIdx.x;
  float s = 0.f;
  #pragma unroll
  for (int j = 0; j < 8; ++j) s += part[(size_t)j * NNODE + bm];
  mu[bm] = s * (1.f / 1024.f);
}

// ---------------- MFMA gram, XCD-swizzled grid: XCD k owns batches 2k..2k+1 ------
// Flat grid 1152 = 8 XCDs x 144. Dispatch round-robins blockIdx across XCDs, so
// xcd = id&7, j = id>>3; work = xcd*144 + j gives each XCD a contiguous 2-batch
// chunk (4MB = one L2). Bijective (1152 % 8 == 0).
__global__ __launch_bounds__(256) void gram_kernel(const unsigned short* __restrict__ XTh,
                                                   const unsigned short* __restrict__ XTl,
                                                   float* __restrict__ G0,
                                                   float* __restrict__ G1) {
  __shared__ unsigned short lAh[2048], lAl[2048], lBh[2048], lBl[2048];
  int id = blockIdx.x;
  int xcd = id & 7;
  int jj = id >> 3;
  int work = xcd * 144 + jj;          // 0..1151
  int b = work / 72;
  int rem = work - b * 72;
  int z = rem / 36;
  int pi = rem - z * 36;
  int ti = 0, rem2 = pi;
  while (rem2 >= 8 - ti) { rem2 -= 8 - ti; ++ti; }
  int tj = ti + rem2;
  int tid = threadIdx.x;
  int wid = tid >> 6, lane = tid & 63;
  int wr = wid >> 1, wc = wid & 1;
  int fr = lane & 15, fkb = lane >> 4;
  size_t abase = ((size_t)(b * 8 + ti)) * 65536 + (size_t)z * 16 * 2048;
  size_t bbase = ((size_t)(b * 8 + tj)) * 65536 + (size_t)z * 16 * 2048;
  int toff = tid * 8;
  int aoff0 = fkb * 512 + (wr*32 + fr) * 8;
  int aoff1 = aoff0 + 128;
  int boff0 = fkb * 512 + (wc*32 + fr) * 8;
  int boff1 = boff0 + 128;
  f32x4 acc00 = {0,0,0,0}, acc01 = {0,0,0,0}, acc10 = {0,0,0,0}, acc11 = {0,0,0,0};
  for (int s = 0; s < 16; ++s) {
    size_t ao = abase + (size_t)s * 2048 + toff;
    size_t bo = bbase + (size_t)s * 2048 + toff;
    async16(XTh + ao, lAh + toff);
    async16(XTl + ao, lAl + toff);
    async16(XTh + bo, lBh + toff);
    async16(XTl + bo, lBl + toff);
    __syncthreads();
    bf16x8 a0h = *(const bf16x8*)(lAh + aoff0);
    bf16x8 a1h = *(const bf16x8*)(lAh + aoff1);
    bf16x8 a0l = *(const bf16x8*)(lAl + aoff0);
    bf16x8 a1l = *(const bf16x8*)(lAl + aoff1);
    bf16x8 b0h = *(const bf16x8*)(lBh + boff0);
    bf16x8 b1h = *(const bf16x8*)(lBh + boff1);
    bf16x8 b0l = *(const bf16x8*)(lBl + boff0);
    bf16x8 b1l = *(const bf16x8*)(lBl + boff1);
    acc00 = MFMA(a0h, b0h, acc00); acc00 = MFMA(a0h, b0l, acc00); acc00 = MFMA(a0l, b0h, acc00);
    acc01 = MFMA(a0h, b1h, acc01); acc01 = MFMA(a0h, b1l, acc01); acc01 = MFMA(a0l, b1h, acc01);
    acc10 = MFMA(a1h, b0h, acc10); acc10 = MFMA(a1h, b0l, acc10); acc10 = MFMA(a1l, b0h, acc10);
    acc11 = MFMA(a1h, b1h, acc11); acc11 = MFMA(a1h, b1l, acc11); acc11 = MFMA(a1l, b1h, acc11);
    __syncthreads();
  }
  int m0 = ti * 64, n0 = tj * 64;
  float* G = (z ? G1 : G0) + (size_t)b * MM * MM;
  int mirror = (ti != tj);
  #pragma unroll
  for (int i = 0; i < 2; ++i) {
    #pragma unroll
    for (int j = 0; j < 2; ++j) {
      const f32x4& a = (i == 0) ? (j == 0 ? acc00 : acc01) : (j == 0 ? acc10 : acc11);
      #pragma unroll
      for (int r = 0; r < 4; ++r) {
        int row = m0 + wr*32 + i*16 + (lane >> 4)*4 + r;
        int col = n0 + wc*32 + j*16 + (lane & 15);
        float v = a[r];
        G[(size_t)row * MM + col] = v;
        if (mirror) G[(size_t)col * MM + row] = v;
      }
    }
  }
}

// ---------------- MFMA GEMM, K=128 fully unrolled: all 32 frags loaded up front ---
// Epilogue: fp32 C, bf16 hi/lo (Ch+Cl), or single bf16 (Ch only, Cl==null).
__global__ __launch_bounds__(256) void bf_gemm_k128_kernel(
    const unsigned short* __restrict__ Ah, const unsigned short* __restrict__ Al,
    const unsigned short* __restrict__ Bh, const unsigned short* __restrict__ Bl,
    float* __restrict__ C, unsigned short* __restrict__ Ch, unsigned short* __restrict__ Cl,
    int Ldc, int col0, const float* __restrict__ bias,
    const float* __restrict__ resid, int relu) {
  int tid = threadIdx.x;
  int m0 = blockIdx.y * 64, n0 = blockIdx.x * 64;
  int wid = tid >> 6, lane = tid & 63;
  int wr = wid >> 1, wc = wid & 1;
  int fr = lane & 15, fkb = lane >> 4;
  size_t arow0 = (size_t)(m0 + wr*32 + fr) * 128;
  size_t arow1 = arow0 + 16 * 128;
  size_t brow0 = (size_t)(n0 + wc*32 + fr) * 128;
  size_t brow1 = brow0 + 16 * 128;
  bf16x8 fa0h[4], fa1h[4], fa0l[4], fa1l[4];
  bf16x8 fb0h[4], fb1h[4], fb0l[4], fb1l[4];
  #pragma unroll
  for (int ks = 0; ks < 4; ++ks) {
    int ko = ks * 32 + fkb * 8;
    fa0h[ks] = *(const bf16x8*)(Ah + arow0 + ko);
    fa1h[ks] = *(const bf16x8*)(Ah + arow1 + ko);
    fa0l[ks] = *(const bf16x8*)(Al + arow0 + ko);
    fa1l[ks] = *(const bf16x8*)(Al + arow1 + ko);
    fb0h[ks] = *(const bf16x8*)(Bh + brow0 + ko);
    fb1h[ks] = *(const bf16x8*)(Bh + brow1 + ko);
    fb0l[ks] = *(const bf16x8*)(Bl + brow0 + ko);
    fb1l[ks] = *(const bf16x8*)(Bl + brow1 + ko);
  }
  f32x4 acc00 = {0,0,0,0}, acc01 = {0,0,0,0}, acc10 = {0,0,0,0}, acc11 = {0,0,0,0};
  #pragma unroll
  for (int ks = 0; ks < 4; ++ks) {
    acc00 = MFMA(fa0h[ks], fb0h[ks], acc00);
    acc00 = MFMA(fa0h[ks], fb0l[ks], acc00);
    acc00 = MFMA(fa0l[ks], fb0h[ks], acc00);
    acc01 = MFMA(fa0h[ks], fb1h[ks], acc01);
    acc01 = MFMA(fa0h[ks], fb1l[ks], acc01);
    acc01 = MFMA(fa0l[ks], fb1h[ks], acc01);
    acc10 = MFMA(fa1h[ks], fb0h[ks], acc10);
    acc10 = MFMA(fa1h[ks], fb0l[ks], acc10);
    acc10 = MFMA(fa1l[ks], fb0h[ks], acc10);
    acc11 = MFMA(fa1h[ks], fb1h[ks], acc11);
    acc11 = MFMA(fa1h[ks], fb1l[ks], acc11);
    acc11 = MFMA(fa1l[ks], fb1h[ks], acc11);
  }
  #pragma unroll
  for (int i = 0; i < 2; ++i) {
    #pragma unroll
    for (int j = 0; j < 2; ++j) {
      const f32x4& a = (i == 0) ? (j == 0 ? acc00 : acc01) : (j == 0 ? acc10 : acc11);
      #pragma unroll
      for (int r = 0; r < 4; ++r) {
        int row = m0 + wr*32 + i*16 + (lane >> 4)*4 + r;
        int col = col0 + n0 + wc*32 + j*16 + (lane & 15);
        float v = a[r];
        if (bias)  v += bias[col - col0];
        if (resid) v += resid[(size_t)row * Ldc + col];
        if (relu)  v = fmaxf(v, 0.f);
        size_t o = (size_t)row * Ldc + col;
        if (C) C[o] = v;
        if (Ch) {
          if (Cl) {
            unsigned short hh, ll;
            hilo(v, hh, ll);
            Ch[o] = hh; Cl[o] = ll;
          } else {
            Ch[o] = bf16rne(v);
          }
        }
      }
    }
  }
}

// ---------------- MFMA GEMM 64x64 tile, 8 waves, in-block split-K2 (K=512) --------
__global__ __launch_bounds__(512) void bf_gemm_sk_kernel(
    const unsigned short* __restrict__ Ah, const unsigned short* __restrict__ Al,
    const unsigned short* __restrict__ Bh, const unsigned short* __restrict__ Bl,
    float* __restrict__ C, unsigned short* __restrict__ Ch, unsigned short* __restrict__ Cl,
    int Ldc, int col0, int Kd, const float* __restrict__ bias,
    const float* __restrict__ resid, int relu) {
  __shared__ float red[64][65];
  int tid = threadIdx.x;
  int m0 = blockIdx.y * 64, n0 = blockIdx.x * 64;
  int wid = tid >> 6, lane = tid & 63;
  int kg = wid >> 2;
  int w4 = wid & 3;
  int wr = w4 >> 1, wc = w4 & 1;
  int fr = lane & 15, fkb = lane >> 4;
  int Kh = Kd >> 1;
  size_t arow0 = (size_t)(m0 + wr*32 + fr) * Kd + (size_t)kg * Kh;
  size_t arow1 = arow0 + (size_t)16 * Kd;
  size_t brow0 = (size_t)(n0 + wc*32 + fr) * Kd + (size_t)kg * Kh;
  size_t brow1 = brow0 + (size_t)16 * Kd;
  f32x4 acc00 = {0,0,0,0}, acc01 = {0,0,0,0}, acc10 = {0,0,0,0}, acc11 = {0,0,0,0};
  int ko = fkb * 8;
  bf16x8 a0h = *(const bf16x8*)(Ah + arow0 + ko);
  bf16x8 a1h = *(const bf16x8*)(Ah + arow1 + ko);
  bf16x8 a0l = *(const bf16x8*)(Al + arow0 + ko);
  bf16x8 a1l = *(const bf16x8*)(Al + arow1 + ko);
  bf16x8 b0h = *(const bf16x8*)(Bh + brow0 + ko);
  bf16x8 b1h = *(const bf16x8*)(Bh + brow1 + ko);
  bf16x8 b0l = *(const bf16x8*)(Bl + brow0 + ko);
  bf16x8 b1l = *(const bf16x8*)(Bl + brow1 + ko);
  for (int k0 = 32; k0 < Kh; k0 += 32) {
    int kn = k0 + fkb * 8;
    bf16x8 na0h = *(const bf16x8*)(Ah + arow0 + kn);
    bf16x8 na1h = *(const bf16x8*)(Ah + arow1 + kn);
    bf16x8 na0l = *(const bf16x8*)(Al + arow0 + kn);
    bf16x8 na1l = *(const bf16x8*)(Al + arow1 + kn);
    bf16x8 nb0h = *(const bf16x8*)(Bh + brow0 + kn);
    bf16x8 nb1h = *(const bf16x8*)(Bh + brow1 + kn);
    bf16x8 nb0l = *(const bf16x8*)(Bl + brow0 + kn);
    bf16x8 nb1l = *(const bf16x8*)(Bl + brow1 + kn);
    acc00 = MFMA(a0h, b0h, acc00); acc00 = MFMA(a0h, b0l, acc00); acc00 = MFMA(a0l, b0h, acc00);
    acc01 = MFMA(a0h, b1h, acc01); acc01 = MFMA(a0h, b1l, acc01); acc01 = MFMA(a0l, b1h, acc01);
    acc10 = MFMA(a1h, b0h, acc10); acc10 = MFMA(a1h, b0l, acc10); acc10 = MFMA(a1l, b0h, acc10);
    acc11 = MFMA(a1h, b1h, acc11); acc11 = MFMA(a1h, b1l, acc11); acc11 = MFMA(a1l, b1h, acc11);
    a0h = na0h; a1h = na1h; a0l = na0l; a1l = na1l;
    b0h = nb0h; b1h = nb1h; b0l = nb0l; b1l = nb1l;
  }
  acc00 = MFMA(a0h, b0h, acc00); acc00 = MFMA(a0h, b0l, acc00); acc00 = MFMA(a0l, b0h, acc00);
  acc01 = MFMA(a0h, b1h, acc01); acc01 = MFMA(a0h, b1l, acc01); acc01 = MFMA(a0l, b1h, acc01);
  acc10 = MFMA(a1h, b0h, acc10); acc10 = MFMA(a1h, b0l, acc10); acc10 = MFMA(a1l, b0h, acc10);
  acc11 = MFMA(a1h, b1h, acc11); acc11 = MFMA(a1h, b1l, acc11); acc11 = MFMA(a1l, b1h, acc11);
  if (kg == 1) {
    #pragma unroll
    for (int i = 0; i < 2; ++i) {
      #pragma unroll
      for (int j = 0; j < 2; ++j) {
        const f32x4& a = (i == 0) ? (j == 0 ? acc00 : acc01) : (j == 0 ? acc10 : acc11);
        #pragma unroll
        for (int r = 0; r < 4; ++r) {
          int lr = wr*32 + i*16 + (lane >> 4)*4 + r;
          int lc = wc*32 + j*16 + (lane & 15);
          red[lr][lc] = a[r];
        }
      }
    }
  }
  __syncthreads();
  if (kg == 0) {
    #pragma unroll
    for (int i = 0; i < 2; ++i) {
      #pragma unroll
      for (int j = 0; j < 2; ++j) {
        const f32x4& a = (i == 0) ? (j == 0 ? acc00 : acc01) : (j == 0 ? acc10 : acc11);
        #pragma unroll
        for (int r = 0; r < 4; ++r) {
          int lr = wr*32 + i*16 + (lane >> 4)*4 + r;
          int lc = wc*32 + j*16 + (lane & 15);
          int row = m0 + lr;
          int col = col0 + n0 + lc;
          float v = a[r] + red[lr][lc];
          if (bias)  v += bias[col - col0];
          if (resid) v += resid[(size_t)row * Ldc + col];
          if (relu)  v = fmaxf(v, 0.f);
          size_t o = (size_t)row * Ldc + col;
          if (C) C[o] = v;
          if (Ch) {
            unsigned short hh, ll;
            hilo(v, hh, ll);
            Ch[o] = hh; Cl[o] = ll;
          }
        }
      }
    }
  }
}

// ---------------- rstd[b,m] = 1/std (std==0 -> 1) ----------------
__global__ void rstd_kernel(const float* __restrict__ G0, const float* __restrict__ G1,
                            const float* __restrict__ mu, float* __restrict__ rstd) {
  int bm = blockIdx.x * 256 + threadIdx.x;
  int b = bm >> 9, m = bm & (MM - 1);
  size_t di = (size_t)b * MM * MM + (size_t)m * MM + m;
  float g = G0[di] + G1[di];
  float mm = mu[bm];
  float cov = (g - 1024.f * mm * mm) * (1.f / 1023.f);
  float sd = sqrtf(fmaxf(cov, 0.f));
  rstd[bm] = (sd == 0.f) ? 1.f : (1.f / sd);
}

// ---------------- neighbors: packed-u32 argsort positions 1..16 ----------------
// key = (sortable_fp32(value) & ~511) | n  -> one u32 min-reduce carries both value
// and index. Ties in truncated value resolve by smaller n (same lexicographic rule).
__global__ void select_kernel(const float* __restrict__ G0, const float* __restrict__ G1,
                              const float* __restrict__ mu,
                              const float* __restrict__ rstd, int* __restrict__ nb) {
  int w = threadIdx.x >> 6, lane = threadIdx.x & 63;
  int bm = blockIdx.x * 4 + w;
  int b = bm >> 9, m = bm & (MM - 1);
  size_t rowoff = (size_t)b * MM * MM + (size_t)m * MM;
  const float* Gr0 = G0 + rowoff;
  const float* Gr1 = G1 + rowoff;
  const float* mub = mu + b * MM;
  const float* rsb = rstd + b * MM;
  float mm = mub[m], rm = rsb[m];
  unsigned key[8];
  int excl = 0;
  #pragma unroll
  for (int j = 0; j < 8; ++j) {
    int n = lane + j * 64;
    float cov = ((Gr0[n] + Gr1[n]) - 1024.f * mm * mub[n]) * (1.f / 1023.f);
    float val = cov * rm * rsb[n];
    union { float f; unsigned u; } cv; cv.f = val;
    unsigned s = cv.u ^ ((unsigned)((int)cv.u >> 31) | 0x80000000u);
    key[j] = (s & 0xFFFFFE00u) | (unsigned)n;
  }
  int* out = nb + (size_t)bm * KK;
  for (int it = 0; it < KK + 1; ++it) {
    unsigned bk = 0xFFFFFFFFu;
    #pragma unroll
    for (int j = 0; j < 8; ++j) {
      if (!((excl >> j) & 1)) bk = bk < key[j] ? bk : key[j];
    }
    #pragma unroll
    for (int off = 32; off; off >>= 1) {
      unsigned ok = __shfl_down(bk, off);
      bk = bk < ok ? bk : ok;
    }
    bk = __shfl(bk, 0);
    int n = (int)(bk & 511u);
    if ((n & 63) == lane) excl |= 1 << (n >> 6);
    if (it > 0 && lane == 0) out[it - 1] = n;
  }
}

// ---------------- degree counts ----------------
__global__ void count_kernel(const int* __restrict__ nb, int* __restrict__ cnt) {
  int e = blockIdx.x * 256 + threadIdx.x;
  int b = e >> 13, i = e & 8191;
  int dst = b * MM + nb[(size_t)b * 8192 + i];
  atomicAdd(&cnt[dst], 1);
}

// ---------------- scan + cursor + dinv ----------------
__global__ void scan_kernel(const int* __restrict__ cnt, int* __restrict__ offs,
                            int* __restrict__ curs, float* __restrict__ dinv) {
  __shared__ int part[256];
  int tid = threadIdx.x;
  int base = tid * 32;
  int local[32];
  int s = 0;
  #pragma unroll
  for (int i = 0; i < 32; ++i) { local[i] = cnt[base + i]; s += local[i]; }
  part[tid] = s;
  __syncthreads();
  for (int off = 1; off < 256; off <<= 1) {
    int v = (tid >= off) ? part[tid - off] : 0;
    __syncthreads();
    part[tid] += v;
    __syncthreads();
  }
  int run = part[tid] - s;
  #pragma unroll
  for (int i = 0; i < 32; ++i) {
    int n = base + i;
    offs[n] = run; curs[n] = run;
    run += local[i];
    dinv[n] = rsqrtf((float)(local[i] + 1));
  }
  if (tid == 255) offs[NNODE] = run;
}

// ---------------- scatter reverse edge lists ----------------
__global__ void scatter_kernel(const int* __restrict__ nb, int* __restrict__ curs,
                               int* __restrict__ lists) {
  int e = blockIdx.x * 256 + threadIdx.x;
  int b = e >> 13, i = e & 8191;
  int dst = b * MM + nb[(size_t)b * 8192 + i];
  int src = b * MM + (i & (MM - 1));
  int pos = atomicAdd(&curs[dst], 1);
  lists[pos] = src;
}

// ---------------- GCN aggregation: fp32 gather in, bf16 hi/lo out ----------------
__global__ void agg_kernel(const float* __restrict__ xw, const float* __restrict__ dinv,
                           const int* __restrict__ offs, const int* __restrict__ lists,
                           const float* __restrict__ bias,
                           unsigned short* __restrict__ outh,
                           unsigned short* __restrict__ outl) {
  int n = blockIdx.x * 2 + (threadIdx.x >> 7);
  int c = threadIdx.x & 127;
  float dn = dinv[n];
  float s = dn * xw[(size_t)n * DD + c];
  int e0 = offs[n], e1 = offs[n + 1];
  for (int e = e0; e < e1; ++e) {
    int src = lists[e];
    s += dinv[src] * xw[(size_t)src * DD + c];
  }
  float v = fmaxf(dn * s + bias[c], 0.f);
  unsigned short hh, ll;
  hilo(v, hh, ll);
  size_t o = (size_t)n * DD + c;
  outh[o] = hh; outl[o] = ll;
}

// ---------------- MFMA flash attention ----------------
__global__ __launch_bounds__(256) void attn_mfma_kernel(
    const unsigned short* __restrict__ Qb16, const unsigned short* __restrict__ KV16,
    int kvoff,
    unsigned short* __restrict__ outh, unsigned short* __restrict__ outl) {
  __shared__ unsigned short Kl[512 * 16];     // [key][16d], row 32B
  __shared__ unsigned short VT[16 * 520];     // [d][520 keys], row 1040B
  __shared__ unsigned short Pl[64 * 136];     // [q][136 keys], row 272B
  int bx = blockIdx.x;
  int qc = bx & 7;
  int h  = (bx >> 3) & 7;
  int b  = bx >> 6;
  int tid = threadIdx.x;

  for (int u = tid; u < 1024; u += 256) {
    int row = u >> 1, half = u & 1;
    const unsigned short* src = KV16 + (size_t)(b * MM + row) * 512 + kvoff + h * 16 + half * 8;
    *(uint4*)&Kl[row * 16 + half * 8] = *(const uint4*)src;
  }
  for (int key = tid; key < 512; key += 256) {
    const unsigned short* src = KV16 + (size_t)(b * MM + key) * 512 + kvoff + 128 + h * 16;
    unsigned short tmp[16];
    *(uint4*)&tmp[0] = *(const uint4*)src;
    *(uint4*)&tmp[8] = *(const uint4*)(src + 8);
    #pragma unroll
    for (int d = 0; d < 16; ++d) VT[d * 520 + key] = tmp[d];
  }
  __syncthreads();

  int wid = tid >> 6, lane = tid & 63;
  int lq = lane & 15, g = lane >> 4;
  bf16x8 zz = {0,0,0,0,0,0,0,0};
  bf16x8 qf = zz;
  if (lane < 32) {
    int qrow = b * MM + qc * 64 + wid * 16 + lq;
    qf = *(const bf16x8*)(Qb16 + (size_t)qrow * 128 + h * 16 + g * 8);
  }
  float m = -1e30f, lp = 0.f;
  f32x4 o = {0,0,0,0};
  int prow = (wid * 16 + lq) * 136;

  for (int c4 = 0; c4 < 4; ++c4) {
    int kbase = c4 * 128;
    f32x4 s[8];
    f32x4 zc = {0,0,0,0};
    #pragma unroll
    for (int t = 0; t < 8; ++t) {
      bf16x8 kf = zz;
      if (lane < 32) kf = *(const bf16x8*)&Kl[(kbase + t * 16 + lq) * 16 + g * 8];
      s[t] = MFMA(kf, qf, zc);
    }
    float tm = -1e30f;
    #pragma unroll
    for (int t = 0; t < 8; ++t) {
      tm = fmaxf(tm, fmaxf(fmaxf(s[t][0], s[t][1]), fmaxf(s[t][2], s[t][3])));
    }
    tm = fmaxf(tm, __shfl_xor(tm, 16));
    tm = fmaxf(tm, __shfl_xor(tm, 32));
    float nm = fmaxf(m, 0.25f * tm);
    float esc = __expf(m - nm);
    m = nm;
    float ls = 0.f;
    #pragma unroll
    for (int t = 0; t < 8; ++t) {
      float p0 = __expf(0.25f * s[t][0] - nm);
      float p1 = __expf(0.25f * s[t][1] - nm);
      float p2 = __expf(0.25f * s[t][2] - nm);
      float p3 = __expf(0.25f * s[t][3] - nm);
      ls += (p0 + p1) + (p2 + p3);
      unsigned w0 = (unsigned)bf16rne(p0) | ((unsigned)bf16rne(p1) << 16);
      unsigned w1 = (unsigned)bf16rne(p2) | ((unsigned)bf16rne(p3) << 16);
      int kc = t * 16 + g * 4;
      *(unsigned*)&Pl[prow + kc]     = w0;
      *(unsigned*)&Pl[prow + kc + 2] = w1;
    }
    lp = lp * esc + ls;
    float e0 = __shfl(esc, g * 4 + 0);
    float e1 = __shfl(esc, g * 4 + 1);
    float e2 = __shfl(esc, g * 4 + 2);
    float e3 = __shfl(esc, g * 4 + 3);
    o[0] *= e0; o[1] *= e1; o[2] *= e2; o[3] *= e3;
    #pragma unroll
    for (int c = 0; c < 4; ++c) {
      bf16x8 pf = *(const bf16x8*)&Pl[prow + c * 32 + g * 8];
      bf16x8 vf = *(const bf16x8*)&VT[lq * 520 + kbase + c * 32 + g * 8];
      o = MFMA(pf, vf, o);
    }
  }
  lp += __shfl_xor(lp, 16);
  lp += __shfl_xor(lp, 32);
  float linv = 1.f / lp;
  float l0 = __shfl(linv, g * 4 + 0);
  float l1 = __shfl(linv, g * 4 + 1);
  float l2 = __shfl(linv, g * 4 + 2);
  float l3 = __shfl(linv, g * 4 + 3);
  float vv[4] = {o[0] * l0, o[1] * l1, o[2] * l2, o[3] * l3};
  #pragma unroll
  for (int r = 0; r < 4; ++r) {
    int qrow = b * MM + qc * 64 + wid * 16 + g * 4 + r;
    size_t off = (size_t)qrow * DD + h * 16 + lq;
    unsigned short hh, ll;
    hilo(vv[r], hh, ll);
    outh[off] = hh; outl[off] = ll;
  }
}

// ---------------- layernorm over D=128: fp32 out + optional bf16 hi/lo out --------
__global__ void ln_kernel(const float* __restrict__ x, const float* __restrict__ g,
                          const float* __restrict__ bb, float* __restrict__ out,
                          unsigned short* __restrict__ outh,
                          unsigned short* __restrict__ outl) {
  int row = blockIdx.x * 4 + (threadIdx.x >> 6);
  int lane = threadIdx.x & 63;
  float2 xv = *(const float2*)&x[(size_t)row * DD + lane * 2];
  float s = xv.x + xv.y;
  #pragma unroll
  for (int off = 1; off < 64; off <<= 1) s += __shfl_xor(s, off);
  float mu = s * (1.f / 128.f);
  float d0 = xv.x - mu, d1 = xv.y - mu;
  float sq = d0 * d0 + d1 * d1;
  #pragma unroll
  for (int off = 1; off < 64; off <<= 1) sq += __shfl_xor(sq, off);
  float rs = rsqrtf(sq * (1.f / 128.f) + 1e-5f);
  float2 gg = *(const float2*)&g[lane * 2];
  float2 bv = *(const float2*)&bb[lane * 2];
  float2 y;
  y.x = d0 * rs * gg.x + bv.x;
  y.y = d1 * rs * gg.y + bv.y;
  *(float2*)&out[(size_t)row * DD + lane * 2] = y;
  if (outh) {
    unsigned short h0, l0, h1, l1;
    hilo(y.x, h0, l0); hilo(y.y, h1, l1);
    unsigned hh = (unsigned)h0 | ((unsigned)h1 << 16);
    unsigned ll = (unsigned)l0 | ((unsigned)l1 << 16);
    *(unsigned*)&outh[(size_t)row * DD + lane * 2] = hh;
    *(unsigned*)&outl[(size_t)row * DD + lane * 2] = ll;
  }
}

extern "C" void kernel_launch(void* const* d_in, const int* in_sizes, int n_in,
                              void* d_out, int out_size, void* d_ws, size_t ws_size,
                              hipStream_t stream) {
  (void)in_sizes; (void)n_in; (void)out_size; (void)ws_size;
  const float* enc  = (const float*)d_in[0];
  const float* xenc = (const float*)d_in[1];
  const float* gw1  = (const float*)d_in[2];
  const float* gb1  = (const float*)d_in[3];
  const float* gw2  = (const float*)d_in[4];
  const float* gb2  = (const float*)d_in[5];
  const float* Wq   = (const float*)d_in[6];
  const float* Wk   = (const float*)d_in[7];
  const float* Wv   = (const float*)d_in[8];
  const float* Wo   = (const float*)d_in[9];
  const float* ln1g = (const float*)d_in[10];
  const float* ln1b = (const float*)d_in[11];
  const float* W1   = (const float*)d_in[12];
  const float* b1   = (const float*)d_in[13];
  const float* W2   = (const float*)d_in[14];
  const float* b2   = (const float*)d_in[15];
  const float* ln2g = (const float*)d_in[16];
  const float* ln2b = (const float*)d_in[17];
  float* outp = (float*)d_out;

  char* w = (char*)d_ws;
  auto alloc = [&](size_t bytes) -> char* {
    char* p = w;
    w += (bytes + 255) & ~(size_t)255;
    return p;
  };
  float* mu    = (float*)alloc((size_t)NNODE * 4);
  float* rstd  = (float*)alloc((size_t)NNODE * 4);
  float* dinv  = (float*)alloc((size_t)NNODE * 4);
  float* mpart = (float*)alloc((size_t)8 * NNODE * 4);
  int*   nb    = (int*)  alloc((size_t)NEDGE * 4);
  int*   cnt   = (int*)  alloc((size_t)NNODE * 4);
  int*   offs  = (int*)  alloc((size_t)(NNODE + 1) * 4);
  int*   curs  = (int*)  alloc((size_t)NNODE * 4);
  int*   lists = (int*)  alloc((size_t)NEDGE * 4);
  float* gram  = (float*)alloc((size_t)BB * MM * MM * 4);   // 16MB: G0; later Qb16+KV16
  float* gram2 = (float*)alloc((size_t)BB * MM * MM * 4);   // 16MB: G1; later ff hi/lo
  float* bufx  = (float*)alloc((size_t)NNODE * DD * 4);
  float* bufxl = (float*)alloc((size_t)NNODE * DD * 4);
  float* bufh  = (float*)alloc((size_t)NNODE * DD * 4);
  float* bufh1 = (float*)alloc((size_t)NNODE * DD * 4);
  unsigned short* xth  = (unsigned short*)alloc((size_t)BB * MM * LL * 2);  // 16MB
  unsigned short* xtl  = (unsigned short*)alloc((size_t)BB * MM * LL * 2);  // 16MB
  unsigned short* wTh  = (unsigned short*)alloc((size_t)425984 * 2);
  unsigned short* wTl  = (unsigned short*)alloc((size_t)425984 * 2);
  unsigned short* ench = (unsigned short*)alloc((size_t)NNODE * DD * 2);
  unsigned short* encl = (unsigned short*)alloc((size_t)NNODE * DD * 2);
  unsigned short* x1h  = (unsigned short*)alloc((size_t)NNODE * DD * 2);
  unsigned short* x1l  = (unsigned short*)alloc((size_t)NNODE * DD * 2);
  unsigned short* kvbh = (unsigned short*)alloc((size_t)NNODE * DD * 2);
  unsigned short* kvbl = (unsigned short*)alloc((size_t)NNODE * DD * 2);
  unsigned short* xlh  = (unsigned short*)alloc((size_t)NNODE * DD * 2);
  unsigned short* xll  = (unsigned short*)alloc((size_t)NNODE * DD * 2);
  unsigned short* h1h  = (unsigned short*)alloc((size_t)NNODE * DD * 2);
  unsigned short* h1l  = (unsigned short*)alloc((size_t)NNODE * DD * 2);
  unsigned short* sdh  = (unsigned short*)alloc((size_t)NNODE * DD * 2);
  unsigned short* sdl  = (unsigned short*)alloc((size_t)NNODE * DD * 2);

  // Phase aliases (valid after graph-build consumes G0/G1):
  unsigned short* Qb16 = (unsigned short*)gram;                       // 2 MB [NNODE][128]
  unsigned short* KV16 = (unsigned short*)(gram + (size_t)1048576);   // 8 MB [NNODE][512]
  unsigned short* ffh = (unsigned short*)gram2;                         // 8MB
  unsigned short* ffl = (unsigned short*)gram2 + (size_t)NNODE * NDFF;  // 8MB

  const unsigned short* gw1Th = wTh,         *gw1Tl = wTl;
  const unsigned short* gw2Th = wTh + 16384, *gw2Tl = wTl + 16384;
  const unsigned short* KVTh01 = wTh + (size_t)2 * 16384;   // [Wk0;Wv0;Wk1;Wv1] [512][128]
  const unsigned short* KVTl01 = wTl + (size_t)2 * 16384;
  auto WqTh = [&](int l) { return wTh + (size_t)(6 + l) * 16384; };
  auto WqTl = [&](int l) { return wTl + (size_t)(6 + l) * 16384; };
  auto WoTh = [&](int l) { return wTh + (size_t)(8 + l) * 16384; };
  auto WoTl = [&](int l) { return wTl + (size_t)(8 + l) * 16384; };
  auto W1Th = [&](int l) { return wTh + 163840 + (size_t)l * 65536; };
  auto W1Tl = [&](int l) { return wTl + 163840 + (size_t)l * 65536; };
  auto W2Th = [&](int l) { return wTh + 294912 + (size_t)l * 65536; };
  auto W2Tl = [&](int l) { return wTl + 294912 + (size_t)l * 65536; };

  auto gemm = [&](const unsigned short* Ah, const unsigned short* Al,
                  const unsigned short* Bh, const unsigned short* Bl,
                  float* C, unsigned short* Ch, unsigned short* Cl,
                  int Mr, int Ncols, int Ldc, int col0, int Kd,
                  const float* bias, const float* resid, int relu) {
    dim3 g(Ncols / 64, Mr / 64);
    if (Kd == 128) {
      bf_gemm_k128_kernel<<<g, 256, 0, stream>>>(Ah, Al, Bh, Bl, C, Ch, Cl, Ldc, col0,
                                                 bias, resid, relu);
    } else {
      bf_gemm_sk_kernel<<<g, 512, 0, stream>>>(Ah, Al, Bh, Bl, C, Ch, Cl, Ldc, col0, Kd,
                                               bias, resid, relu);
    }
  };

  // ---- transposes & splits ----
  transpose_x_kernel<<<dim3(16, 32, 16), 256, 0, stream>>>(xenc, xth, xtl);
  transpose_w_kernel<<<dim3(16, 16, 14), 256, 0, stream>>>(gw1, gw2, Wq, Wk, Wv, Wo, W1, W2, wTh, wTl);
  split_kernel<<<(NNODE * DD / 4) / 256, 256, 0, stream>>>(enc, ench, encl);

  // ---- graph build ----
  colmean_part_kernel<<<dim3(32, 8), 256, 0, stream>>>(xenc, mpart);
  colmean_finish_kernel<<<NNODE / 256, 256, 0, stream>>>(mpart, mu);
  gram_kernel<<<1152, 256, 0, stream>>>(xth, xtl, gram, gram2);
  rstd_kernel<<<NNODE / 256, 256, 0, stream>>>(gram, gram2, mu, rstd);
  select_kernel<<<NNODE / 4, 256, 0, stream>>>(gram, gram2, mu, rstd, nb);
  hipMemsetAsync(cnt, 0, (size_t)NNODE * 4, stream);
  count_kernel<<<NEDGE / 256, 256, 0, stream>>>(nb, cnt);
  scan_kernel<<<1, 256, 0, stream>>>(cnt, offs, curs, dinv);
  scatter_kernel<<<NEDGE / 256, 256, 0, stream>>>(nb, curs, lists);

  // ---- 2-layer GCN (xw scratch uses bufx) ----
  gemm(ench, encl, gw1Th, gw1Tl, bufx, nullptr, nullptr, NNODE, DD, DD, 0, DD,
       nullptr, nullptr, 0);
  agg_kernel<<<NNODE / 2, 256, 0, stream>>>(bufx, dinv, offs, lists, gb1, x1h, x1l);
  gemm(x1h, x1l, gw2Th, gw2Tl, bufx, nullptr, nullptr, NNODE, DD, DD, 0, DD,
       nullptr, nullptr, 0);
  agg_kernel<<<NNODE / 2, 256, 0, stream>>>(bufx, dinv, offs, lists, gb2, kvbh, kvbl);

  // ---- fused KV projection for BOTH layers -> single bf16 [NNODE][512] ----
  gemm(kvbh, kvbl, KVTh01, KVTl01, nullptr, KV16, nullptr, NNODE, 512, 512, 0, DD,
       nullptr, nullptr, 0);

  // ---- transformer encoder layers ----
  for (int l = 0; l < 2; ++l) {
    const float* hq = (l == 0) ? enc : bufh1;
    const unsigned short* hqh = (l == 0) ? ench : h1h;
    const unsigned short* hql = (l == 0) ? encl : h1l;
    gemm(hqh, hql, WqTh(l), WqTl(l), nullptr, Qb16, nullptr, NNODE, DD, DD, 0, DD,
         nullptr, nullptr, 0);                                         // q bf16
    attn_mfma_kernel<<<BB * HH * 8, 256, 0, stream>>>(Qb16, KV16, l * 256, sdh, sdl);
    gemm(sdh, sdl, WoTh(l), WoTl(l), bufx, nullptr, nullptr, NNODE, DD, DD, 0, DD,
         nullptr, hq, 0);
    ln_kernel<<<NNODE / 4, 256, 0, stream>>>(bufx, ln1g + l * DD, ln1b + l * DD, bufxl, xlh, xll);
    gemm(xlh, xll, W1Th(l), W1Tl(l), nullptr, ffh, ffl, NNODE, NDFF, NDFF, 0, DD,
         b1 + l * NDFF, nullptr, 1);
    gemm(ffh, ffl, W2Th(l), W2Tl(l), bufh, nullptr, nullptr, NNODE, DD, DD, 0, NDFF,
         b2 + l * DD, bufxl, 0);
    if (l == 1) {
      ln_kernel<<<NNODE / 4, 256, 0, stream>>>(bufh, ln2g + l * DD, ln2b + l * DD,
                                               outp, nullptr, nullptr);
    } else {
      ln_kernel<<<NNODE / 4, 256, 0, stream>>>(bufh, ln2g + l * DD, ln2b + l * DD,
                                               bufh1, h1h, h1l);
    }
  }
}